// Round 12
// baseline (522.712 us; speedup 1.0000x reference)
//
#include <hip/hip_runtime.h>

#define VSZ 50257
#define DSZ 1024
#define TSZ 512
#define BSZ 4
#define HSZ 4096
#define VPAD 50432   // 394*128
#define NCH (VPAD / 64)   // 788 v-stripes of 64
#define NPOS 2048
#define QS 16.0f
#define DQS (1.0f / 256.0f)
#define CG 32        // stage-1 chunk groups
#define CPC 25       // chunks per group (32*25 = 800 >= 788)

typedef __attribute__((ext_vector_type(4))) float f32x4;
typedef __attribute__((ext_vector_type(16))) float f32x16;
typedef __attribute__((ext_vector_type(4))) int i32x4;
typedef __attribute__((ext_vector_type(8))) int i32x8;

#define GLD16(gp, lp) __builtin_amdgcn_global_load_lds( \
  (const __attribute__((address_space(1))) unsigned int*)(gp), \
  (__attribute__((address_space(3))) unsigned int*)(lp), 16, 0, 0)

__device__ __forceinline__ float gelu_f(float x) {
  float x3 = x * x * x;
  float u = 0.7978845608028654f * (x + 0.044715f * x3);
  return 0.5f * x * (1.f + tanhf(u));
}

__device__ __forceinline__ unsigned char q8(float v) {
  return (unsigned char)__builtin_amdgcn_cvt_pk_fp8_f32(v * QS, v * QS, 0, 0);
}

// -------- fused: all weight transposes (f32 -> fp8 x16) + enc1 partials.
// Blocks 0..14783: transposes (64x64 tiles). Blocks 14784..14911: enc1p.
#define KS1 8
#define KS2 16
__global__ __launch_bounds__(256) void transpose_all(
    const float* __restrict__ lm_w, const float* __restrict__ dw1,
    const float* __restrict__ dw2, const float* __restrict__ pw,
    unsigned char* __restrict__ lm8, unsigned char* __restrict__ w18,
    unsigned char* __restrict__ w28, unsigned char* __restrict__ p8,
    const int* __restrict__ ids, const float* __restrict__ wte,
    const float* __restrict__ w1, float* __restrict__ t1p) {
  __shared__ float tile[64][65];
  int bid = blockIdx.x;
  int tid = threadIdx.x;

  if (bid >= 14784) {
    // ---- enc1 partials: all 4 batch rows, K-chunk kc of 128 dims
    int eb = bid - 14784;
    int h = (eb & 15) * 256 + tid;
    int kc = eb >> 4;
    float (*ev)[128] = (float(*)[128])tile;
    for (int i = tid; i < 512; i += 256) {
      int b = i >> 7, d = i & 127;
      int tok = ids[b * TSZ + (TSZ - 1)];
      ev[b][d] = wte[(size_t)tok * DSZ + kc * 128 + d];
    }
    __syncthreads();
    const float* w = w1 + (size_t)(kc * 128) * HSZ + h;
    float s0 = 0.f, s1 = 0.f, s2 = 0.f, s3 = 0.f;
#pragma unroll 4
    for (int d = 0; d < 128; ++d) {
      float wv = w[(size_t)d * HSZ];
      s0 += ev[0][d] * wv; s1 += ev[1][d] * wv;
      s2 += ev[2][d] * wv; s3 += ev[3][d] * wv;
    }
    t1p[((size_t)(0 * KS1 + kc)) * HSZ + h] = s0;
    t1p[((size_t)(1 * KS1 + kc)) * HSZ + h] = s1;
    t1p[((size_t)(2 * KS1 + kc)) * HSZ + h] = s2;
    t1p[((size_t)(3 * KS1 + kc)) * HSZ + h] = s3;
    return;
  }

  const float* src; unsigned char* dst; int R, C, Cpad, bx, by;
  if (bid < 12608)      { src = lm_w; dst = lm8; R = DSZ; C = VSZ; Cpad = VPAD; bx = bid % 788; by = bid / 788; }
  else if (bid < 13632) { int b = bid - 12608; src = dw1; dst = w18; R = DSZ; C = HSZ; Cpad = HSZ; bx = b % 64; by = b / 64; }
  else if (bid < 14656) { int b = bid - 13632; src = dw2; dst = w28; R = HSZ; C = DSZ; Cpad = DSZ; bx = b % 16; by = b / 16; }
  else                  { int b = bid - 14656; src = pw;  dst = p8;  R = 512; C = DSZ; Cpad = DSZ; bx = b % 16; by = b / 16; }
  int c0 = bx * 64, r0 = by * 64;
  int wv = tid >> 6, ln = tid & 63;
  int c = c0 + ln;
#pragma unroll 4
  for (int i = 0; i < 16; ++i) {
    int r = i * 4 + wv;
    tile[r][ln] = (c < C) ? src[(size_t)(r0 + r) * C + c] : 0.f;
  }
  __syncthreads();
  int ccb = tid >> 4;
  int r4 = (tid & 15) * 4;
#pragma unroll
  for (int j = 0; j < 4; ++j) {
    int cc = ccb + j * 16;
    if (c0 + cc >= Cpad) continue;
    unsigned int u = __builtin_amdgcn_cvt_pk_fp8_f32(QS * tile[r4 + 0][cc], QS * tile[r4 + 1][cc], 0, 0);
    u = __builtin_amdgcn_cvt_pk_fp8_f32(QS * tile[r4 + 2][cc], QS * tile[r4 + 3][cc], u, 1);
    *(unsigned int*)(dst + (size_t)(c0 + cc) * R + r0 + r4) = u;
  }
}

// -------- encoder layer 2 partials: all 4 batch rows per block (w2 read once)
__global__ __launch_bounds__(256) void enc2p_kernel(const float* __restrict__ t1p,
                                                    const float* __restrict__ b1,
                                                    const float* __restrict__ w2,
                                                    float* __restrict__ ep) {
  __shared__ float ts[4][256];
  int i = blockIdx.x * 256 + threadIdx.x;
  int kc = blockIdx.y;
  int h = kc * 256 + threadIdx.x;
  float bv = b1[h];
#pragma unroll
  for (int b = 0; b < 4; ++b) {
    float s0 = bv;
#pragma unroll
    for (int cc = 0; cc < KS1; ++cc) s0 += t1p[((size_t)(b * KS1 + cc)) * HSZ + h];
    ts[b][threadIdx.x] = gelu_f(s0);
  }
  __syncthreads();
  const float* w = w2 + (size_t)(kc * 256) * DSZ + i;
  float a0 = 0.f, a1 = 0.f, a2 = 0.f, a3 = 0.f;
#pragma unroll 4
  for (int j = 0; j < 256; ++j) {
    float wv = w[(size_t)j * DSZ];
    a0 += ts[0][j] * wv; a1 += ts[1][j] * wv;
    a2 += ts[2][j] * wv; a3 += ts[3][j] * wv;
  }
  ep[((size_t)(0 * KS2 + kc)) * DSZ + i] = a0;
  ep[((size_t)(1 * KS2 + kc)) * DSZ + i] = a1;
  ep[((size_t)(2 * KS2 + kc)) * DSZ + i] = a2;
  ep[((size_t)(3 * KS2 + kc)) * DSZ + i] = a3;
}

// -------- windows (enc2 combine fused): win8[b*T+t][j] = fp8((b2[t+j] + sum ep)*16)
__global__ __launch_bounds__(256) void win8_kernel(const float* __restrict__ ep,
                                                   const float* __restrict__ b2,
                                                   unsigned char* __restrict__ win8) {
  int blk = blockIdx.x;
  int b = blk >> 9, t = blk & 511;
  const float* epb = ep + (size_t)b * KS2 * DSZ;
  for (int j = threadIdx.x; j < 512; j += 256) {
    int d = t + j;                      // < 1024 always
    float s = b2[d];
#pragma unroll
    for (int kc = 0; kc < KS2; ++kc) s += epb[(size_t)kc * DSZ + d];
    win8[(size_t)blk * 512 + j] = q8(s);
  }
}

// -------- mid fp8 GEMM (proj/dec1/dec2): 16x16x32 fp8, 128x128 tile, BK=64,
// 3-buffer ring, depth-2 prefetch, 16B-pair rotation (unchanged, proven).
template<int GELU>
__global__ __launch_bounds__(256, 3) void gemm8(
    const unsigned char* __restrict__ A, const unsigned char* __restrict__ Bm,
    const float* __restrict__ bias, unsigned char* __restrict__ out8,
    int NT, int N, int K) {
  __shared__ __align__(16) char SM[49152];
  const int tid = threadIdx.x;
  const int lane = tid & 63;
  const int wave = tid >> 6;
  const int wr = (wave >> 1) * 64, wc = (wave & 1) * 64;
  const int l15 = lane & 15, l4 = lane >> 4;

  const int cpx = (int)gridDim.x >> 3;
  const int wg = ((int)blockIdx.x & 7) * cpx + ((int)blockIdx.x >> 3);
  const int m0 = (wg / NT) * 128, n0 = (wg % NT) * 128;

  f32x4 acc[4][4];
#pragma unroll
  for (int i = 0; i < 4; ++i)
#pragma unroll
    for (int j = 0; j < 4; ++j) acc[i][j] = (f32x4){0.f, 0.f, 0.f, 0.f};

  const int ppair = lane & 3;
  const int row0 = wave * 16 + (lane >> 2);
  const int row1 = row0 + 64;
  const int og0 = (ppair - (row0 >> 1)) & 3;
  const int og1 = (ppair - (row1 >> 1)) & 3;
  const unsigned char* a0 = A + (size_t)(m0 + row0) * K + og0 * 16;
  const unsigned char* a1 = A + (size_t)(m0 + row1) * K + og1 * 16;
  const unsigned char* b0 = Bm + (size_t)(n0 + row0) * K + og0 * 16;
  const unsigned char* b1 = Bm + (size_t)(n0 + row1) * K + og1 * 16;

#define STG8(tt, bufb) do { \
    GLD16(a0 + (size_t)(tt) * 64, SM + (bufb) + wave * 1024); \
    GLD16(a1 + (size_t)(tt) * 64, SM + (bufb) + 4096 + wave * 1024); \
    GLD16(b0 + (size_t)(tt) * 64, SM + (bufb) + 8192 + wave * 1024); \
    GLD16(b1 + (size_t)(tt) * 64, SM + (bufb) + 12288 + wave * 1024); \
  } while (0)

  const int KT = K >> 6;
  STG8(0, 0);
  if (KT > 1) STG8(1, 16384);
  int cb = 0;
  for (int t = 0; t < KT; ++t) {
    if (t + 2 < KT) {
      int nb = cb + 32768; if (nb >= 49152) nb -= 49152;
      STG8(t + 2, nb);
      asm volatile("s_waitcnt vmcnt(8)" ::: "memory");
    } else if (t + 1 < KT) {
      asm volatile("s_waitcnt vmcnt(4)" ::: "memory");
    } else {
      asm volatile("s_waitcnt vmcnt(0)" ::: "memory");
    }
    __builtin_amdgcn_s_barrier();
    asm volatile("" ::: "memory");
    long af[4][2], bfr[4][2];
#pragma unroll
    for (int mi = 0; mi < 4; ++mi) {
      const int row = wr + mi * 16 + l15;
#pragma unroll
      for (int kk = 0; kk < 2; ++kk) {
        const int ph = ((kk * 2 + (l4 >> 1)) + (row >> 1)) & 3;
        af[mi][kk] = *(const long*)(SM + cb + row * 64 + ph * 16 + (l4 & 1) * 8);
      }
    }
#pragma unroll
    for (int ni = 0; ni < 4; ++ni) {
      const int row = wc + ni * 16 + l15;
#pragma unroll
      for (int kk = 0; kk < 2; ++kk) {
        const int ph = ((kk * 2 + (l4 >> 1)) + (row >> 1)) & 3;
        bfr[ni][kk] = *(const long*)(SM + cb + 8192 + row * 64 + ph * 16 + (l4 & 1) * 8);
      }
    }
    asm volatile("s_waitcnt lgkmcnt(0)" ::: "memory");
    __builtin_amdgcn_sched_barrier(0);
    __builtin_amdgcn_s_setprio(1);
#pragma unroll
    for (int kk = 0; kk < 2; ++kk)
#pragma unroll
      for (int mi = 0; mi < 4; ++mi)
#pragma unroll
        for (int ni = 0; ni < 4; ++ni)
          acc[mi][ni] = __builtin_amdgcn_mfma_f32_16x16x32_fp8_fp8(
              af[mi][kk], bfr[ni][kk], acc[mi][ni], 0, 0, 0);
    __builtin_amdgcn_s_setprio(0);
    __builtin_amdgcn_s_barrier();
    asm volatile("" ::: "memory");
    cb += 16384; if (cb >= 49152) cb = 0;
  }
#undef STG8

#pragma unroll
  for (int ni = 0; ni < 4; ++ni) {
    int n = n0 + wc + ni * 16 + l15;
    float bv = bias[n];
#pragma unroll
    for (int mi = 0; mi < 4; ++mi) {
#pragma unroll
      for (int r = 0; r < 4; ++r) {
        int m = m0 + wr + mi * 16 + l4 * 4 + r;
        float v = acc[mi][ni][r] * DQS + bv;
        if (GELU) v = gelu_f(v);
        out8[(size_t)m * N + n] = q8(v);
      }
    }
  }
}

// -------- lm-head MX-fp8 GEMM: mfma_scale 32x32x64 (2x fp8 rate), 128x128 tile,
// BK=64, 3-buffer ring depth-2, proven rotation LDS layout (0 conflicts).
// E8M0 scales = 123 (2^-4 each) fold in the 1/256 dequant. Epilogue: fused
// softmax partials + DIRECT nontemporal stores (no LDS restage, no barriers).
__global__ __launch_bounds__(256, 3) void gemmLM(
    const unsigned char* __restrict__ A, const unsigned char* __restrict__ Bm,
    float* __restrict__ outF, float* __restrict__ pm, float* __restrict__ ps) {
  __shared__ __align__(16) char SM[49152];
  const int tid = threadIdx.x;
  const int lane = tid & 63;
  const int wave = tid >> 6;
  const int wr = (wave >> 1) * 64, wc = (wave & 1) * 64;
  const int l31 = lane & 31, hi = lane >> 5;

  const int cpx = (int)gridDim.x >> 3;
  const int wg = ((int)blockIdx.x & 7) * cpx + ((int)blockIdx.x >> 3);
  const int m0 = (wg >> 4) * 128, n0 = (wg & 15) * 128;

  f32x16 acc[2][2];
#pragma unroll
  for (int i = 0; i < 2; ++i)
#pragma unroll
    for (int j = 0; j < 2; ++j)
#pragma unroll
      for (int r = 0; r < 16; ++r) acc[i][j][r] = 0.f;

  // staging: rotation layout (linear LDS dest, inverse-rotated global src)
  const int ppair = lane & 3;
  const int row0 = wave * 16 + (lane >> 2);
  const int row1 = row0 + 64;
  const int og0 = (ppair - (row0 >> 1)) & 3;
  const int og1 = (ppair - (row1 >> 1)) & 3;
  const unsigned char* a0 = A + (size_t)(m0 + row0) * DSZ + og0 * 16;
  const unsigned char* a1 = A + (size_t)(m0 + row1) * DSZ + og1 * 16;
  const unsigned char* b0 = Bm + (size_t)(n0 + row0) * DSZ + og0 * 16;
  const unsigned char* b1 = Bm + (size_t)(n0 + row1) * DSZ + og1 * 16;

#define STGL(tt, bufb) do { \
    GLD16(a0 + (size_t)(tt) * 64, SM + (bufb) + wave * 1024); \
    GLD16(a1 + (size_t)(tt) * 64, SM + (bufb) + 4096 + wave * 1024); \
    GLD16(b0 + (size_t)(tt) * 64, SM + (bufb) + 8192 + wave * 1024); \
    GLD16(b1 + (size_t)(tt) * 64, SM + (bufb) + 12288 + wave * 1024); \
  } while (0)

  STGL(0, 0);
  STGL(1, 16384);
  int cb = 0;
  for (int t = 0; t < 16; ++t) {
    if (t + 2 < 16) {
      int nb = cb + 32768; if (nb >= 49152) nb -= 49152;
      STGL(t + 2, nb);
      asm volatile("s_waitcnt vmcnt(8)" ::: "memory");
    } else if (t + 1 < 16) {
      asm volatile("s_waitcnt vmcnt(4)" ::: "memory");
    } else {
      asm volatile("s_waitcnt vmcnt(0)" ::: "memory");
    }
    __builtin_amdgcn_s_barrier();
    asm volatile("" ::: "memory");
    // fragment = 32B of k per lane: pairs {2hi, 2hi+1} at rotated positions
    i32x8 a8[2], b8[2];
#pragma unroll
    for (int mf = 0; mf < 2; ++mf) {
      const int row = wr + mf * 32 + l31;
      const char* base = SM + cb + row * 64;
      const int ph0 = (2 * hi + (row >> 1)) & 3;
      const int ph1 = (2 * hi + 1 + (row >> 1)) & 3;
      i32x4 q01 = *(const i32x4*)(base + ph0 * 16);
      i32x4 q23 = *(const i32x4*)(base + ph1 * 16);
      a8[mf] = __builtin_shufflevector(q01, q23, 0, 1, 2, 3, 4, 5, 6, 7);
    }
#pragma unroll
    for (int nf = 0; nf < 2; ++nf) {
      const int row = wc + nf * 32 + l31;
      const char* base = SM + cb + 8192 + row * 64;
      const int ph0 = (2 * hi + (row >> 1)) & 3;
      const int ph1 = (2 * hi + 1 + (row >> 1)) & 3;
      i32x4 q01 = *(const i32x4*)(base + ph0 * 16);
      i32x4 q23 = *(const i32x4*)(base + ph1 * 16);
      b8[nf] = __builtin_shufflevector(q01, q23, 0, 1, 2, 3, 4, 5, 6, 7);
    }
    asm volatile("s_waitcnt lgkmcnt(0)" ::: "memory");
    __builtin_amdgcn_sched_barrier(0);
    __builtin_amdgcn_s_setprio(1);
#pragma unroll
    for (int mf = 0; mf < 2; ++mf)
#pragma unroll
      for (int nf = 0; nf < 2; ++nf)
        acc[mf][nf] = __builtin_amdgcn_mfma_scale_f32_32x32x64_f8f6f4(
            a8[mf], b8[nf], acc[mf][nf], 0, 0, 0, 123, 0, 123);
    __builtin_amdgcn_s_setprio(0);
    __builtin_amdgcn_s_barrier();
    asm volatile("" ::: "memory");
    cb += 16384; if (cb >= 49152) cb = 0;
  }
#undef STGL

  // ---- fused softmax partials: wave's 64 v-rows = stripe ch
  // C/D: col = l31, row = (reg&3) + 8*(reg>>2) + 4*hi
  const int ch = (m0 + wr) >> 6;
#pragma unroll
  for (int nf = 0; nf < 2; ++nf) {
    const int pos = n0 + wc + nf * 32 + l31;
    float mloc = -1e30f, sloc = 0.f;
#pragma unroll
    for (int mf = 0; mf < 2; ++mf) {
      const int vb = m0 + wr + mf * 32 + 4 * hi;
#pragma unroll
      for (int r = 0; r < 16; ++r) {
        const int v = vb + (r & 3) + 8 * (r >> 2);
        if (v < VSZ) mloc = fmaxf(mloc, acc[mf][nf][r]);
      }
    }
#pragma unroll
    for (int mf = 0; mf < 2; ++mf) {
      const int vb = m0 + wr + mf * 32 + 4 * hi;
#pragma unroll
      for (int r = 0; r < 16; ++r) {
        const int v = vb + (r & 3) + 8 * (r >> 2);
        if (v < VSZ) sloc += __expf(acc[mf][nf][r] - mloc);
      }
    }
    {
      float mo = __shfl_xor(mloc, 32, 64);
      float so = __shfl_xor(sloc, 32, 64);
      float nm = fmaxf(mloc, mo);
      sloc = sloc * __expf(mloc - nm) + so * __expf(mo - nm);
      mloc = nm;
    }
    if (hi == 0) {
      pm[(size_t)ch * NPOS + pos] = mloc;
      ps[(size_t)ch * NPOS + pos] = sloc;
    }
  }

  // ---- direct nontemporal logit stores: per instr 2 x 128B contiguous
  // segments; 4 nf/wc segments tile each v-row's 512B contiguously.
  const int bb = n0 >> 9, t0 = n0 & 511;
  float* outG = outF + 1 + (size_t)bb * VSZ * TSZ + t0;
#pragma unroll
  for (int mf = 0; mf < 2; ++mf) {
#pragma unroll
    for (int nf = 0; nf < 2; ++nf) {
      const int pcol = wc + nf * 32 + l31;
#pragma unroll
      for (int r = 0; r < 16; ++r) {
        const int vrow = m0 + wr + mf * 32 + (r & 3) + 8 * (r >> 2) + 4 * hi;
        if (vrow < VSZ)
          __builtin_nontemporal_store(acc[mf][nf][r], outG + (size_t)vrow * TSZ + pcol);
      }
    }
  }
}

// -------- loss stage 1: merge 25-chunk groups (256 blocks = full GPU)
__global__ __launch_bounds__(256) void lsestage1_kernel(const float* __restrict__ pm,
                                                        const float* __restrict__ ps,
                                                        float* __restrict__ pm2,
                                                        float* __restrict__ ps2) {
  int pos = (blockIdx.x & 7) * 256 + threadIdx.x;
  int cg = blockIdx.x >> 3;
  int c0 = cg * CPC;
  int c1 = c0 + CPC; if (c1 > NCH) c1 = NCH;
  float m = -1e30f, s = 0.f;
  for (int c = c0; c < c1; ++c) {
    float cm = pm[(size_t)c * NPOS + pos];
    float cs = ps[(size_t)c * NPOS + pos];
    float nm = fmaxf(m, cm);
    s = s * __expf(m - nm) + cs * __expf(cm - nm);
    m = nm;
  }
  pm2[(size_t)cg * NPOS + pos] = m;
  ps2[(size_t)cg * NPOS + pos] = s;
}

// -------- loss stage 2: merge 32 groups per position, gather label logit
__global__ __launch_bounds__(256) void lsemerge_kernel(const float* __restrict__ pm2,
                                                       const float* __restrict__ ps2,
                                                       const float* __restrict__ outF,
                                                       const int* __restrict__ labels,
                                                       float* __restrict__ contrib) {
  int pos = blockIdx.x * 256 + threadIdx.x;
  float m[4] = {-1e30f, -1e30f, -1e30f, -1e30f};
  float s[4] = {0.f, 0.f, 0.f, 0.f};
  for (int c = 0; c < CG; c += 4) {
#pragma unroll
    for (int j = 0; j < 4; ++j) {
      float cm = pm2[(size_t)(c + j) * NPOS + pos];
      float cs = ps2[(size_t)(c + j) * NPOS + pos];
      float nm = fmaxf(m[j], cm);
      s[j] = s[j] * __expf(m[j] - nm) + cs * __expf(cm - nm);
      m[j] = nm;
    }
  }
#pragma unroll
  for (int j = 1; j < 4; ++j) {
    float nm = fmaxf(m[0], m[j]);
    s[0] = s[0] * __expf(m[0] - nm) + s[j] * __expf(m[j] - nm);
    m[0] = nm;
  }
  float lse = m[0] + logf(s[0]);
  int b = pos >> 9, t = pos & 511;
  int lab = labels[pos];
  float x = outF[1 + (size_t)b * VSZ * TSZ + (size_t)lab * TSZ + t];
  contrib[pos] = lse - x;
}

__global__ __launch_bounds__(256) void lossfinal_kernel(const float* __restrict__ contrib,
                                                        float* __restrict__ dout) {
  __shared__ float red[256];
  int tid = threadIdx.x;
  float a = 0.f;
  for (int i = tid; i < NPOS; i += 256) a += contrib[i];
  red[tid] = a;
  __syncthreads();
  for (int off = 128; off; off >>= 1) {
    if (tid < off) red[tid] += red[tid + off];
    __syncthreads();
  }
  if (tid == 0) dout[0] = red[0] / (float)NPOS;
}

extern "C" void kernel_launch(void* const* d_in, const int* in_sizes, int n_in,
                              void* d_out, int out_size, void* d_ws, size_t ws_size,
                              hipStream_t stream) {
  const int* input_ids = (const int*)d_in[0];
  const int* labels    = (const int*)d_in[1];
  const float* wte     = (const float*)d_in[2];
  const float* enc_w1  = (const float*)d_in[3];
  const float* enc_b1  = (const float*)d_in[4];
  const float* enc_w2  = (const float*)d_in[5];
  const float* enc_b2  = (const float*)d_in[6];
  const float* proj_w  = (const float*)d_in[7];
  const float* proj_b  = (const float*)d_in[8];
  const float* dec_w1  = (const float*)d_in[9];
  const float* dec_b1  = (const float*)d_in[10];
  const float* dec_w2  = (const float*)d_in[11];
  const float* dec_b2  = (const float*)d_in[12];
  const float* lm_w    = (const float*)d_in[13];
  float* outF = (float*)d_out;

  char* w = (char*)d_ws;
  size_t off = 0;
  unsigned char* lm8  = (unsigned char*)(w + off); off += (size_t)VPAD * DSZ;   // 51.6 MB
  unsigned char* w18  = (unsigned char*)(w + off); off += (size_t)HSZ * DSZ;    // 4 MB
  unsigned char* w28  = (unsigned char*)(w + off); off += (size_t)DSZ * HSZ;    // 4 MB
  unsigned char* p8   = (unsigned char*)(w + off); off += (size_t)DSZ * 512;    // 0.5 MB
  unsigned char* win8 = (unsigned char*)(w + off); off += (size_t)NPOS * 512;   // 1 MB
  unsigned char* pbuf8= (unsigned char*)(w + off); off += (size_t)NPOS * DSZ;   // 2 MB
  unsigned char* abuf8= (unsigned char*)(w + off); off += (size_t)NPOS * HSZ;   // 8 MB
  unsigned char* dbuf8= (unsigned char*)(w + off); off += (size_t)NPOS * DSZ;   // 2 MB
  float* t1p    = (float*)(w + off);  off += (size_t)BSZ * KS1 * HSZ * 4;
  float* ep     = (float*)(w + off);  off += (size_t)BSZ * KS2 * DSZ * 4;
  float* contrib= (float*)(w + off);  off += (size_t)NPOS * 4;
  float* pm     = (float*)(w + off);  off += (size_t)NCH * NPOS * 4;            // 6.5 MB
  float* ps     = (float*)(w + off);  off += (size_t)NCH * NPOS * 4;            // 6.5 MB
  float* pm2    = (float*)(w + off);  off += (size_t)CG * NPOS * 4;             // 256 KB
  float* ps2    = (float*)(w + off);  off += (size_t)CG * NPOS * 4;             // 256 KB
  (void)ws_size; (void)in_sizes; (void)n_in; (void)out_size;

  // weight transposes + enc1 partials in one dispatch
  transpose_all<<<14912, 256, 0, stream>>>(lm_w, dec_w1, dec_w2, proj_w,
                                           lm8, w18, w28, p8,
                                           input_ids, wte, enc_w1, t1p);

  // encoder layer 2 + windows (enc2 combine fused into win8)
  enc2p_kernel<<<dim3(DSZ / 256, KS2), 256, 0, stream>>>(t1p, enc_b1, enc_w2, ep);
  win8_kernel<<<2048, 256, 0, stream>>>(ep, enc_b2, win8);

  // fp8 GEMM chain (1D grids, all divisible by 8 for the XCD swizzle)
  gemm8<0><<<128, 256, 0, stream>>>(win8, p8, proj_b, pbuf8, 8, DSZ, 512);
  gemm8<1><<<512, 256, 0, stream>>>(pbuf8, w18, dec_b1, abuf8, 32, HSZ, DSZ);
  gemm8<0><<<128, 256, 0, stream>>>(abuf8, w28, dec_b2, dbuf8, 8, DSZ, HSZ);
  // lm head MX-fp8: 394 m-tiles x 16 n-tiles = 6304 blocks
  gemmLM<<<6304, 256, 0, stream>>>(lm8, dbuf8, outF, pm, ps);

  // loss: two-stage merge + mean
  lsestage1_kernel<<<256, 256, 0, stream>>>(pm, ps, pm2, ps2);
  lsemerge_kernel<<<dim3(NPOS / 256), 256, 0, stream>>>(pm2, ps2, outF, labels, contrib);
  lossfinal_kernel<<<1, 256, 0, stream>>>(contrib, outF);
}

// Round 13
// 398.708 us; speedup vs baseline: 1.3110x; 1.3110x over previous
//
#include <hip/hip_runtime.h>

#define VSZ 50257
#define DSZ 1024
#define TSZ 512
#define BSZ 4
#define HSZ 4096
#define VPAD 50432   // 394*128
#define NCH (VPAD / 64)   // 788 v-stripes of 64
#define NPOS 2048
#define QS 16.0f
#define DQS (1.0f / 256.0f)
#define CG 32        // stage-1 chunk groups
#define CPC 25       // chunks per group (32*25 = 800 >= 788)

typedef __attribute__((ext_vector_type(4))) float f32x4;
typedef __attribute__((ext_vector_type(16))) float f32x16;
typedef __attribute__((ext_vector_type(4))) int i32x4;
typedef __attribute__((ext_vector_type(8))) int i32x8;

#define GLD16(gp, lp) __builtin_amdgcn_global_load_lds( \
  (const __attribute__((address_space(1))) unsigned int*)(gp), \
  (__attribute__((address_space(3))) unsigned int*)(lp), 16, 0, 0)

__device__ __forceinline__ float gelu_f(float x) {
  float x3 = x * x * x;
  float u = 0.7978845608028654f * (x + 0.044715f * x3);
  return 0.5f * x * (1.f + tanhf(u));
}

__device__ __forceinline__ unsigned char q8(float v) {
  return (unsigned char)__builtin_amdgcn_cvt_pk_fp8_f32(v * QS, v * QS, 0, 0);
}

// -------- all weight transposes fused: f32 (R x C) -> fp8 x16 (Cpad x R), 64x64 tiles
__global__ __launch_bounds__(256) void transpose_all(
    const float* __restrict__ lm_w, const float* __restrict__ dw1,
    const float* __restrict__ dw2, const float* __restrict__ pw,
    unsigned char* __restrict__ lm8, unsigned char* __restrict__ w18,
    unsigned char* __restrict__ w28, unsigned char* __restrict__ p8) {
  __shared__ float tile[64][65];
  int bid = blockIdx.x;
  const float* src; unsigned char* dst; int R, C, Cpad, bx, by;
  if (bid < 12608)      { src = lm_w; dst = lm8; R = DSZ; C = VSZ; Cpad = VPAD; bx = bid % 788; by = bid / 788; }
  else if (bid < 13632) { int b = bid - 12608; src = dw1; dst = w18; R = DSZ; C = HSZ; Cpad = HSZ; bx = b % 64; by = b / 64; }
  else if (bid < 14656) { int b = bid - 13632; src = dw2; dst = w28; R = HSZ; C = DSZ; Cpad = DSZ; bx = b % 16; by = b / 16; }
  else                  { int b = bid - 14656; src = pw;  dst = p8;  R = 512; C = DSZ; Cpad = DSZ; bx = b % 16; by = b / 16; }
  int c0 = bx * 64, r0 = by * 64;
  int tid = threadIdx.x;
  int wv = tid >> 6, ln = tid & 63;
  int c = c0 + ln;
#pragma unroll 4
  for (int i = 0; i < 16; ++i) {
    int r = i * 4 + wv;
    tile[r][ln] = (c < C) ? src[(size_t)(r0 + r) * C + c] : 0.f;
  }
  __syncthreads();
  int ccb = tid >> 4;
  int r4 = (tid & 15) * 4;
#pragma unroll
  for (int j = 0; j < 4; ++j) {
    int cc = ccb + j * 16;
    if (c0 + cc >= Cpad) continue;
    unsigned int u = __builtin_amdgcn_cvt_pk_fp8_f32(QS * tile[r4 + 0][cc], QS * tile[r4 + 1][cc], 0, 0);
    u = __builtin_amdgcn_cvt_pk_fp8_f32(QS * tile[r4 + 2][cc], QS * tile[r4 + 3][cc], u, 1);
    *(unsigned int*)(dst + (size_t)(c0 + cc) * R + r0 + r4) = u;
  }
}

// -------- encoder layer 1 partials: all 4 batch rows per block (w1 read once)
#define KS1 8
__global__ __launch_bounds__(256) void enc1p_kernel(const int* __restrict__ ids,
                                                    const float* __restrict__ wte,
                                                    const float* __restrict__ w1,
                                                    float* __restrict__ t1p) {
  __shared__ float ev[4][128];
  int h = blockIdx.x * 256 + threadIdx.x;
  int kc = blockIdx.y;
  for (int i = threadIdx.x; i < 512; i += 256) {
    int b = i >> 7, d = i & 127;
    int tok = ids[b * TSZ + (TSZ - 1)];
    ev[b][d] = wte[(size_t)tok * DSZ + kc * 128 + d];
  }
  __syncthreads();
  const float* w = w1 + (size_t)(kc * 128) * HSZ + h;
  float s0 = 0.f, s1 = 0.f, s2 = 0.f, s3 = 0.f;
#pragma unroll 4
  for (int d = 0; d < 128; ++d) {
    float wv = w[(size_t)d * HSZ];
    s0 += ev[0][d] * wv; s1 += ev[1][d] * wv;
    s2 += ev[2][d] * wv; s3 += ev[3][d] * wv;
  }
  t1p[((size_t)(0 * KS1 + kc)) * HSZ + h] = s0;
  t1p[((size_t)(1 * KS1 + kc)) * HSZ + h] = s1;
  t1p[((size_t)(2 * KS1 + kc)) * HSZ + h] = s2;
  t1p[((size_t)(3 * KS1 + kc)) * HSZ + h] = s3;
}

// -------- encoder layer 2 partials: all 4 batch rows per block (w2 read once)
#define KS2 16
__global__ __launch_bounds__(256) void enc2p_kernel(const float* __restrict__ t1p,
                                                    const float* __restrict__ b1,
                                                    const float* __restrict__ w2,
                                                    float* __restrict__ ep) {
  __shared__ float ts[4][256];
  int i = blockIdx.x * 256 + threadIdx.x;
  int kc = blockIdx.y;
  int h = kc * 256 + threadIdx.x;
  float bv = b1[h];
#pragma unroll
  for (int b = 0; b < 4; ++b) {
    float s0 = bv;
#pragma unroll
    for (int cc = 0; cc < KS1; ++cc) s0 += t1p[((size_t)(b * KS1 + cc)) * HSZ + h];
    ts[b][threadIdx.x] = gelu_f(s0);
  }
  __syncthreads();
  const float* w = w2 + (size_t)(kc * 256) * DSZ + i;
  float a0 = 0.f, a1 = 0.f, a2 = 0.f, a3 = 0.f;
#pragma unroll 4
  for (int j = 0; j < 256; ++j) {
    float wv = w[(size_t)j * DSZ];
    a0 += ts[0][j] * wv; a1 += ts[1][j] * wv;
    a2 += ts[2][j] * wv; a3 += ts[3][j] * wv;
  }
  ep[((size_t)(0 * KS2 + kc)) * DSZ + i] = a0;
  ep[((size_t)(1 * KS2 + kc)) * DSZ + i] = a1;
  ep[((size_t)(2 * KS2 + kc)) * DSZ + i] = a2;
  ep[((size_t)(3 * KS2 + kc)) * DSZ + i] = a3;
}

__global__ __launch_bounds__(256) void enc2c_kernel(const float* __restrict__ ep,
                                                    const float* __restrict__ b2,
                                                    float* __restrict__ e) {
  int idx = blockIdx.x * 256 + threadIdx.x;
  int b = idx >> 10, i = idx & (DSZ - 1);
  float s = b2[i];
#pragma unroll
  for (int kc = 0; kc < KS2; ++kc) s += ep[((size_t)(b * KS2 + kc)) * DSZ + i];
  e[idx] = s;
}

// -------- windows: win8[b*T+t][j] = fp8(e[b][t+j] * 16)
__global__ void win8_kernel(const float* __restrict__ e, unsigned char* __restrict__ win8) {
  int blk = blockIdx.x;
  int b = blk >> 9, t = blk & 511;
  const float* eb = e + b * DSZ;
  for (int j = threadIdx.x; j < 512; j += 256)
    win8[(size_t)blk * 512 + j] = q8(eb[t + j]);
}

// -------- mid fp8 GEMM (proj/dec1/dec2): 16x16x32 fp8, 128x128 tile, BK=64,
// 3-buffer ring, depth-2 prefetch, 16B-pair rotation (unchanged, proven).
template<int GELU>
__global__ __launch_bounds__(256, 3) void gemm8(
    const unsigned char* __restrict__ A, const unsigned char* __restrict__ Bm,
    const float* __restrict__ bias, unsigned char* __restrict__ out8,
    int NT, int N, int K) {
  __shared__ __align__(16) char SM[49152];
  const int tid = threadIdx.x;
  const int lane = tid & 63;
  const int wave = tid >> 6;
  const int wr = (wave >> 1) * 64, wc = (wave & 1) * 64;
  const int l15 = lane & 15, l4 = lane >> 4;

  const int cpx = (int)gridDim.x >> 3;
  const int wg = ((int)blockIdx.x & 7) * cpx + ((int)blockIdx.x >> 3);
  const int m0 = (wg / NT) * 128, n0 = (wg % NT) * 128;

  f32x4 acc[4][4];
#pragma unroll
  for (int i = 0; i < 4; ++i)
#pragma unroll
    for (int j = 0; j < 4; ++j) acc[i][j] = (f32x4){0.f, 0.f, 0.f, 0.f};

  const int ppair = lane & 3;
  const int row0 = wave * 16 + (lane >> 2);
  const int row1 = row0 + 64;
  const int og0 = (ppair - (row0 >> 1)) & 3;
  const int og1 = (ppair - (row1 >> 1)) & 3;
  const unsigned char* a0 = A + (size_t)(m0 + row0) * K + og0 * 16;
  const unsigned char* a1 = A + (size_t)(m0 + row1) * K + og1 * 16;
  const unsigned char* b0 = Bm + (size_t)(n0 + row0) * K + og0 * 16;
  const unsigned char* b1 = Bm + (size_t)(n0 + row1) * K + og1 * 16;

#define STG8(tt, bufb) do { \
    GLD16(a0 + (size_t)(tt) * 64, SM + (bufb) + wave * 1024); \
    GLD16(a1 + (size_t)(tt) * 64, SM + (bufb) + 4096 + wave * 1024); \
    GLD16(b0 + (size_t)(tt) * 64, SM + (bufb) + 8192 + wave * 1024); \
    GLD16(b1 + (size_t)(tt) * 64, SM + (bufb) + 12288 + wave * 1024); \
  } while (0)

  const int KT = K >> 6;
  STG8(0, 0);
  if (KT > 1) STG8(1, 16384);
  int cb = 0;
  for (int t = 0; t < KT; ++t) {
    if (t + 2 < KT) {
      int nb = cb + 32768; if (nb >= 49152) nb -= 49152;
      STG8(t + 2, nb);
      asm volatile("s_waitcnt vmcnt(8)" ::: "memory");
    } else if (t + 1 < KT) {
      asm volatile("s_waitcnt vmcnt(4)" ::: "memory");
    } else {
      asm volatile("s_waitcnt vmcnt(0)" ::: "memory");
    }
    __builtin_amdgcn_s_barrier();
    asm volatile("" ::: "memory");
    long af[4][2], bfr[4][2];
#pragma unroll
    for (int mi = 0; mi < 4; ++mi) {
      const int row = wr + mi * 16 + l15;
#pragma unroll
      for (int kk = 0; kk < 2; ++kk) {
        const int ph = ((kk * 2 + (l4 >> 1)) + (row >> 1)) & 3;
        af[mi][kk] = *(const long*)(SM + cb + row * 64 + ph * 16 + (l4 & 1) * 8);
      }
    }
#pragma unroll
    for (int ni = 0; ni < 4; ++ni) {
      const int row = wc + ni * 16 + l15;
#pragma unroll
      for (int kk = 0; kk < 2; ++kk) {
        const int ph = ((kk * 2 + (l4 >> 1)) + (row >> 1)) & 3;
        bfr[ni][kk] = *(const long*)(SM + cb + 8192 + row * 64 + ph * 16 + (l4 & 1) * 8);
      }
    }
    asm volatile("s_waitcnt lgkmcnt(0)" ::: "memory");
    __builtin_amdgcn_sched_barrier(0);
    __builtin_amdgcn_s_setprio(1);
#pragma unroll
    for (int kk = 0; kk < 2; ++kk)
#pragma unroll
      for (int mi = 0; mi < 4; ++mi)
#pragma unroll
        for (int ni = 0; ni < 4; ++ni)
          acc[mi][ni] = __builtin_amdgcn_mfma_f32_16x16x32_fp8_fp8(
              af[mi][kk], bfr[ni][kk], acc[mi][ni], 0, 0, 0);
    __builtin_amdgcn_s_setprio(0);
    __builtin_amdgcn_s_barrier();
    asm volatile("" ::: "memory");
    cb += 16384; if (cb >= 49152) cb = 0;
  }
#undef STG8

#pragma unroll
  for (int ni = 0; ni < 4; ++ni) {
    int n = n0 + wc + ni * 16 + l15;
    float bv = bias[n];
#pragma unroll
    for (int mi = 0; mi < 4; ++mi) {
#pragma unroll
      for (int r = 0; r < 4; ++r) {
        int m = m0 + wr + mi * 16 + l4 * 4 + r;
        float v = acc[mi][ni][r] * DQS + bv;
        if (GELU) v = gelu_f(v);
        out8[(size_t)m * N + n] = q8(v);
      }
    }
  }
}

// -------- lm-head MX-fp8 GEMM: mfma_scale 32x32x64 (2x fp8 rate), 128x128 tile,
// BK=64, 3-buffer ring depth-2, proven rotation LDS layout. E8M0 scales = 123
// (2^-4 each) fold in the 1/256 dequant. Epilogue: fused softmax partials +
// 2-pass dual-region LDS restage (4 barriers) + aligned f32x4 NT stores.
__global__ __launch_bounds__(256, 3) void gemmLM(
    const unsigned char* __restrict__ A, const unsigned char* __restrict__ Bm,
    float* __restrict__ outF, float* __restrict__ pm, float* __restrict__ ps) {
  __shared__ __align__(16) char SM[49152];
  const int tid = threadIdx.x;
  const int lane = tid & 63;
  const int wave = tid >> 6;
  const int wr = (wave >> 1) * 64, wc = (wave & 1) * 64;
  const int l31 = lane & 31, hi = lane >> 5;

  const int cpx = (int)gridDim.x >> 3;
  const int wg = ((int)blockIdx.x & 7) * cpx + ((int)blockIdx.x >> 3);
  const int m0 = (wg >> 4) * 128, n0 = (wg & 15) * 128;

  f32x16 acc[2][2];
#pragma unroll
  for (int i = 0; i < 2; ++i)
#pragma unroll
    for (int j = 0; j < 2; ++j)
#pragma unroll
      for (int r = 0; r < 16; ++r) acc[i][j][r] = 0.f;

  // staging: rotation layout (linear LDS dest, inverse-rotated global src)
  const int ppair = lane & 3;
  const int row0 = wave * 16 + (lane >> 2);
  const int row1 = row0 + 64;
  const int og0 = (ppair - (row0 >> 1)) & 3;
  const int og1 = (ppair - (row1 >> 1)) & 3;
  const unsigned char* a0 = A + (size_t)(m0 + row0) * DSZ + og0 * 16;
  const unsigned char* a1 = A + (size_t)(m0 + row1) * DSZ + og1 * 16;
  const unsigned char* b0 = Bm + (size_t)(n0 + row0) * DSZ + og0 * 16;
  const unsigned char* b1 = Bm + (size_t)(n0 + row1) * DSZ + og1 * 16;

#define STGL(tt, bufb) do { \
    GLD16(a0 + (size_t)(tt) * 64, SM + (bufb) + wave * 1024); \
    GLD16(a1 + (size_t)(tt) * 64, SM + (bufb) + 4096 + wave * 1024); \
    GLD16(b0 + (size_t)(tt) * 64, SM + (bufb) + 8192 + wave * 1024); \
    GLD16(b1 + (size_t)(tt) * 64, SM + (bufb) + 12288 + wave * 1024); \
  } while (0)

  STGL(0, 0);
  STGL(1, 16384);
  int cb = 0;
  for (int t = 0; t < 16; ++t) {
    if (t + 2 < 16) {
      int nb = cb + 32768; if (nb >= 49152) nb -= 49152;
      STGL(t + 2, nb);
      asm volatile("s_waitcnt vmcnt(8)" ::: "memory");
    } else if (t + 1 < 16) {
      asm volatile("s_waitcnt vmcnt(4)" ::: "memory");
    } else {
      asm volatile("s_waitcnt vmcnt(0)" ::: "memory");
    }
    __builtin_amdgcn_s_barrier();
    asm volatile("" ::: "memory");
    // fragment = 32B of k per lane: pairs {2hi, 2hi+1} at rotated positions
    i32x8 a8[2], b8[2];
#pragma unroll
    for (int mf = 0; mf < 2; ++mf) {
      const int row = wr + mf * 32 + l31;
      const char* base = SM + cb + row * 64;
      const int ph0 = (2 * hi + (row >> 1)) & 3;
      const int ph1 = (2 * hi + 1 + (row >> 1)) & 3;
      i32x4 q01 = *(const i32x4*)(base + ph0 * 16);
      i32x4 q23 = *(const i32x4*)(base + ph1 * 16);
      a8[mf] = __builtin_shufflevector(q01, q23, 0, 1, 2, 3, 4, 5, 6, 7);
    }
#pragma unroll
    for (int nf = 0; nf < 2; ++nf) {
      const int row = wc + nf * 32 + l31;
      const char* base = SM + cb + 8192 + row * 64;
      const int ph0 = (2 * hi + (row >> 1)) & 3;
      const int ph1 = (2 * hi + 1 + (row >> 1)) & 3;
      i32x4 q01 = *(const i32x4*)(base + ph0 * 16);
      i32x4 q23 = *(const i32x4*)(base + ph1 * 16);
      b8[nf] = __builtin_shufflevector(q01, q23, 0, 1, 2, 3, 4, 5, 6, 7);
    }
    asm volatile("s_waitcnt lgkmcnt(0)" ::: "memory");
    __builtin_amdgcn_sched_barrier(0);
    __builtin_amdgcn_s_setprio(1);
#pragma unroll
    for (int mf = 0; mf < 2; ++mf)
#pragma unroll
      for (int nf = 0; nf < 2; ++nf)
        acc[mf][nf] = __builtin_amdgcn_mfma_scale_f32_32x32x64_f8f6f4(
            a8[mf], b8[nf], acc[mf][nf], 0, 0, 0, 123, 0, 123);
    __builtin_amdgcn_s_setprio(0);
    __builtin_amdgcn_s_barrier();
    asm volatile("" ::: "memory");
    cb += 16384; if (cb >= 49152) cb = 0;
  }
#undef STGL

  // ---- fused softmax partials: wave's 64 v-rows = stripe ch
  // C/D: col = l31, row = (reg&3) + 8*(reg>>2) + 4*hi
  const int ch = (m0 + wr) >> 6;
#pragma unroll
  for (int nf = 0; nf < 2; ++nf) {
    const int pos = n0 + wc + nf * 32 + l31;
    float mloc = -1e30f, sloc = 0.f;
#pragma unroll
    for (int mf = 0; mf < 2; ++mf) {
      const int vb = m0 + wr + mf * 32 + 4 * hi;
#pragma unroll
      for (int r = 0; r < 16; ++r) {
        const int v = vb + (r & 3) + 8 * (r >> 2);
        if (v < VSZ) mloc = fmaxf(mloc, acc[mf][nf][r]);
      }
    }
#pragma unroll
    for (int mf = 0; mf < 2; ++mf) {
      const int vb = m0 + wr + mf * 32 + 4 * hi;
#pragma unroll
      for (int r = 0; r < 16; ++r) {
        const int v = vb + (r & 3) + 8 * (r >> 2);
        if (v < VSZ) sloc += __expf(acc[mf][nf][r] - mloc);
      }
    }
    {
      float mo = __shfl_xor(mloc, 32, 64);
      float so = __shfl_xor(sloc, 32, 64);
      float nm = fmaxf(mloc, mo);
      sloc = sloc * __expf(mloc - nm) + so * __expf(mo - nm);
      mloc = nm;
    }
    if (hi == 0) {
      pm[(size_t)ch * NPOS + pos] = mloc;
      ps[(size_t)ch * NPOS + pos] = sloc;
    }
  }

  // ---- 2-pass dual-region LDS restage + aligned NT stores.
  // Pass p: wave-pair wp writes its mf=p quarter into region wp (2 x [32][132]);
  // quarter index q = wp*2 + p -> global rows m0 + q*32 .. +31.
  float* epi = (float*)SM;                 // 2 x 32 x 132 f32 = 33.8 KB
  const int bb = n0 >> 9, t0 = n0 & 511;
  float* outG = outF + 1 + (size_t)bb * VSZ * TSZ + t0;
  const int trow = tid >> 5;
  const int lofs = (tid & 31) * 4;
#pragma unroll
  for (int p = 0; p < 2; ++p) {
    __builtin_amdgcn_s_barrier();
    asm volatile("" ::: "memory");
    {
      const int rg = wave >> 1;
#pragma unroll
      for (int nf = 0; nf < 2; ++nf)
#pragma unroll
        for (int r = 0; r < 16; ++r)
          epi[rg * 4224 + ((r & 3) + 8 * (r >> 2) + 4 * hi) * 132 + wc + nf * 32 + l31] =
              acc[p][nf][r];
    }
    __builtin_amdgcn_s_barrier();
    asm volatile("" ::: "memory");
#pragma unroll
    for (int rg = 0; rg < 2; ++rg) {
      const int q = rg * 2 + p;
#pragma unroll
      for (int pp = 0; pp < 4; ++pp) {
        int row = pp * 8 + trow;
        int v = m0 + q * 32 + row;
        if (v < VSZ) {
          f32x4 val = *(const f32x4*)&epi[rg * 4224 + row * 132 + lofs];
          float* gp = outG + (size_t)v * TSZ + lofs;
          __builtin_nontemporal_store(val[0], gp + 0);
          __builtin_nontemporal_store(val[1], gp + 1);
          __builtin_nontemporal_store(val[2], gp + 2);
          __builtin_nontemporal_store(val[3], gp + 3);
        }
      }
    }
  }
}

// -------- loss stage 1: merge 25-chunk groups (256 blocks = full GPU)
__global__ __launch_bounds__(256) void lsestage1_kernel(const float* __restrict__ pm,
                                                        const float* __restrict__ ps,
                                                        float* __restrict__ pm2,
                                                        float* __restrict__ ps2) {
  int pos = (blockIdx.x & 7) * 256 + threadIdx.x;
  int cg = blockIdx.x >> 3;
  int c0 = cg * CPC;
  int c1 = c0 + CPC; if (c1 > NCH) c1 = NCH;
  float m = -1e30f, s = 0.f;
  for (int c = c0; c < c1; ++c) {
    float cm = pm[(size_t)c * NPOS + pos];
    float cs = ps[(size_t)c * NPOS + pos];
    float nm = fmaxf(m, cm);
    s = s * __expf(m - nm) + cs * __expf(cm - nm);
    m = nm;
  }
  pm2[(size_t)cg * NPOS + pos] = m;
  ps2[(size_t)cg * NPOS + pos] = s;
}

// -------- loss stage 2: merge 32 groups per position, gather label logit
__global__ __launch_bounds__(256) void lsemerge_kernel(const float* __restrict__ pm2,
                                                       const float* __restrict__ ps2,
                                                       const float* __restrict__ outF,
                                                       const int* __restrict__ labels,
                                                       float* __restrict__ contrib) {
  int pos = blockIdx.x * 256 + threadIdx.x;
  float m[4] = {-1e30f, -1e30f, -1e30f, -1e30f};
  float s[4] = {0.f, 0.f, 0.f, 0.f};
  for (int c = 0; c < CG; c += 4) {
#pragma unroll
    for (int j = 0; j < 4; ++j) {
      float cm = pm2[(size_t)(c + j) * NPOS + pos];
      float cs = ps2[(size_t)(c + j) * NPOS + pos];
      float nm = fmaxf(m[j], cm);
      s[j] = s[j] * __expf(m[j] - nm) + cs * __expf(cm - nm);
      m[j] = nm;
    }
  }
#pragma unroll
  for (int j = 1; j < 4; ++j) {
    float nm = fmaxf(m[0], m[j]);
    s[0] = s[0] * __expf(m[0] - nm) + s[j] * __expf(m[j] - nm);
    m[0] = nm;
  }
  float lse = m[0] + logf(s[0]);
  int b = pos >> 9, t = pos & 511;
  int lab = labels[pos];
  float x = outF[1 + (size_t)b * VSZ * TSZ + (size_t)lab * TSZ + t];
  contrib[pos] = lse - x;
}

__global__ __launch_bounds__(256) void lossfinal_kernel(const float* __restrict__ contrib,
                                                        float* __restrict__ dout) {
  __shared__ float red[256];
  int tid = threadIdx.x;
  float a = 0.f;
  for (int i = tid; i < NPOS; i += 256) a += contrib[i];
  red[tid] = a;
  __syncthreads();
  for (int off = 128; off; off >>= 1) {
    if (tid < off) red[tid] += red[tid + off];
    __syncthreads();
  }
  if (tid == 0) dout[0] = red[0] / (float)NPOS;
}

extern "C" void kernel_launch(void* const* d_in, const int* in_sizes, int n_in,
                              void* d_out, int out_size, void* d_ws, size_t ws_size,
                              hipStream_t stream) {
  const int* input_ids = (const int*)d_in[0];
  const int* labels    = (const int*)d_in[1];
  const float* wte     = (const float*)d_in[2];
  const float* enc_w1  = (const float*)d_in[3];
  const float* enc_b1  = (const float*)d_in[4];
  const float* enc_w2  = (const float*)d_in[5];
  const float* enc_b2  = (const float*)d_in[6];
  const float* proj_w  = (const float*)d_in[7];
  const float* proj_b  = (const float*)d_in[8];
  const float* dec_w1  = (const float*)d_in[9];
  const float* dec_b1  = (const float*)d_in[10];
  const float* dec_w2  = (const float*)d_in[11];
  const float* dec_b2  = (const float*)d_in[12];
  const float* lm_w    = (const float*)d_in[13];
  float* outF = (float*)d_out;

  char* w = (char*)d_ws;
  size_t off = 0;
  unsigned char* lm8  = (unsigned char*)(w + off); off += (size_t)VPAD * DSZ;   // 51.6 MB
  unsigned char* w18  = (unsigned char*)(w + off); off += (size_t)HSZ * DSZ;    // 4 MB
  unsigned char* w28  = (unsigned char*)(w + off); off += (size_t)DSZ * HSZ;    // 4 MB
  unsigned char* p8   = (unsigned char*)(w + off); off += (size_t)DSZ * 512;    // 0.5 MB
  unsigned char* win8 = (unsigned char*)(w + off); off += (size_t)NPOS * 512;   // 1 MB
  unsigned char* pbuf8= (unsigned char*)(w + off); off += (size_t)NPOS * DSZ;   // 2 MB
  unsigned char* abuf8= (unsigned char*)(w + off); off += (size_t)NPOS * HSZ;   // 8 MB
  unsigned char* dbuf8= (unsigned char*)(w + off); off += (size_t)NPOS * DSZ;   // 2 MB
  float* e      = (float*)(w + off);  off += (size_t)BSZ * DSZ * 4;
  float* t1p    = (float*)(w + off);  off += (size_t)BSZ * KS1 * HSZ * 4;
  float* ep     = (float*)(w + off);  off += (size_t)BSZ * KS2 * DSZ * 4;
  float* contrib= (float*)(w + off);  off += (size_t)NPOS * 4;
  float* pm     = (float*)(w + off);  off += (size_t)NCH * NPOS * 4;            // 6.5 MB
  float* ps     = (float*)(w + off);  off += (size_t)NCH * NPOS * 4;            // 6.5 MB
  float* pm2    = (float*)(w + off);  off += (size_t)CG * NPOS * 4;             // 256 KB
  float* ps2    = (float*)(w + off);  off += (size_t)CG * NPOS * 4;             // 256 KB
  (void)ws_size; (void)in_sizes; (void)n_in; (void)out_size;

  // all weight transposes in one dispatch (all -> fp8 x16)
  transpose_all<<<14784, 256, 0, stream>>>(lm_w, dec_w1, dec_w2, proj_w, lm8, w18, w28, p8);

  // encoder on last token only (4-batch weight reuse)
  enc1p_kernel<<<dim3(HSZ / 256, KS1), 256, 0, stream>>>(input_ids, wte, enc_w1, t1p);
  enc2p_kernel<<<dim3(DSZ / 256, KS2), 256, 0, stream>>>(t1p, enc_b1, enc_w2, ep);
  enc2c_kernel<<<dim3(BSZ * DSZ / 256), 256, 0, stream>>>(ep, enc_b2, e);
  win8_kernel<<<2048, 256, 0, stream>>>(e, win8);

  // fp8 GEMM chain (1D grids, all divisible by 8 for the XCD swizzle)
  gemm8<0><<<128, 256, 0, stream>>>(win8, p8, proj_b, pbuf8, 8, DSZ, 512);
  gemm8<1><<<512, 256, 0, stream>>>(pbuf8, w18, dec_b1, abuf8, 32, HSZ, DSZ);
  gemm8<0><<<128, 256, 0, stream>>>(abuf8, w28, dec_b2, dbuf8, 8, DSZ, HSZ);
  // lm head MX-fp8: 394 m-tiles x 16 n-tiles = 6304 blocks
  gemmLM<<<6304, 256, 0, stream>>>(lm8, dbuf8, outF, pm, ps);

  // loss: two-stage merge + mean
  lsestage1_kernel<<<256, 256, 0, stream>>>(pm, ps, pm2, ps2);
  lsemerge_kernel<<<dim3(NPOS / 256), 256, 0, stream>>>(pm2, ps2, outF, labels, contrib);
  lossfinal_kernel<<<1, 256, 0, stream>>>(contrib, outF);
}

// Round 14
// 388.796 us; speedup vs baseline: 1.3444x; 1.0255x over previous
//
#include <hip/hip_runtime.h>

#define VSZ 50257
#define DSZ 1024
#define TSZ 512
#define BSZ 4
#define HSZ 4096
#define VPAD 50432   // 394*128
#define NCH (VPAD / 64)   // 788 v-stripes of 64
#define NPOS 2048
#define QS 16.0f
#define DQS (1.0f / 256.0f)
#define CG 64        // stage-1 chunk groups
#define CPC 13       // chunks per group (64*13 = 832 >= 788)

typedef __attribute__((ext_vector_type(4))) float f32x4;
typedef __attribute__((ext_vector_type(16))) float f32x16;
typedef __attribute__((ext_vector_type(4))) int i32x4;
typedef __attribute__((ext_vector_type(8))) int i32x8;

#define GLD16(gp, lp) __builtin_amdgcn_global_load_lds( \
  (const __attribute__((address_space(1))) unsigned int*)(gp), \
  (__attribute__((address_space(3))) unsigned int*)(lp), 16, 0, 0)

__device__ __forceinline__ float gelu_f(float x) {
  float x3 = x * x * x;
  float u = 0.7978845608028654f * (x + 0.044715f * x3);
  return 0.5f * x * (1.f + tanhf(u));
}

__device__ __forceinline__ unsigned char q8(float v) {
  return (unsigned char)__builtin_amdgcn_cvt_pk_fp8_f32(v * QS, v * QS, 0, 0);
}

// -------- fused: all weight transposes (f32 -> fp8 x16) + enc1 partials.
// Blocks 0..14783: transposes (64x64 tiles). Blocks 14784..14911: enc1p.
#define KS1 8
#define KS2 16
__global__ __launch_bounds__(256) void transpose_all(
    const float* __restrict__ lm_w, const float* __restrict__ dw1,
    const float* __restrict__ dw2, const float* __restrict__ pw,
    unsigned char* __restrict__ lm8, unsigned char* __restrict__ w18,
    unsigned char* __restrict__ w28, unsigned char* __restrict__ p8,
    const int* __restrict__ ids, const float* __restrict__ wte,
    const float* __restrict__ w1, float* __restrict__ t1p) {
  __shared__ float tile[64][65];
  int bid = blockIdx.x;
  int tid = threadIdx.x;

  if (bid >= 14784) {
    // ---- enc1 partials: all 4 batch rows, K-chunk kc of 128 dims
    int eb = bid - 14784;
    int h = (eb & 15) * 256 + tid;
    int kc = eb >> 4;
    float (*ev)[128] = (float(*)[128])tile;
    for (int i = tid; i < 512; i += 256) {
      int b = i >> 7, d = i & 127;
      int tok = ids[b * TSZ + (TSZ - 1)];
      ev[b][d] = wte[(size_t)tok * DSZ + kc * 128 + d];
    }
    __syncthreads();
    const float* w = w1 + (size_t)(kc * 128) * HSZ + h;
    float s0 = 0.f, s1 = 0.f, s2 = 0.f, s3 = 0.f;
#pragma unroll 4
    for (int d = 0; d < 128; ++d) {
      float wv = w[(size_t)d * HSZ];
      s0 += ev[0][d] * wv; s1 += ev[1][d] * wv;
      s2 += ev[2][d] * wv; s3 += ev[3][d] * wv;
    }
    t1p[((size_t)(0 * KS1 + kc)) * HSZ + h] = s0;
    t1p[((size_t)(1 * KS1 + kc)) * HSZ + h] = s1;
    t1p[((size_t)(2 * KS1 + kc)) * HSZ + h] = s2;
    t1p[((size_t)(3 * KS1 + kc)) * HSZ + h] = s3;
    return;
  }

  const float* src; unsigned char* dst; int R, C, Cpad, bx, by;
  if (bid < 12608)      { src = lm_w; dst = lm8; R = DSZ; C = VSZ; Cpad = VPAD; bx = bid % 788; by = bid / 788; }
  else if (bid < 13632) { int b = bid - 12608; src = dw1; dst = w18; R = DSZ; C = HSZ; Cpad = HSZ; bx = b % 64; by = b / 64; }
  else if (bid < 14656) { int b = bid - 13632; src = dw2; dst = w28; R = HSZ; C = DSZ; Cpad = DSZ; bx = b % 16; by = b / 16; }
  else                  { int b = bid - 14656; src = pw;  dst = p8;  R = 512; C = DSZ; Cpad = DSZ; bx = b % 16; by = b / 16; }
  int c0 = bx * 64, r0 = by * 64;
  int wv = tid >> 6, ln = tid & 63;
  int c = c0 + ln;
#pragma unroll 4
  for (int i = 0; i < 16; ++i) {
    int r = i * 4 + wv;
    tile[r][ln] = (c < C) ? src[(size_t)(r0 + r) * C + c] : 0.f;
  }
  __syncthreads();
  int ccb = tid >> 4;
  int r4 = (tid & 15) * 4;
#pragma unroll
  for (int j = 0; j < 4; ++j) {
    int cc = ccb + j * 16;
    if (c0 + cc >= Cpad) continue;
    unsigned int u = __builtin_amdgcn_cvt_pk_fp8_f32(QS * tile[r4 + 0][cc], QS * tile[r4 + 1][cc], 0, 0);
    u = __builtin_amdgcn_cvt_pk_fp8_f32(QS * tile[r4 + 2][cc], QS * tile[r4 + 3][cc], u, 1);
    *(unsigned int*)(dst + (size_t)(c0 + cc) * R + r0 + r4) = u;
  }
}

// -------- encoder layer 2 partials: all 4 batch rows per block (w2 read once)
__global__ __launch_bounds__(256) void enc2p_kernel(const float* __restrict__ t1p,
                                                    const float* __restrict__ b1,
                                                    const float* __restrict__ w2,
                                                    float* __restrict__ ep) {
  __shared__ float ts[4][256];
  int i = blockIdx.x * 256 + threadIdx.x;
  int kc = blockIdx.y;
  int h = kc * 256 + threadIdx.x;
  float bv = b1[h];
#pragma unroll
  for (int b = 0; b < 4; ++b) {
    float s0 = bv;
#pragma unroll
    for (int cc = 0; cc < KS1; ++cc) s0 += t1p[((size_t)(b * KS1 + cc)) * HSZ + h];
    ts[b][threadIdx.x] = gelu_f(s0);
  }
  __syncthreads();
  const float* w = w2 + (size_t)(kc * 256) * DSZ + i;
  float a0 = 0.f, a1 = 0.f, a2 = 0.f, a3 = 0.f;
#pragma unroll 4
  for (int j = 0; j < 256; ++j) {
    float wv = w[(size_t)j * DSZ];
    a0 += ts[0][j] * wv; a1 += ts[1][j] * wv;
    a2 += ts[2][j] * wv; a3 += ts[3][j] * wv;
  }
  ep[((size_t)(0 * KS2 + kc)) * DSZ + i] = a0;
  ep[((size_t)(1 * KS2 + kc)) * DSZ + i] = a1;
  ep[((size_t)(2 * KS2 + kc)) * DSZ + i] = a2;
  ep[((size_t)(3 * KS2 + kc)) * DSZ + i] = a3;
}

// -------- windows (enc2 combine fused): win8[b*T+t][j] = fp8((b2[t+j] + sum ep)*16)
__global__ __launch_bounds__(256) void win8_kernel(const float* __restrict__ ep,
                                                   const float* __restrict__ b2,
                                                   unsigned char* __restrict__ win8) {
  int blk = blockIdx.x;
  int b = blk >> 9, t = blk & 511;
  const float* epb = ep + (size_t)b * KS2 * DSZ;
  for (int j = threadIdx.x; j < 512; j += 256) {
    int d = t + j;                      // < 1024 always
    float s = b2[d];
#pragma unroll
    for (int kc = 0; kc < KS2; ++kc) s += epb[(size_t)kc * DSZ + d];
    win8[(size_t)blk * 512 + j] = q8(s);
  }
}

// -------- mid fp8 GEMM (proj/dec1/dec2): 16x16x32 fp8, 128x128 tile, BK=64,
// 3-buffer ring, depth-2 prefetch, 16B-pair rotation (unchanged, proven).
template<int GELU>
__global__ __launch_bounds__(256, 3) void gemm8(
    const unsigned char* __restrict__ A, const unsigned char* __restrict__ Bm,
    const float* __restrict__ bias, unsigned char* __restrict__ out8,
    int NT, int N, int K) {
  __shared__ __align__(16) char SM[49152];
  const int tid = threadIdx.x;
  const int lane = tid & 63;
  const int wave = tid >> 6;
  const int wr = (wave >> 1) * 64, wc = (wave & 1) * 64;
  const int l15 = lane & 15, l4 = lane >> 4;

  const int cpx = (int)gridDim.x >> 3;
  const int wg = ((int)blockIdx.x & 7) * cpx + ((int)blockIdx.x >> 3);
  const int m0 = (wg / NT) * 128, n0 = (wg % NT) * 128;

  f32x4 acc[4][4];
#pragma unroll
  for (int i = 0; i < 4; ++i)
#pragma unroll
    for (int j = 0; j < 4; ++j) acc[i][j] = (f32x4){0.f, 0.f, 0.f, 0.f};

  const int ppair = lane & 3;
  const int row0 = wave * 16 + (lane >> 2);
  const int row1 = row0 + 64;
  const int og0 = (ppair - (row0 >> 1)) & 3;
  const int og1 = (ppair - (row1 >> 1)) & 3;
  const unsigned char* a0 = A + (size_t)(m0 + row0) * K + og0 * 16;
  const unsigned char* a1 = A + (size_t)(m0 + row1) * K + og1 * 16;
  const unsigned char* b0 = Bm + (size_t)(n0 + row0) * K + og0 * 16;
  const unsigned char* b1 = Bm + (size_t)(n0 + row1) * K + og1 * 16;

#define STG8(tt, bufb) do { \
    GLD16(a0 + (size_t)(tt) * 64, SM + (bufb) + wave * 1024); \
    GLD16(a1 + (size_t)(tt) * 64, SM + (bufb) + 4096 + wave * 1024); \
    GLD16(b0 + (size_t)(tt) * 64, SM + (bufb) + 8192 + wave * 1024); \
    GLD16(b1 + (size_t)(tt) * 64, SM + (bufb) + 12288 + wave * 1024); \
  } while (0)

  const int KT = K >> 6;
  STG8(0, 0);
  if (KT > 1) STG8(1, 16384);
  int cb = 0;
  for (int t = 0; t < KT; ++t) {
    if (t + 2 < KT) {
      int nb = cb + 32768; if (nb >= 49152) nb -= 49152;
      STG8(t + 2, nb);
      asm volatile("s_waitcnt vmcnt(8)" ::: "memory");
    } else if (t + 1 < KT) {
      asm volatile("s_waitcnt vmcnt(4)" ::: "memory");
    } else {
      asm volatile("s_waitcnt vmcnt(0)" ::: "memory");
    }
    __builtin_amdgcn_s_barrier();
    asm volatile("" ::: "memory");
    long af[4][2], bfr[4][2];
#pragma unroll
    for (int mi = 0; mi < 4; ++mi) {
      const int row = wr + mi * 16 + l15;
#pragma unroll
      for (int kk = 0; kk < 2; ++kk) {
        const int ph = ((kk * 2 + (l4 >> 1)) + (row >> 1)) & 3;
        af[mi][kk] = *(const long*)(SM + cb + row * 64 + ph * 16 + (l4 & 1) * 8);
      }
    }
#pragma unroll
    for (int ni = 0; ni < 4; ++ni) {
      const int row = wc + ni * 16 + l15;
#pragma unroll
      for (int kk = 0; kk < 2; ++kk) {
        const int ph = ((kk * 2 + (l4 >> 1)) + (row >> 1)) & 3;
        bfr[ni][kk] = *(const long*)(SM + cb + 8192 + row * 64 + ph * 16 + (l4 & 1) * 8);
      }
    }
    asm volatile("s_waitcnt lgkmcnt(0)" ::: "memory");
    __builtin_amdgcn_sched_barrier(0);
    __builtin_amdgcn_s_setprio(1);
#pragma unroll
    for (int kk = 0; kk < 2; ++kk)
#pragma unroll
      for (int mi = 0; mi < 4; ++mi)
#pragma unroll
        for (int ni = 0; ni < 4; ++ni)
          acc[mi][ni] = __builtin_amdgcn_mfma_f32_16x16x32_fp8_fp8(
              af[mi][kk], bfr[ni][kk], acc[mi][ni], 0, 0, 0);
    __builtin_amdgcn_s_setprio(0);
    __builtin_amdgcn_s_barrier();
    asm volatile("" ::: "memory");
    cb += 16384; if (cb >= 49152) cb = 0;
  }
#undef STG8

#pragma unroll
  for (int ni = 0; ni < 4; ++ni) {
    int n = n0 + wc + ni * 16 + l15;
    float bv = bias[n];
#pragma unroll
    for (int mi = 0; mi < 4; ++mi) {
#pragma unroll
      for (int r = 0; r < 4; ++r) {
        int m = m0 + wr + mi * 16 + l4 * 4 + r;
        float v = acc[mi][ni][r] * DQS + bv;
        if (GELU) v = gelu_f(v);
        out8[(size_t)m * N + n] = q8(v);
      }
    }
  }
}

// -------- lm-head MX-fp8 GEMM: mfma_scale 32x32x64 (2x fp8 rate), 128x128 tile,
// BK=64, 3-buffer ring depth-2, proven rotation LDS layout. E8M0 scales = 123
// (2^-4 each) fold in the 1/256 dequant. Epilogue: fused softmax partials +
// 2-pass dual-region LDS restage (4 barriers) + aligned f32x4 NT stores.
__global__ __launch_bounds__(256, 3) void gemmLM(
    const unsigned char* __restrict__ A, const unsigned char* __restrict__ Bm,
    float* __restrict__ outF, float* __restrict__ pm, float* __restrict__ ps) {
  __shared__ __align__(16) char SM[49152];
  const int tid = threadIdx.x;
  const int lane = tid & 63;
  const int wave = tid >> 6;
  const int wr = (wave >> 1) * 64, wc = (wave & 1) * 64;
  const int l31 = lane & 31, hi = lane >> 5;

  const int cpx = (int)gridDim.x >> 3;
  const int wg = ((int)blockIdx.x & 7) * cpx + ((int)blockIdx.x >> 3);
  const int m0 = (wg >> 4) * 128, n0 = (wg & 15) * 128;

  f32x16 acc[2][2];
#pragma unroll
  for (int i = 0; i < 2; ++i)
#pragma unroll
    for (int j = 0; j < 2; ++j)
#pragma unroll
      for (int r = 0; r < 16; ++r) acc[i][j][r] = 0.f;

  // staging: rotation layout (linear LDS dest, inverse-rotated global src)
  const int ppair = lane & 3;
  const int row0 = wave * 16 + (lane >> 2);
  const int row1 = row0 + 64;
  const int og0 = (ppair - (row0 >> 1)) & 3;
  const int og1 = (ppair - (row1 >> 1)) & 3;
  const unsigned char* a0 = A + (size_t)(m0 + row0) * DSZ + og0 * 16;
  const unsigned char* a1 = A + (size_t)(m0 + row1) * DSZ + og1 * 16;
  const unsigned char* b0 = Bm + (size_t)(n0 + row0) * DSZ + og0 * 16;
  const unsigned char* b1 = Bm + (size_t)(n0 + row1) * DSZ + og1 * 16;

#define STGL(tt, bufb) do { \
    GLD16(a0 + (size_t)(tt) * 64, SM + (bufb) + wave * 1024); \
    GLD16(a1 + (size_t)(tt) * 64, SM + (bufb) + 4096 + wave * 1024); \
    GLD16(b0 + (size_t)(tt) * 64, SM + (bufb) + 8192 + wave * 1024); \
    GLD16(b1 + (size_t)(tt) * 64, SM + (bufb) + 12288 + wave * 1024); \
  } while (0)

  STGL(0, 0);
  STGL(1, 16384);
  int cb = 0;
  for (int t = 0; t < 16; ++t) {
    if (t + 2 < 16) {
      int nb = cb + 32768; if (nb >= 49152) nb -= 49152;
      STGL(t + 2, nb);
      asm volatile("s_waitcnt vmcnt(8)" ::: "memory");
    } else if (t + 1 < 16) {
      asm volatile("s_waitcnt vmcnt(4)" ::: "memory");
    } else {
      asm volatile("s_waitcnt vmcnt(0)" ::: "memory");
    }
    __builtin_amdgcn_s_barrier();
    asm volatile("" ::: "memory");
    // fragment = 32B of k per lane: pairs {2hi, 2hi+1} at rotated positions
    i32x8 a8[2], b8[2];
#pragma unroll
    for (int mf = 0; mf < 2; ++mf) {
      const int row = wr + mf * 32 + l31;
      const char* base = SM + cb + row * 64;
      const int ph0 = (2 * hi + (row >> 1)) & 3;
      const int ph1 = (2 * hi + 1 + (row >> 1)) & 3;
      i32x4 q01 = *(const i32x4*)(base + ph0 * 16);
      i32x4 q23 = *(const i32x4*)(base + ph1 * 16);
      a8[mf] = __builtin_shufflevector(q01, q23, 0, 1, 2, 3, 4, 5, 6, 7);
    }
#pragma unroll
    for (int nf = 0; nf < 2; ++nf) {
      const int row = wc + nf * 32 + l31;
      const char* base = SM + cb + 8192 + row * 64;
      const int ph0 = (2 * hi + (row >> 1)) & 3;
      const int ph1 = (2 * hi + 1 + (row >> 1)) & 3;
      i32x4 q01 = *(const i32x4*)(base + ph0 * 16);
      i32x4 q23 = *(const i32x4*)(base + ph1 * 16);
      b8[nf] = __builtin_shufflevector(q01, q23, 0, 1, 2, 3, 4, 5, 6, 7);
    }
    asm volatile("s_waitcnt lgkmcnt(0)" ::: "memory");
    __builtin_amdgcn_sched_barrier(0);
    __builtin_amdgcn_s_setprio(1);
#pragma unroll
    for (int mf = 0; mf < 2; ++mf)
#pragma unroll
      for (int nf = 0; nf < 2; ++nf)
        acc[mf][nf] = __builtin_amdgcn_mfma_scale_f32_32x32x64_f8f6f4(
            a8[mf], b8[nf], acc[mf][nf], 0, 0, 0, 123, 0, 123);
    __builtin_amdgcn_s_setprio(0);
    __builtin_amdgcn_s_barrier();
    asm volatile("" ::: "memory");
    cb += 16384; if (cb >= 49152) cb = 0;
  }
#undef STGL

  // ---- fused softmax partials: wave's 64 v-rows = stripe ch
  // C/D: col = l31, row = (reg&3) + 8*(reg>>2) + 4*hi
  const int ch = (m0 + wr) >> 6;
#pragma unroll
  for (int nf = 0; nf < 2; ++nf) {
    const int pos = n0 + wc + nf * 32 + l31;
    float mloc = -1e30f, sloc = 0.f;
#pragma unroll
    for (int mf = 0; mf < 2; ++mf) {
      const int vb = m0 + wr + mf * 32 + 4 * hi;
#pragma unroll
      for (int r = 0; r < 16; ++r) {
        const int v = vb + (r & 3) + 8 * (r >> 2);
        if (v < VSZ) mloc = fmaxf(mloc, acc[mf][nf][r]);
      }
    }
#pragma unroll
    for (int mf = 0; mf < 2; ++mf) {
      const int vb = m0 + wr + mf * 32 + 4 * hi;
#pragma unroll
      for (int r = 0; r < 16; ++r) {
        const int v = vb + (r & 3) + 8 * (r >> 2);
        if (v < VSZ) sloc += __expf(acc[mf][nf][r] - mloc);
      }
    }
    {
      float mo = __shfl_xor(mloc, 32, 64);
      float so = __shfl_xor(sloc, 32, 64);
      float nm = fmaxf(mloc, mo);
      sloc = sloc * __expf(mloc - nm) + so * __expf(mo - nm);
      mloc = nm;
    }
    if (hi == 0) {
      pm[(size_t)ch * NPOS + pos] = mloc;
      ps[(size_t)ch * NPOS + pos] = sloc;
    }
  }

  // ---- 2-pass dual-region LDS restage + aligned NT stores.
  float* epi = (float*)SM;                 // 2 x 32 x 132 f32 = 33.8 KB
  const int bb = n0 >> 9, t0 = n0 & 511;
  float* outG = outF + 1 + (size_t)bb * VSZ * TSZ + t0;
  const int trow = tid >> 5;
  const int lofs = (tid & 31) * 4;
#pragma unroll
  for (int p = 0; p < 2; ++p) {
    __builtin_amdgcn_s_barrier();
    asm volatile("" ::: "memory");
    {
      const int rg = wave >> 1;
#pragma unroll
      for (int nf = 0; nf < 2; ++nf)
#pragma unroll
        for (int r = 0; r < 16; ++r)
          epi[rg * 4224 + ((r & 3) + 8 * (r >> 2) + 4 * hi) * 132 + wc + nf * 32 + l31] =
              acc[p][nf][r];
    }
    __builtin_amdgcn_s_barrier();
    asm volatile("" ::: "memory");
#pragma unroll
    for (int rg = 0; rg < 2; ++rg) {
      const int q = rg * 2 + p;
#pragma unroll
      for (int pp = 0; pp < 4; ++pp) {
        int row = pp * 8 + trow;
        int v = m0 + q * 32 + row;
        if (v < VSZ) {
          f32x4 val = *(const f32x4*)&epi[rg * 4224 + row * 132 + lofs];
          float* gp = outG + (size_t)v * TSZ + lofs;
          __builtin_nontemporal_store(val[0], gp + 0);
          __builtin_nontemporal_store(val[1], gp + 1);
          __builtin_nontemporal_store(val[2], gp + 2);
          __builtin_nontemporal_store(val[3], gp + 3);
        }
      }
    }
  }
}

// -------- loss stage 1: merge 13-chunk groups (512 blocks, 2/CU)
__global__ __launch_bounds__(256) void lsestage1_kernel(const float* __restrict__ pm,
                                                        const float* __restrict__ ps,
                                                        float* __restrict__ pm2,
                                                        float* __restrict__ ps2) {
  int pos = (blockIdx.x & 7) * 256 + threadIdx.x;
  int cg = blockIdx.x >> 3;
  int c0 = cg * CPC;
  int c1 = c0 + CPC; if (c1 > NCH) c1 = NCH;
  float m = -1e30f, s = 0.f;
  for (int c = c0; c < c1; ++c) {
    float cm = pm[(size_t)c * NPOS + pos];
    float cs = ps[(size_t)c * NPOS + pos];
    float nm = fmaxf(m, cm);
    s = s * __expf(m - nm) + cs * __expf(cm - nm);
    m = nm;
  }
  pm2[(size_t)cg * NPOS + pos] = m;
  ps2[(size_t)cg * NPOS + pos] = s;
}

// -------- loss stage 2: merge 64 groups per position, gather label logit
__global__ __launch_bounds__(256) void lsemerge_kernel(const float* __restrict__ pm2,
                                                       const float* __restrict__ ps2,
                                                       const float* __restrict__ outF,
                                                       const int* __restrict__ labels,
                                                       float* __restrict__ contrib) {
  int pos = blockIdx.x * 256 + threadIdx.x;
  float m[4] = {-1e30f, -1e30f, -1e30f, -1e30f};
  float s[4] = {0.f, 0.f, 0.f, 0.f};
  for (int c = 0; c < CG; c += 4) {
#pragma unroll
    for (int j = 0; j < 4; ++j) {
      float cm = pm2[(size_t)(c + j) * NPOS + pos];
      float cs = ps2[(size_t)(c + j) * NPOS + pos];
      float nm = fmaxf(m[j], cm);
      s[j] = s[j] * __expf(m[j] - nm) + cs * __expf(cm - nm);
      m[j] = nm;
    }
  }
#pragma unroll
  for (int j = 1; j < 4; ++j) {
    float nm = fmaxf(m[0], m[j]);
    s[0] = s[0] * __expf(m[0] - nm) + s[j] * __expf(m[j] - nm);
    m[0] = nm;
  }
  float lse = m[0] + logf(s[0]);
  int b = pos >> 9, t = pos & 511;
  int lab = labels[pos];
  float x = outF[1 + (size_t)b * VSZ * TSZ + (size_t)lab * TSZ + t];
  contrib[pos] = lse - x;
}

__global__ __launch_bounds__(256) void lossfinal_kernel(const float* __restrict__ contrib,
                                                        float* __restrict__ dout) {
  __shared__ float red[256];
  int tid = threadIdx.x;
  float a = 0.f;
  for (int i = tid; i < NPOS; i += 256) a += contrib[i];
  red[tid] = a;
  __syncthreads();
  for (int off = 128; off; off >>= 1) {
    if (tid < off) red[tid] += red[tid + off];
    __syncthreads();
  }
  if (tid == 0) dout[0] = red[0] / (float)NPOS;
}

extern "C" void kernel_launch(void* const* d_in, const int* in_sizes, int n_in,
                              void* d_out, int out_size, void* d_ws, size_t ws_size,
                              hipStream_t stream) {
  const int* input_ids = (const int*)d_in[0];
  const int* labels    = (const int*)d_in[1];
  const float* wte     = (const float*)d_in[2];
  const float* enc_w1  = (const float*)d_in[3];
  const float* enc_b1  = (const float*)d_in[4];
  const float* enc_w2  = (const float*)d_in[5];
  const float* enc_b2  = (const float*)d_in[6];
  const float* proj_w  = (const float*)d_in[7];
  const float* proj_b  = (const float*)d_in[8];
  const float* dec_w1  = (const float*)d_in[9];
  const float* dec_b1  = (const float*)d_in[10];
  const float* dec_w2  = (const float*)d_in[11];
  const float* dec_b2  = (const float*)d_in[12];
  const float* lm_w    = (const float*)d_in[13];
  float* outF = (float*)d_out;

  char* w = (char*)d_ws;
  size_t off = 0;
  unsigned char* lm8  = (unsigned char*)(w + off); off += (size_t)VPAD * DSZ;   // 51.6 MB
  unsigned char* w18  = (unsigned char*)(w + off); off += (size_t)HSZ * DSZ;    // 4 MB
  unsigned char* w28  = (unsigned char*)(w + off); off += (size_t)DSZ * HSZ;    // 4 MB
  unsigned char* p8   = (unsigned char*)(w + off); off += (size_t)DSZ * 512;    // 0.5 MB
  unsigned char* win8 = (unsigned char*)(w + off); off += (size_t)NPOS * 512;   // 1 MB
  unsigned char* pbuf8= (unsigned char*)(w + off); off += (size_t)NPOS * DSZ;   // 2 MB
  unsigned char* abuf8= (unsigned char*)(w + off); off += (size_t)NPOS * HSZ;   // 8 MB
  unsigned char* dbuf8= (unsigned char*)(w + off); off += (size_t)NPOS * DSZ;   // 2 MB
  float* t1p    = (float*)(w + off);  off += (size_t)BSZ * KS1 * HSZ * 4;
  float* ep     = (float*)(w + off);  off += (size_t)BSZ * KS2 * DSZ * 4;
  float* contrib= (float*)(w + off);  off += (size_t)NPOS * 4;
  float* pm     = (float*)(w + off);  off += (size_t)NCH * NPOS * 4;            // 6.5 MB
  float* ps     = (float*)(w + off);  off += (size_t)NCH * NPOS * 4;            // 6.5 MB
  float* pm2    = (float*)(w + off);  off += (size_t)CG * NPOS * 4;             // 512 KB
  float* ps2    = (float*)(w + off);  off += (size_t)CG * NPOS * 4;             // 512 KB
  (void)ws_size; (void)in_sizes; (void)n_in; (void)out_size;

  // weight transposes + enc1 partials in one dispatch
  transpose_all<<<14912, 256, 0, stream>>>(lm_w, dec_w1, dec_w2, proj_w,
                                           lm8, w18, w28, p8,
                                           input_ids, wte, enc_w1, t1p);

  // encoder layer 2 + windows (enc2 combine fused into win8)
  enc2p_kernel<<<dim3(DSZ / 256, KS2), 256, 0, stream>>>(t1p, enc_b1, enc_w2, ep);
  win8_kernel<<<2048, 256, 0, stream>>>(ep, enc_b2, win8);

  // fp8 GEMM chain (1D grids, all divisible by 8 for the XCD swizzle)
  gemm8<0><<<128, 256, 0, stream>>>(win8, p8, proj_b, pbuf8, 8, DSZ, 512);
  gemm8<1><<<512, 256, 0, stream>>>(pbuf8, w18, dec_b1, abuf8, 32, HSZ, DSZ);
  gemm8<0><<<128, 256, 0, stream>>>(abuf8, w28, dec_b2, dbuf8, 8, DSZ, HSZ);
  // lm head MX-fp8: 394 m-tiles x 16 n-tiles = 6304 blocks
  gemmLM<<<6304, 256, 0, stream>>>(lm8, dbuf8, outF, pm, ps);

  // loss: two-stage merge + mean
  lsestage1_kernel<<<512, 256, 0, stream>>>(pm, ps, pm2, ps2);
  lsemerge_kernel<<<dim3(NPOS / 256), 256, 0, stream>>>(pm2, ps2, outF, labels, contrib);
  lossfinal_kernel<<<1, 256, 0, stream>>>(contrib, outF);
}

// Round 16
// 384.576 us; speedup vs baseline: 1.3592x; 1.0110x over previous
//
#include <hip/hip_runtime.h>

#define VSZ 50257
#define DSZ 1024
#define TSZ 512
#define BSZ 4
#define HSZ 4096
#define VPAD 50432   // 394*128
#define NCH (VPAD / 64)   // 788 v-stripes of 64
#define NPOS 2048
#define QS 16.0f
#define DQS (1.0f / 256.0f)
#define CG 64        // stage-1 chunk groups
#define CPC 13       // chunks per group (64*13 = 832 >= 788)

typedef __attribute__((ext_vector_type(4))) float f32x4;
typedef __attribute__((ext_vector_type(16))) float f32x16;
typedef __attribute__((ext_vector_type(4))) int i32x4;
typedef __attribute__((ext_vector_type(8))) int i32x8;

#define GLD16(gp, lp) __builtin_amdgcn_global_load_lds( \
  (const __attribute__((address_space(1))) unsigned int*)(gp), \
  (__attribute__((address_space(3))) unsigned int*)(lp), 16, 0, 0)

__device__ __forceinline__ float gelu_f(float x) {
  float x3 = x * x * x;
  float u = 0.7978845608028654f * (x + 0.044715f * x3);
  return 0.5f * x * (1.f + tanhf(u));
}

__device__ __forceinline__ unsigned char q8(float v) {
  return (unsigned char)__builtin_amdgcn_cvt_pk_fp8_f32(v * QS, v * QS, 0, 0);
}

// -------- fused: all weight transposes (f32 -> fp8 x16) + enc1 partials.
// Blocks 0..14783: transposes (64x64 tiles). Blocks 14784..14911: enc1p.
#define KS1 8
#define KS2 16
__global__ __launch_bounds__(256) void transpose_all(
    const float* __restrict__ lm_w, const float* __restrict__ dw1,
    const float* __restrict__ dw2, const float* __restrict__ pw,
    unsigned char* __restrict__ lm8, unsigned char* __restrict__ w18,
    unsigned char* __restrict__ w28, unsigned char* __restrict__ p8,
    const int* __restrict__ ids, const float* __restrict__ wte,
    const float* __restrict__ w1, float* __restrict__ t1p) {
  __shared__ float tile[64][65];
  int bid = blockIdx.x;
  int tid = threadIdx.x;

  if (bid >= 14784) {
    // ---- enc1 partials: all 4 batch rows, K-chunk kc of 128 dims
    int eb = bid - 14784;
    int h = (eb & 15) * 256 + tid;
    int kc = eb >> 4;
    float (*ev)[128] = (float(*)[128])tile;
    for (int i = tid; i < 512; i += 256) {
      int b = i >> 7, d = i & 127;
      int tok = ids[b * TSZ + (TSZ - 1)];
      ev[b][d] = wte[(size_t)tok * DSZ + kc * 128 + d];
    }
    __syncthreads();
    const float* w = w1 + (size_t)(kc * 128) * HSZ + h;
    float s0 = 0.f, s1 = 0.f, s2 = 0.f, s3 = 0.f;
#pragma unroll 4
    for (int d = 0; d < 128; ++d) {
      float wv = w[(size_t)d * HSZ];
      s0 += ev[0][d] * wv; s1 += ev[1][d] * wv;
      s2 += ev[2][d] * wv; s3 += ev[3][d] * wv;
    }
    t1p[((size_t)(0 * KS1 + kc)) * HSZ + h] = s0;
    t1p[((size_t)(1 * KS1 + kc)) * HSZ + h] = s1;
    t1p[((size_t)(2 * KS1 + kc)) * HSZ + h] = s2;
    t1p[((size_t)(3 * KS1 + kc)) * HSZ + h] = s3;
    return;
  }

  const float* src; unsigned char* dst; int R, C, Cpad, bx, by;
  if (bid < 12608)      { src = lm_w; dst = lm8; R = DSZ; C = VSZ; Cpad = VPAD; bx = bid % 788; by = bid / 788; }
  else if (bid < 13632) { int b = bid - 12608; src = dw1; dst = w18; R = DSZ; C = HSZ; Cpad = HSZ; bx = b % 64; by = b / 64; }
  else if (bid < 14656) { int b = bid - 13632; src = dw2; dst = w28; R = HSZ; C = DSZ; Cpad = DSZ; bx = b % 16; by = b / 16; }
  else                  { int b = bid - 14656; src = pw;  dst = p8;  R = 512; C = DSZ; Cpad = DSZ; bx = b % 16; by = b / 16; }
  int c0 = bx * 64, r0 = by * 64;
  int wv = tid >> 6, ln = tid & 63;
  int c = c0 + ln;
#pragma unroll 4
  for (int i = 0; i < 16; ++i) {
    int r = i * 4 + wv;
    tile[r][ln] = (c < C) ? src[(size_t)(r0 + r) * C + c] : 0.f;
  }
  __syncthreads();
  int ccb = tid >> 4;
  int r4 = (tid & 15) * 4;
#pragma unroll
  for (int j = 0; j < 4; ++j) {
    int cc = ccb + j * 16;
    if (c0 + cc >= Cpad) continue;
    unsigned int u = __builtin_amdgcn_cvt_pk_fp8_f32(QS * tile[r4 + 0][cc], QS * tile[r4 + 1][cc], 0, 0);
    u = __builtin_amdgcn_cvt_pk_fp8_f32(QS * tile[r4 + 2][cc], QS * tile[r4 + 3][cc], u, 1);
    *(unsigned int*)(dst + (size_t)(c0 + cc) * R + r0 + r4) = u;
  }
}

// -------- encoder layer 2 partials: all 4 batch rows per block (w2 read once)
__global__ __launch_bounds__(256) void enc2p_kernel(const float* __restrict__ t1p,
                                                    const float* __restrict__ b1,
                                                    const float* __restrict__ w2,
                                                    float* __restrict__ ep) {
  __shared__ float ts[4][256];
  int i = blockIdx.x * 256 + threadIdx.x;
  int kc = blockIdx.y;
  int h = kc * 256 + threadIdx.x;
  float bv = b1[h];
#pragma unroll
  for (int b = 0; b < 4; ++b) {
    float s0 = bv;
#pragma unroll
    for (int cc = 0; cc < KS1; ++cc) s0 += t1p[((size_t)(b * KS1 + cc)) * HSZ + h];
    ts[b][threadIdx.x] = gelu_f(s0);
  }
  __syncthreads();
  const float* w = w2 + (size_t)(kc * 256) * DSZ + i;
  float a0 = 0.f, a1 = 0.f, a2 = 0.f, a3 = 0.f;
#pragma unroll 4
  for (int j = 0; j < 256; ++j) {
    float wv = w[(size_t)j * DSZ];
    a0 += ts[0][j] * wv; a1 += ts[1][j] * wv;
    a2 += ts[2][j] * wv; a3 += ts[3][j] * wv;
  }
  ep[((size_t)(0 * KS2 + kc)) * DSZ + i] = a0;
  ep[((size_t)(1 * KS2 + kc)) * DSZ + i] = a1;
  ep[((size_t)(2 * KS2 + kc)) * DSZ + i] = a2;
  ep[((size_t)(3 * KS2 + kc)) * DSZ + i] = a3;
}

// -------- windows (enc2 combine fused): win8[b*T+t][j] = fp8((b2[t+j] + sum ep)*16)
__global__ __launch_bounds__(256) void win8_kernel(const float* __restrict__ ep,
                                                   const float* __restrict__ b2,
                                                   unsigned char* __restrict__ win8) {
  int blk = blockIdx.x;
  int b = blk >> 9, t = blk & 511;
  const float* epb = ep + (size_t)b * KS2 * DSZ;
  for (int j = threadIdx.x; j < 512; j += 256) {
    int d = t + j;                      // < 1024 always
    float s = b2[d];
#pragma unroll
    for (int kc = 0; kc < KS2; ++kc) s += epb[(size_t)kc * DSZ + d];
    win8[(size_t)blk * 512 + j] = q8(s);
  }
}

// -------- mid fp8 GEMM (proj/dec1/dec2): 16x16x32 fp8, 128x128 tile, BK=64,
// 3-buffer ring, depth-2 prefetch, 16B-pair rotation, ONE barrier per K-step.
// vmcnt ledger: end-of-step-t outstanding = tiles {t+1, t+2} -> vmcnt(4)
// guarantees tile t+1 landed (t+2's 4 loads may remain in flight).
template<int GELU>
__global__ __launch_bounds__(256, 3) void gemm8(
    const unsigned char* __restrict__ A, const unsigned char* __restrict__ Bm,
    const float* __restrict__ bias, unsigned char* __restrict__ out8,
    int NT, int N, int K) {
  __shared__ __align__(16) char SM[49152];
  const int tid = threadIdx.x;
  const int lane = tid & 63;
  const int wave = tid >> 6;
  const int wr = (wave >> 1) * 64, wc = (wave & 1) * 64;
  const int l15 = lane & 15, l4 = lane >> 4;

  const int cpx = (int)gridDim.x >> 3;
  const int wg = ((int)blockIdx.x & 7) * cpx + ((int)blockIdx.x >> 3);
  const int m0 = (wg / NT) * 128, n0 = (wg % NT) * 128;

  f32x4 acc[4][4];
#pragma unroll
  for (int i = 0; i < 4; ++i)
#pragma unroll
    for (int j = 0; j < 4; ++j) acc[i][j] = (f32x4){0.f, 0.f, 0.f, 0.f};

  const int ppair = lane & 3;
  const int row0 = wave * 16 + (lane >> 2);
  const int row1 = row0 + 64;
  const int og0 = (ppair - (row0 >> 1)) & 3;
  const int og1 = (ppair - (row1 >> 1)) & 3;
  const unsigned char* a0 = A + (size_t)(m0 + row0) * K + og0 * 16;
  const unsigned char* a1 = A + (size_t)(m0 + row1) * K + og1 * 16;
  const unsigned char* b0 = Bm + (size_t)(n0 + row0) * K + og0 * 16;
  const unsigned char* b1 = Bm + (size_t)(n0 + row1) * K + og1 * 16;

#define STG8(tt, bufb) do { \
    GLD16(a0 + (size_t)(tt) * 64, SM + (bufb) + wave * 1024); \
    GLD16(a1 + (size_t)(tt) * 64, SM + (bufb) + 4096 + wave * 1024); \
    GLD16(b0 + (size_t)(tt) * 64, SM + (bufb) + 8192 + wave * 1024); \
    GLD16(b1 + (size_t)(tt) * 64, SM + (bufb) + 12288 + wave * 1024); \
  } while (0)

  const int KT = K >> 6;
  STG8(0, 0);
  STG8(1, 16384);
  asm volatile("s_waitcnt vmcnt(4)" ::: "memory");   // tile 0 landed; tile 1 in flight
  __builtin_amdgcn_s_barrier();
  asm volatile("" ::: "memory");
  int cb = 0;
  for (int t = 0; t < KT; ++t) {
    if (t + 2 < KT) {
      int nb = cb + 32768; if (nb >= 49152) nb -= 49152;
      STG8(t + 2, nb);
    }
    long af[4][2], bfr[4][2];
#pragma unroll
    for (int mi = 0; mi < 4; ++mi) {
      const int row = wr + mi * 16 + l15;
#pragma unroll
      for (int kk = 0; kk < 2; ++kk) {
        const int ph = ((kk * 2 + (l4 >> 1)) + (row >> 1)) & 3;
        af[mi][kk] = *(const long*)(SM + cb + row * 64 + ph * 16 + (l4 & 1) * 8);
      }
    }
#pragma unroll
    for (int ni = 0; ni < 4; ++ni) {
      const int row = wc + ni * 16 + l15;
#pragma unroll
      for (int kk = 0; kk < 2; ++kk) {
        const int ph = ((kk * 2 + (l4 >> 1)) + (row >> 1)) & 3;
        bfr[ni][kk] = *(const long*)(SM + cb + 8192 + row * 64 + ph * 16 + (l4 & 1) * 8);
      }
    }
    asm volatile("s_waitcnt lgkmcnt(0)" ::: "memory");
    __builtin_amdgcn_sched_barrier(0);
    __builtin_amdgcn_s_setprio(1);
#pragma unroll
    for (int kk = 0; kk < 2; ++kk)
#pragma unroll
      for (int mi = 0; mi < 4; ++mi)
#pragma unroll
        for (int ni = 0; ni < 4; ++ni)
          acc[mi][ni] = __builtin_amdgcn_mfma_f32_16x16x32_fp8_fp8(
              af[mi][kk], bfr[ni][kk], acc[mi][ni], 0, 0, 0);
    __builtin_amdgcn_s_setprio(0);
    // single end-of-step sync: tile t+1 landed for all waves; prev buffer released
    if (t + 2 < KT) {
      asm volatile("s_waitcnt vmcnt(4)" ::: "memory");
      __builtin_amdgcn_s_barrier();
      asm volatile("" ::: "memory");
    } else if (t + 1 < KT) {
      asm volatile("s_waitcnt vmcnt(0)" ::: "memory");
      __builtin_amdgcn_s_barrier();
      asm volatile("" ::: "memory");
    }
    cb += 16384; if (cb >= 49152) cb = 0;
  }
#undef STG8

#pragma unroll
  for (int ni = 0; ni < 4; ++ni) {
    int n = n0 + wc + ni * 16 + l15;
    float bv = bias[n];
#pragma unroll
    for (int mi = 0; mi < 4; ++mi) {
#pragma unroll
      for (int r = 0; r < 4; ++r) {
        int m = m0 + wr + mi * 16 + l4 * 4 + r;
        float v = acc[mi][ni][r] * DQS + bv;
        if (GELU) v = gelu_f(v);
        out8[(size_t)m * N + n] = q8(v);
      }
    }
  }
}

// -------- lm-head MX-fp8 GEMM: mfma_scale 32x32x64 (2x fp8 rate), 128x128 tile,
// BK=64, 3-buffer ring depth-2, rotation LDS layout, ONE barrier per K-step
// (vmcnt(4) ledger as gemm8). E8M0 scales = 123 (2^-4 each) fold in the 1/256
// dequant. Epilogue: fused softmax partials + 2-pass dual-region LDS restage.
__global__ __launch_bounds__(256, 3) void gemmLM(
    const unsigned char* __restrict__ A, const unsigned char* __restrict__ Bm,
    float* __restrict__ outF, float* __restrict__ pm, float* __restrict__ ps) {
  __shared__ __align__(16) char SM[49152];
  const int tid = threadIdx.x;
  const int lane = tid & 63;
  const int wave = tid >> 6;
  const int wr = (wave >> 1) * 64, wc = (wave & 1) * 64;
  const int l31 = lane & 31, hi = lane >> 5;

  const int cpx = (int)gridDim.x >> 3;
  const int wg = ((int)blockIdx.x & 7) * cpx + ((int)blockIdx.x >> 3);
  const int m0 = (wg >> 4) * 128, n0 = (wg & 15) * 128;

  f32x16 acc[2][2];
#pragma unroll
  for (int i = 0; i < 2; ++i)
#pragma unroll
    for (int j = 0; j < 2; ++j)
#pragma unroll
      for (int r = 0; r < 16; ++r) acc[i][j][r] = 0.f;

  // staging: rotation layout (linear LDS dest, inverse-rotated global src)
  const int ppair = lane & 3;
  const int row0 = wave * 16 + (lane >> 2);
  const int row1 = row0 + 64;
  const int og0 = (ppair - (row0 >> 1)) & 3;
  const int og1 = (ppair - (row1 >> 1)) & 3;
  const unsigned char* a0 = A + (size_t)(m0 + row0) * DSZ + og0 * 16;
  const unsigned char* a1 = A + (size_t)(m0 + row1) * DSZ + og1 * 16;
  const unsigned char* b0 = Bm + (size_t)(n0 + row0) * DSZ + og0 * 16;
  const unsigned char* b1 = Bm + (size_t)(n0 + row1) * DSZ + og1 * 16;

#define STGL(tt, bufb) do { \
    GLD16(a0 + (size_t)(tt) * 64, SM + (bufb) + wave * 1024); \
    GLD16(a1 + (size_t)(tt) * 64, SM + (bufb) + 4096 + wave * 1024); \
    GLD16(b0 + (size_t)(tt) * 64, SM + (bufb) + 8192 + wave * 1024); \
    GLD16(b1 + (size_t)(tt) * 64, SM + (bufb) + 12288 + wave * 1024); \
  } while (0)

  STGL(0, 0);
  STGL(1, 16384);
  asm volatile("s_waitcnt vmcnt(4)" ::: "memory");   // tile 0 landed; tile 1 in flight
  __builtin_amdgcn_s_barrier();
  asm volatile("" ::: "memory");
  int cb = 0;
  for (int t = 0; t < 16; ++t) {
    if (t + 2 < 16) {
      int nb = cb + 32768; if (nb >= 49152) nb -= 49152;
      STGL(t + 2, nb);
    }
    // fragment = 32B of k per lane: pairs {2hi, 2hi+1} at rotated positions
    i32x8 a8[2], b8[2];
#pragma unroll
    for (int mf = 0; mf < 2; ++mf) {
      const int row = wr + mf * 32 + l31;
      const char* base = SM + cb + row * 64;
      const int ph0 = (2 * hi + (row >> 1)) & 3;
      const int ph1 = (2 * hi + 1 + (row >> 1)) & 3;
      i32x4 q01 = *(const i32x4*)(base + ph0 * 16);
      i32x4 q23 = *(const i32x4*)(base + ph1 * 16);
      a8[mf] = __builtin_shufflevector(q01, q23, 0, 1, 2, 3, 4, 5, 6, 7);
    }
#pragma unroll
    for (int nf = 0; nf < 2; ++nf) {
      const int row = wc + nf * 32 + l31;
      const char* base = SM + cb + 8192 + row * 64;
      const int ph0 = (2 * hi + (row >> 1)) & 3;
      const int ph1 = (2 * hi + 1 + (row >> 1)) & 3;
      i32x4 q01 = *(const i32x4*)(base + ph0 * 16);
      i32x4 q23 = *(const i32x4*)(base + ph1 * 16);
      b8[nf] = __builtin_shufflevector(q01, q23, 0, 1, 2, 3, 4, 5, 6, 7);
    }
    asm volatile("s_waitcnt lgkmcnt(0)" ::: "memory");
    __builtin_amdgcn_sched_barrier(0);
    __builtin_amdgcn_s_setprio(1);
#pragma unroll
    for (int mf = 0; mf < 2; ++mf)
#pragma unroll
      for (int nf = 0; nf < 2; ++nf)
        acc[mf][nf] = __builtin_amdgcn_mfma_scale_f32_32x32x64_f8f6f4(
            a8[mf], b8[nf], acc[mf][nf], 0, 0, 0, 123, 0, 123);
    __builtin_amdgcn_s_setprio(0);
    // single end-of-step sync
    if (t + 2 < 16) {
      asm volatile("s_waitcnt vmcnt(4)" ::: "memory");
      __builtin_amdgcn_s_barrier();
      asm volatile("" ::: "memory");
    } else if (t + 1 < 16) {
      asm volatile("s_waitcnt vmcnt(0)" ::: "memory");
      __builtin_amdgcn_s_barrier();
      asm volatile("" ::: "memory");
    }
    cb += 16384; if (cb >= 49152) cb = 0;
  }
#undef STGL

  // ---- fused softmax partials: wave's 64 v-rows = stripe ch
  // C/D: col = l31, row = (reg&3) + 8*(reg>>2) + 4*hi
  const int ch = (m0 + wr) >> 6;
#pragma unroll
  for (int nf = 0; nf < 2; ++nf) {
    const int pos = n0 + wc + nf * 32 + l31;
    float mloc = -1e30f, sloc = 0.f;
#pragma unroll
    for (int mf = 0; mf < 2; ++mf) {
      const int vb = m0 + wr + mf * 32 + 4 * hi;
#pragma unroll
      for (int r = 0; r < 16; ++r) {
        const int v = vb + (r & 3) + 8 * (r >> 2);
        if (v < VSZ) mloc = fmaxf(mloc, acc[mf][nf][r]);
      }
    }
#pragma unroll
    for (int mf = 0; mf < 2; ++mf) {
      const int vb = m0 + wr + mf * 32 + 4 * hi;
#pragma unroll
      for (int r = 0; r < 16; ++r) {
        const int v = vb + (r & 3) + 8 * (r >> 2);
        if (v < VSZ) sloc += __expf(acc[mf][nf][r] - mloc);
      }
    }
    {
      float mo = __shfl_xor(mloc, 32, 64);
      float so = __shfl_xor(sloc, 32, 64);
      float nm = fmaxf(mloc, mo);
      sloc = sloc * __expf(mloc - nm) + so * __expf(mo - nm);
      mloc = nm;
    }
    if (hi == 0) {
      pm[(size_t)ch * NPOS + pos] = mloc;
      ps[(size_t)ch * NPOS + pos] = sloc;
    }
  }

  // ---- 2-pass dual-region LDS restage + aligned NT stores.
  float* epi = (float*)SM;                 // 2 x 32 x 132 f32 = 33.8 KB
  const int bb = n0 >> 9, t0 = n0 & 511;
  float* outG = outF + 1 + (size_t)bb * VSZ * TSZ + t0;
  const int trow = tid >> 5;
  const int lofs = (tid & 31) * 4;
#pragma unroll
  for (int p = 0; p < 2; ++p) {
    __builtin_amdgcn_s_barrier();
    asm volatile("" ::: "memory");
    {
      const int rg = wave >> 1;
#pragma unroll
      for (int nf = 0; nf < 2; ++nf)
#pragma unroll
        for (int r = 0; r < 16; ++r)
          epi[rg * 4224 + ((r & 3) + 8 * (r >> 2) + 4 * hi) * 132 + wc + nf * 32 + l31] =
              acc[p][nf][r];
    }
    __builtin_amdgcn_s_barrier();
    asm volatile("" ::: "memory");
#pragma unroll
    for (int rg = 0; rg < 2; ++rg) {
      const int q = rg * 2 + p;
#pragma unroll
      for (int pp = 0; pp < 4; ++pp) {
        int row = pp * 8 + trow;
        int v = m0 + q * 32 + row;
        if (v < VSZ) {
          f32x4 val = *(const f32x4*)&epi[rg * 4224 + row * 132 + lofs];
          float* gp = outG + (size_t)v * TSZ + lofs;
          __builtin_nontemporal_store(val[0], gp + 0);
          __builtin_nontemporal_store(val[1], gp + 1);
          __builtin_nontemporal_store(val[2], gp + 2);
          __builtin_nontemporal_store(val[3], gp + 3);
        }
      }
    }
  }
}

// -------- loss stage 1: merge 13-chunk groups (512 blocks, 2/CU)
__global__ __launch_bounds__(256) void lsestage1_kernel(const float* __restrict__ pm,
                                                        const float* __restrict__ ps,
                                                        float* __restrict__ pm2,
                                                        float* __restrict__ ps2) {
  int pos = (blockIdx.x & 7) * 256 + threadIdx.x;
  int cg = blockIdx.x >> 3;
  int c0 = cg * CPC;
  int c1 = c0 + CPC; if (c1 > NCH) c1 = NCH;
  float m = -1e30f, s = 0.f;
  for (int c = c0; c < c1; ++c) {
    float cm = pm[(size_t)c * NPOS + pos];
    float cs = ps[(size_t)c * NPOS + pos];
    float nm = fmaxf(m, cm);
    s = s * __expf(m - nm) + cs * __expf(cm - nm);
    m = nm;
  }
  pm2[(size_t)cg * NPOS + pos] = m;
  ps2[(size_t)cg * NPOS + pos] = s;
}

// -------- loss stage 2: merge 64 groups per position, gather label logit
__global__ __launch_bounds__(256) void lsemerge_kernel(const float* __restrict__ pm2,
                                                       const float* __restrict__ ps2,
                                                       const float* __restrict__ outF,
                                                       const int* __restrict__ labels,
                                                       float* __restrict__ contrib) {
  int pos = blockIdx.x * 256 + threadIdx.x;
  float m[4] = {-1e30f, -1e30f, -1e30f, -1e30f};
  float s[4] = {0.f, 0.f, 0.f, 0.f};
  for (int c = 0; c < CG; c += 4) {
#pragma unroll
    for (int j = 0; j < 4; ++j) {
      float cm = pm2[(size_t)(c + j) * NPOS + pos];
      float cs = ps2[(size_t)(c + j) * NPOS + pos];
      float nm = fmaxf(m[j], cm);
      s[j] = s[j] * __expf(m[j] - nm) + cs * __expf(cm - nm);
      m[j] = nm;
    }
  }
#pragma unroll
  for (int j = 1; j < 4; ++j) {
    float nm = fmaxf(m[0], m[j]);
    s[0] = s[0] * __expf(m[0] - nm) + s[j] * __expf(m[j] - nm);
    m[0] = nm;
  }
  float lse = m[0] + logf(s[0]);
  int b = pos >> 9, t = pos & 511;
  int lab = labels[pos];
  float x = outF[1 + (size_t)b * VSZ * TSZ + (size_t)lab * TSZ + t];
  contrib[pos] = lse - x;
}

__global__ __launch_bounds__(256) void lossfinal_kernel(const float* __restrict__ contrib,
                                                        float* __restrict__ dout) {
  __shared__ float red[256];
  int tid = threadIdx.x;
  float a = 0.f;
  for (int i = tid; i < NPOS; i += 256) a += contrib[i];
  red[tid] = a;
  __syncthreads();
  for (int off = 128; off; off >>= 1) {
    if (tid < off) red[tid] += red[tid + off];
    __syncthreads();
  }
  if (tid == 0) dout[0] = red[0] / (float)NPOS;
}

extern "C" void kernel_launch(void* const* d_in, const int* in_sizes, int n_in,
                              void* d_out, int out_size, void* d_ws, size_t ws_size,
                              hipStream_t stream) {
  const int* input_ids = (const int*)d_in[0];
  const int* labels    = (const int*)d_in[1];
  const float* wte     = (const float*)d_in[2];
  const float* enc_w1  = (const float*)d_in[3];
  const float* enc_b1  = (const float*)d_in[4];
  const float* enc_w2  = (const float*)d_in[5];
  const float* enc_b2  = (const float*)d_in[6];
  const float* proj_w  = (const float*)d_in[7];
  const float* proj_b  = (const float*)d_in[8];
  const float* dec_w1  = (const float*)d_in[9];
  const float* dec_b1  = (const float*)d_in[10];
  const float* dec_w2  = (const float*)d_in[11];
  const float* dec_b2  = (const float*)d_in[12];
  const float* lm_w    = (const float*)d_in[13];
  float* outF = (float*)d_out;

  char* w = (char*)d_ws;
  size_t off = 0;
  unsigned char* lm8  = (unsigned char*)(w + off); off += (size_t)VPAD * DSZ;   // 51.6 MB
  unsigned char* w18  = (unsigned char*)(w + off); off += (size_t)HSZ * DSZ;    // 4 MB
  unsigned char* w28  = (unsigned char*)(w + off); off += (size_t)DSZ * HSZ;    // 4 MB
  unsigned char* p8   = (unsigned char*)(w + off); off += (size_t)DSZ * 512;    // 0.5 MB
  unsigned char* win8 = (unsigned char*)(w + off); off += (size_t)NPOS * 512;   // 1 MB
  unsigned char* pbuf8= (unsigned char*)(w + off); off += (size_t)NPOS * DSZ;   // 2 MB
  unsigned char* abuf8= (unsigned char*)(w + off); off += (size_t)NPOS * HSZ;   // 8 MB
  unsigned char* dbuf8= (unsigned char*)(w + off); off += (size_t)NPOS * DSZ;   // 2 MB
  float* t1p    = (float*)(w + off);  off += (size_t)BSZ * KS1 * HSZ * 4;
  float* ep     = (float*)(w + off);  off += (size_t)BSZ * KS2 * DSZ * 4;
  float* contrib= (float*)(w + off);  off += (size_t)NPOS * 4;
  float* pm     = (float*)(w + off);  off += (size_t)NCH * NPOS * 4;            // 6.5 MB
  float* ps     = (float*)(w + off);  off += (size_t)NCH * NPOS * 4;            // 6.5 MB
  float* pm2    = (float*)(w + off);  off += (size_t)CG * NPOS * 4;             // 512 KB
  float* ps2    = (float*)(w + off);  off += (size_t)CG * NPOS * 4;             // 512 KB
  (void)ws_size; (void)in_sizes; (void)n_in; (void)out_size;

  // weight transposes + enc1 partials in one dispatch
  transpose_all<<<14912, 256, 0, stream>>>(lm_w, dec_w1, dec_w2, proj_w,
                                           lm8, w18, w28, p8,
                                           input_ids, wte, enc_w1, t1p);

  // encoder layer 2 + windows (enc2 combine fused into win8)
  enc2p_kernel<<<dim3(DSZ / 256, KS2), 256, 0, stream>>>(t1p, enc_b1, enc_w2, ep);
  win8_kernel<<<2048, 256, 0, stream>>>(ep, enc_b2, win8);

  // fp8 GEMM chain (1D grids, all divisible by 8 for the XCD swizzle)
  gemm8<0><<<128, 256, 0, stream>>>(win8, p8, proj_b, pbuf8, 8, DSZ, 512);
  gemm8<1><<<512, 256, 0, stream>>>(pbuf8, w18, dec_b1, abuf8, 32, HSZ, DSZ);
  gemm8<0><<<128, 256, 0, stream>>>(abuf8, w28, dec_b2, dbuf8, 8, DSZ, HSZ);
  // lm head MX-fp8: 394 m-tiles x 16 n-tiles = 6304 blocks
  gemmLM<<<6304, 256, 0, stream>>>(lm8, dbuf8, outF, pm, ps);

  // loss: two-stage merge + mean
  lsestage1_kernel<<<512, 256, 0, stream>>>(pm, ps, pm2, ps2);
  lsemerge_kernel<<<dim3(NPOS / 256), 256, 0, stream>>>(pm2, ps2, outF, labels, contrib);
  lossfinal_kernel<<<1, 256, 0, stream>>>(contrib, outF);
}

// Round 17
// 368.273 us; speedup vs baseline: 1.4194x; 1.0443x over previous
//
#include <hip/hip_runtime.h>

#define VSZ 50257
#define DSZ 1024
#define TSZ 512
#define BSZ 4
#define HSZ 4096
#define VPAD 50432   // 394*128
#define NCH (VPAD / 64)   // 788 v-stripes of 64
#define NPOS 2048
#define QS 16.0f
#define DQS (1.0f / 256.0f)
#define CG 64        // stage-1 chunk groups
#define CPC 13       // chunks per group (64*13 = 832 >= 788)

typedef __attribute__((ext_vector_type(4))) float f32x4;
typedef __attribute__((ext_vector_type(16))) float f32x16;
typedef __attribute__((ext_vector_type(4))) int i32x4;
typedef __attribute__((ext_vector_type(8))) int i32x8;

#define GLD16(gp, lp) __builtin_amdgcn_global_load_lds( \
  (const __attribute__((address_space(1))) unsigned int*)(gp), \
  (__attribute__((address_space(3))) unsigned int*)(lp), 16, 0, 0)

__device__ __forceinline__ float gelu_f(float x) {
  float x3 = x * x * x;
  float u = 0.7978845608028654f * (x + 0.044715f * x3);
  return 0.5f * x * (1.f + tanhf(u));
}

__device__ __forceinline__ unsigned char q8(float v) {
  return (unsigned char)__builtin_amdgcn_cvt_pk_fp8_f32(v * QS, v * QS, 0, 0);
}

// -------- fused: all weight transposes (f32 -> fp8 x16) + enc1 partials.
// Blocks 0..14783: transposes (64x64 tiles). Blocks 14784..14911: enc1p.
#define KS1 8
#define KS2 16
__global__ __launch_bounds__(256) void transpose_all(
    const float* __restrict__ lm_w, const float* __restrict__ dw1,
    const float* __restrict__ dw2, const float* __restrict__ pw,
    unsigned char* __restrict__ lm8, unsigned char* __restrict__ w18,
    unsigned char* __restrict__ w28, unsigned char* __restrict__ p8,
    const int* __restrict__ ids, const float* __restrict__ wte,
    const float* __restrict__ w1, float* __restrict__ t1p) {
  __shared__ float tile[64][65];
  int bid = blockIdx.x;
  int tid = threadIdx.x;

  if (bid >= 14784) {
    // ---- enc1 partials: all 4 batch rows, K-chunk kc of 128 dims
    int eb = bid - 14784;
    int h = (eb & 15) * 256 + tid;
    int kc = eb >> 4;
    float (*ev)[128] = (float(*)[128])tile;
    for (int i = tid; i < 512; i += 256) {
      int b = i >> 7, d = i & 127;
      int tok = ids[b * TSZ + (TSZ - 1)];
      ev[b][d] = wte[(size_t)tok * DSZ + kc * 128 + d];
    }
    __syncthreads();
    const float* w = w1 + (size_t)(kc * 128) * HSZ + h;
    float s0 = 0.f, s1 = 0.f, s2 = 0.f, s3 = 0.f;
#pragma unroll 4
    for (int d = 0; d < 128; ++d) {
      float wv = w[(size_t)d * HSZ];
      s0 += ev[0][d] * wv; s1 += ev[1][d] * wv;
      s2 += ev[2][d] * wv; s3 += ev[3][d] * wv;
    }
    t1p[((size_t)(0 * KS1 + kc)) * HSZ + h] = s0;
    t1p[((size_t)(1 * KS1 + kc)) * HSZ + h] = s1;
    t1p[((size_t)(2 * KS1 + kc)) * HSZ + h] = s2;
    t1p[((size_t)(3 * KS1 + kc)) * HSZ + h] = s3;
    return;
  }

  const float* src; unsigned char* dst; int R, C, Cpad, bx, by;
  if (bid < 12608)      { src = lm_w; dst = lm8; R = DSZ; C = VSZ; Cpad = VPAD; bx = bid % 788; by = bid / 788; }
  else if (bid < 13632) { int b = bid - 12608; src = dw1; dst = w18; R = DSZ; C = HSZ; Cpad = HSZ; bx = b % 64; by = b / 64; }
  else if (bid < 14656) { int b = bid - 13632; src = dw2; dst = w28; R = HSZ; C = DSZ; Cpad = DSZ; bx = b % 16; by = b / 16; }
  else                  { int b = bid - 14656; src = pw;  dst = p8;  R = 512; C = DSZ; Cpad = DSZ; bx = b % 16; by = b / 16; }
  int c0 = bx * 64, r0 = by * 64;
  int wv = tid >> 6, ln = tid & 63;
  int c = c0 + ln;
#pragma unroll 4
  for (int i = 0; i < 16; ++i) {
    int r = i * 4 + wv;
    tile[r][ln] = (c < C) ? src[(size_t)(r0 + r) * C + c] : 0.f;
  }
  __syncthreads();
  int ccb = tid >> 4;
  int r4 = (tid & 15) * 4;
#pragma unroll
  for (int j = 0; j < 4; ++j) {
    int cc = ccb + j * 16;
    if (c0 + cc >= Cpad) continue;
    unsigned int u = __builtin_amdgcn_cvt_pk_fp8_f32(QS * tile[r4 + 0][cc], QS * tile[r4 + 1][cc], 0, 0);
    u = __builtin_amdgcn_cvt_pk_fp8_f32(QS * tile[r4 + 2][cc], QS * tile[r4 + 3][cc], u, 1);
    *(unsigned int*)(dst + (size_t)(c0 + cc) * R + r0 + r4) = u;
  }
}

// -------- encoder layer 2 partials: all 4 batch rows per block (w2 read once)
__global__ __launch_bounds__(256) void enc2p_kernel(const float* __restrict__ t1p,
                                                    const float* __restrict__ b1,
                                                    const float* __restrict__ w2,
                                                    float* __restrict__ ep) {
  __shared__ float ts[4][256];
  int i = blockIdx.x * 256 + threadIdx.x;
  int kc = blockIdx.y;
  int h = kc * 256 + threadIdx.x;
  float bv = b1[h];
#pragma unroll
  for (int b = 0; b < 4; ++b) {
    float s0 = bv;
#pragma unroll
    for (int cc = 0; cc < KS1; ++cc) s0 += t1p[((size_t)(b * KS1 + cc)) * HSZ + h];
    ts[b][threadIdx.x] = gelu_f(s0);
  }
  __syncthreads();
  const float* w = w2 + (size_t)(kc * 256) * DSZ + i;
  float a0 = 0.f, a1 = 0.f, a2 = 0.f, a3 = 0.f;
#pragma unroll 4
  for (int j = 0; j < 256; ++j) {
    float wv = w[(size_t)j * DSZ];
    a0 += ts[0][j] * wv; a1 += ts[1][j] * wv;
    a2 += ts[2][j] * wv; a3 += ts[3][j] * wv;
  }
  ep[((size_t)(0 * KS2 + kc)) * DSZ + i] = a0;
  ep[((size_t)(1 * KS2 + kc)) * DSZ + i] = a1;
  ep[((size_t)(2 * KS2 + kc)) * DSZ + i] = a2;
  ep[((size_t)(3 * KS2 + kc)) * DSZ + i] = a3;
}

// -------- windows (enc2 combine fused): win8[b*T+t][j] = fp8((b2[t+j] + sum ep)*16)
__global__ __launch_bounds__(256) void win8_kernel(const float* __restrict__ ep,
                                                   const float* __restrict__ b2,
                                                   unsigned char* __restrict__ win8) {
  int blk = blockIdx.x;
  int b = blk >> 9, t = blk & 511;
  const float* epb = ep + (size_t)b * KS2 * DSZ;
  for (int j = threadIdx.x; j < 512; j += 256) {
    int d = t + j;                      // < 1024 always
    float s = b2[d];
#pragma unroll
    for (int kc = 0; kc < KS2; ++kc) s += epb[(size_t)kc * DSZ + d];
    win8[(size_t)blk * 512 + j] = q8(s);
  }
}

// -------- mid MX-fp8 GEMM (proj/dec1/dec2): mfma_scale 32x32x64, 128x128 tile,
// BK=64, 3-buffer ring depth-2, rotation LDS layout, ONE barrier per K-step
// (vmcnt(4) ledger, proven in gemmLM r16). Scales 2^-4 each cancel the x16
// input prescale exactly -> acc is true product; epilogue adds bias directly.
template<int GELU>
__global__ __launch_bounds__(256, 3) void gemmMX0(
    const unsigned char* __restrict__ A, const unsigned char* __restrict__ Bm,
    const float* __restrict__ bias, unsigned char* __restrict__ out8,
    int NT, int N, int K) {
  __shared__ __align__(16) char SM[49152];
  const int tid = threadIdx.x;
  const int lane = tid & 63;
  const int wave = tid >> 6;
  const int wr = (wave >> 1) * 64, wc = (wave & 1) * 64;
  const int l31 = lane & 31, hi = lane >> 5;

  const int cpx = (int)gridDim.x >> 3;
  const int wg = ((int)blockIdx.x & 7) * cpx + ((int)blockIdx.x >> 3);
  const int m0 = (wg / NT) * 128, n0 = (wg % NT) * 128;

  f32x16 acc[2][2];
#pragma unroll
  for (int i = 0; i < 2; ++i)
#pragma unroll
    for (int j = 0; j < 2; ++j)
#pragma unroll
      for (int r = 0; r < 16; ++r) acc[i][j][r] = 0.f;

  const int ppair = lane & 3;
  const int row0 = wave * 16 + (lane >> 2);
  const int row1 = row0 + 64;
  const int og0 = (ppair - (row0 >> 1)) & 3;
  const int og1 = (ppair - (row1 >> 1)) & 3;
  const unsigned char* a0 = A + (size_t)(m0 + row0) * K + og0 * 16;
  const unsigned char* a1 = A + (size_t)(m0 + row1) * K + og1 * 16;
  const unsigned char* b0 = Bm + (size_t)(n0 + row0) * K + og0 * 16;
  const unsigned char* b1 = Bm + (size_t)(n0 + row1) * K + og1 * 16;

#define STGM(tt, bufb) do { \
    GLD16(a0 + (size_t)(tt) * 64, SM + (bufb) + wave * 1024); \
    GLD16(a1 + (size_t)(tt) * 64, SM + (bufb) + 4096 + wave * 1024); \
    GLD16(b0 + (size_t)(tt) * 64, SM + (bufb) + 8192 + wave * 1024); \
    GLD16(b1 + (size_t)(tt) * 64, SM + (bufb) + 12288 + wave * 1024); \
  } while (0)

  const int KT = K >> 6;
  STGM(0, 0);
  STGM(1, 16384);
  asm volatile("s_waitcnt vmcnt(4)" ::: "memory");
  __builtin_amdgcn_s_barrier();
  asm volatile("" ::: "memory");
  int cb = 0;
  for (int t = 0; t < KT; ++t) {
    if (t + 2 < KT) {
      int nb = cb + 32768; if (nb >= 49152) nb -= 49152;
      STGM(t + 2, nb);
    }
    i32x8 a8[2], b8[2];
#pragma unroll
    for (int mf = 0; mf < 2; ++mf) {
      const int row = wr + mf * 32 + l31;
      const char* base = SM + cb + row * 64;
      const int ph0 = (2 * hi + (row >> 1)) & 3;
      const int ph1 = (2 * hi + 1 + (row >> 1)) & 3;
      i32x4 q01 = *(const i32x4*)(base + ph0 * 16);
      i32x4 q23 = *(const i32x4*)(base + ph1 * 16);
      a8[mf] = __builtin_shufflevector(q01, q23, 0, 1, 2, 3, 4, 5, 6, 7);
    }
#pragma unroll
    for (int nf = 0; nf < 2; ++nf) {
      const int row = wc + nf * 32 + l31;
      const char* base = SM + cb + 8192 + row * 64;
      const int ph0 = (2 * hi + (row >> 1)) & 3;
      const int ph1 = (2 * hi + 1 + (row >> 1)) & 3;
      i32x4 q01 = *(const i32x4*)(base + ph0 * 16);
      i32x4 q23 = *(const i32x4*)(base + ph1 * 16);
      b8[nf] = __builtin_shufflevector(q01, q23, 0, 1, 2, 3, 4, 5, 6, 7);
    }
    asm volatile("s_waitcnt lgkmcnt(0)" ::: "memory");
    __builtin_amdgcn_sched_barrier(0);
    __builtin_amdgcn_s_setprio(1);
#pragma unroll
    for (int mf = 0; mf < 2; ++mf)
#pragma unroll
      for (int nf = 0; nf < 2; ++nf)
        acc[mf][nf] = __builtin_amdgcn_mfma_scale_f32_32x32x64_f8f6f4(
            a8[mf], b8[nf], acc[mf][nf], 0, 0, 0, 123, 0, 123);
    __builtin_amdgcn_s_setprio(0);
    if (t + 2 < KT) {
      asm volatile("s_waitcnt vmcnt(4)" ::: "memory");
      __builtin_amdgcn_s_barrier();
      asm volatile("" ::: "memory");
    } else if (t + 1 < KT) {
      asm volatile("s_waitcnt vmcnt(0)" ::: "memory");
      __builtin_amdgcn_s_barrier();
      asm volatile("" ::: "memory");
    }
    cb += 16384; if (cb >= 49152) cb = 0;
  }
#undef STGM

  // epilogue: bias + opt gelu + q8; C/D col=l31 (n side), row=(r&3)+8*(r>>2)+4*hi (m side)
#pragma unroll
  for (int nf = 0; nf < 2; ++nf) {
    const int n = n0 + wc + nf * 32 + l31;
    const float bv = bias[n];
#pragma unroll
    for (int mf = 0; mf < 2; ++mf) {
      const int mb = m0 + wr + mf * 32 + 4 * hi;
#pragma unroll
      for (int r = 0; r < 16; ++r) {
        const int m = mb + (r & 3) + 8 * (r >> 2);
        float v = acc[mf][nf][r] + bv;
        if (GELU) v = gelu_f(v);
        out8[(size_t)m * N + n] = q8(v);
      }
    }
  }
}

// -------- lm-head MX-fp8 GEMM: unchanged from round 16 (proven).
__global__ __launch_bounds__(256, 3) void gemmLM(
    const unsigned char* __restrict__ A, const unsigned char* __restrict__ Bm,
    float* __restrict__ outF, float* __restrict__ pm, float* __restrict__ ps) {
  __shared__ __align__(16) char SM[49152];
  const int tid = threadIdx.x;
  const int lane = tid & 63;
  const int wave = tid >> 6;
  const int wr = (wave >> 1) * 64, wc = (wave & 1) * 64;
  const int l31 = lane & 31, hi = lane >> 5;

  const int cpx = (int)gridDim.x >> 3;
  const int wg = ((int)blockIdx.x & 7) * cpx + ((int)blockIdx.x >> 3);
  const int m0 = (wg >> 4) * 128, n0 = (wg & 15) * 128;

  f32x16 acc[2][2];
#pragma unroll
  for (int i = 0; i < 2; ++i)
#pragma unroll
    for (int j = 0; j < 2; ++j)
#pragma unroll
      for (int r = 0; r < 16; ++r) acc[i][j][r] = 0.f;

  const int ppair = lane & 3;
  const int row0 = wave * 16 + (lane >> 2);
  const int row1 = row0 + 64;
  const int og0 = (ppair - (row0 >> 1)) & 3;
  const int og1 = (ppair - (row1 >> 1)) & 3;
  const unsigned char* a0 = A + (size_t)(m0 + row0) * DSZ + og0 * 16;
  const unsigned char* a1 = A + (size_t)(m0 + row1) * DSZ + og1 * 16;
  const unsigned char* b0 = Bm + (size_t)(n0 + row0) * DSZ + og0 * 16;
  const unsigned char* b1 = Bm + (size_t)(n0 + row1) * DSZ + og1 * 16;

#define STGL(tt, bufb) do { \
    GLD16(a0 + (size_t)(tt) * 64, SM + (bufb) + wave * 1024); \
    GLD16(a1 + (size_t)(tt) * 64, SM + (bufb) + 4096 + wave * 1024); \
    GLD16(b0 + (size_t)(tt) * 64, SM + (bufb) + 8192 + wave * 1024); \
    GLD16(b1 + (size_t)(tt) * 64, SM + (bufb) + 12288 + wave * 1024); \
  } while (0)

  STGL(0, 0);
  STGL(1, 16384);
  asm volatile("s_waitcnt vmcnt(4)" ::: "memory");   // tile 0 landed; tile 1 in flight
  __builtin_amdgcn_s_barrier();
  asm volatile("" ::: "memory");
  int cb = 0;
  for (int t = 0; t < 16; ++t) {
    if (t + 2 < 16) {
      int nb = cb + 32768; if (nb >= 49152) nb -= 49152;
      STGL(t + 2, nb);
    }
    i32x8 a8[2], b8[2];
#pragma unroll
    for (int mf = 0; mf < 2; ++mf) {
      const int row = wr + mf * 32 + l31;
      const char* base = SM + cb + row * 64;
      const int ph0 = (2 * hi + (row >> 1)) & 3;
      const int ph1 = (2 * hi + 1 + (row >> 1)) & 3;
      i32x4 q01 = *(const i32x4*)(base + ph0 * 16);
      i32x4 q23 = *(const i32x4*)(base + ph1 * 16);
      a8[mf] = __builtin_shufflevector(q01, q23, 0, 1, 2, 3, 4, 5, 6, 7);
    }
#pragma unroll
    for (int nf = 0; nf < 2; ++nf) {
      const int row = wc + nf * 32 + l31;
      const char* base = SM + cb + 8192 + row * 64;
      const int ph0 = (2 * hi + (row >> 1)) & 3;
      const int ph1 = (2 * hi + 1 + (row >> 1)) & 3;
      i32x4 q01 = *(const i32x4*)(base + ph0 * 16);
      i32x4 q23 = *(const i32x4*)(base + ph1 * 16);
      b8[nf] = __builtin_shufflevector(q01, q23, 0, 1, 2, 3, 4, 5, 6, 7);
    }
    asm volatile("s_waitcnt lgkmcnt(0)" ::: "memory");
    __builtin_amdgcn_sched_barrier(0);
    __builtin_amdgcn_s_setprio(1);
#pragma unroll
    for (int mf = 0; mf < 2; ++mf)
#pragma unroll
      for (int nf = 0; nf < 2; ++nf)
        acc[mf][nf] = __builtin_amdgcn_mfma_scale_f32_32x32x64_f8f6f4(
            a8[mf], b8[nf], acc[mf][nf], 0, 0, 0, 123, 0, 123);
    __builtin_amdgcn_s_setprio(0);
    if (t + 2 < 16) {
      asm volatile("s_waitcnt vmcnt(4)" ::: "memory");
      __builtin_amdgcn_s_barrier();
      asm volatile("" ::: "memory");
    } else if (t + 1 < 16) {
      asm volatile("s_waitcnt vmcnt(0)" ::: "memory");
      __builtin_amdgcn_s_barrier();
      asm volatile("" ::: "memory");
    }
    cb += 16384; if (cb >= 49152) cb = 0;
  }
#undef STGL

  // ---- fused softmax partials: wave's 64 v-rows = stripe ch
  const int ch = (m0 + wr) >> 6;
#pragma unroll
  for (int nf = 0; nf < 2; ++nf) {
    const int pos = n0 + wc + nf * 32 + l31;
    float mloc = -1e30f, sloc = 0.f;
#pragma unroll
    for (int mf = 0; mf < 2; ++mf) {
      const int vb = m0 + wr + mf * 32 + 4 * hi;
#pragma unroll
      for (int r = 0; r < 16; ++r) {
        const int v = vb + (r & 3) + 8 * (r >> 2);
        if (v < VSZ) mloc = fmaxf(mloc, acc[mf][nf][r]);
      }
    }
#pragma unroll
    for (int mf = 0; mf < 2; ++mf) {
      const int vb = m0 + wr + mf * 32 + 4 * hi;
#pragma unroll
      for (int r = 0; r < 16; ++r) {
        const int v = vb + (r & 3) + 8 * (r >> 2);
        if (v < VSZ) sloc += __expf(acc[mf][nf][r] - mloc);
      }
    }
    {
      float mo = __shfl_xor(mloc, 32, 64);
      float so = __shfl_xor(sloc, 32, 64);
      float nm = fmaxf(mloc, mo);
      sloc = sloc * __expf(mloc - nm) + so * __expf(mo - nm);
      mloc = nm;
    }
    if (hi == 0) {
      pm[(size_t)ch * NPOS + pos] = mloc;
      ps[(size_t)ch * NPOS + pos] = sloc;
    }
  }

  // ---- 2-pass dual-region LDS restage + aligned NT stores.
  float* epi = (float*)SM;                 // 2 x 32 x 132 f32 = 33.8 KB
  const int bb = n0 >> 9, t0 = n0 & 511;
  float* outG = outF + 1 + (size_t)bb * VSZ * TSZ + t0;
  const int trow = tid >> 5;
  const int lofs = (tid & 31) * 4;
#pragma unroll
  for (int p = 0; p < 2; ++p) {
    __builtin_amdgcn_s_barrier();
    asm volatile("" ::: "memory");
    {
      const int rg = wave >> 1;
#pragma unroll
      for (int nf = 0; nf < 2; ++nf)
#pragma unroll
        for (int r = 0; r < 16; ++r)
          epi[rg * 4224 + ((r & 3) + 8 * (r >> 2) + 4 * hi) * 132 + wc + nf * 32 + l31] =
              acc[p][nf][r];
    }
    __builtin_amdgcn_s_barrier();
    asm volatile("" ::: "memory");
#pragma unroll
    for (int rg = 0; rg < 2; ++rg) {
      const int q = rg * 2 + p;
#pragma unroll
      for (int pp = 0; pp < 4; ++pp) {
        int row = pp * 8 + trow;
        int v = m0 + q * 32 + row;
        if (v < VSZ) {
          f32x4 val = *(const f32x4*)&epi[rg * 4224 + row * 132 + lofs];
          float* gp = outG + (size_t)v * TSZ + lofs;
          __builtin_nontemporal_store(val[0], gp + 0);
          __builtin_nontemporal_store(val[1], gp + 1);
          __builtin_nontemporal_store(val[2], gp + 2);
          __builtin_nontemporal_store(val[3], gp + 3);
        }
      }
    }
  }
}

// -------- loss stage 1: merge 13-chunk groups (512 blocks, 2/CU)
__global__ __launch_bounds__(256) void lsestage1_kernel(const float* __restrict__ pm,
                                                        const float* __restrict__ ps,
                                                        float* __restrict__ pm2,
                                                        float* __restrict__ ps2) {
  int pos = (blockIdx.x & 7) * 256 + threadIdx.x;
  int cg = blockIdx.x >> 3;
  int c0 = cg * CPC;
  int c1 = c0 + CPC; if (c1 > NCH) c1 = NCH;
  float m = -1e30f, s = 0.f;
  for (int c = c0; c < c1; ++c) {
    float cm = pm[(size_t)c * NPOS + pos];
    float cs = ps[(size_t)c * NPOS + pos];
    float nm = fmaxf(m, cm);
    s = s * __expf(m - nm) + cs * __expf(cm - nm);
    m = nm;
  }
  pm2[(size_t)cg * NPOS + pos] = m;
  ps2[(size_t)cg * NPOS + pos] = s;
}

// -------- loss stage 2: merge 64 groups per position, gather label logit
__global__ __launch_bounds__(256) void lsemerge_kernel(const float* __restrict__ pm2,
                                                       const float* __restrict__ ps2,
                                                       const float* __restrict__ outF,
                                                       const int* __restrict__ labels,
                                                       float* __restrict__ contrib) {
  int pos = blockIdx.x * 256 + threadIdx.x;
  float m[4] = {-1e30f, -1e30f, -1e30f, -1e30f};
  float s[4] = {0.f, 0.f, 0.f, 0.f};
  for (int c = 0; c < CG; c += 4) {
#pragma unroll
    for (int j = 0; j < 4; ++j) {
      float cm = pm2[(size_t)(c + j) * NPOS + pos];
      float cs = ps2[(size_t)(c + j) * NPOS + pos];
      float nm = fmaxf(m[j], cm);
      s[j] = s[j] * __expf(m[j] - nm) + cs * __expf(cm - nm);
      m[j] = nm;
    }
  }
#pragma unroll
  for (int j = 1; j < 4; ++j) {
    float nm = fmaxf(m[0], m[j]);
    s[0] = s[0] * __expf(m[0] - nm) + s[j] * __expf(m[j] - nm);
    m[0] = nm;
  }
  float lse = m[0] + logf(s[0]);
  int b = pos >> 9, t = pos & 511;
  int lab = labels[pos];
  float x = outF[1 + (size_t)b * VSZ * TSZ + (size_t)lab * TSZ + t];
  contrib[pos] = lse - x;
}

__global__ __launch_bounds__(256) void lossfinal_kernel(const float* __restrict__ contrib,
                                                        float* __restrict__ dout) {
  __shared__ float red[256];
  int tid = threadIdx.x;
  float a = 0.f;
  for (int i = tid; i < NPOS; i += 256) a += contrib[i];
  red[tid] = a;
  __syncthreads();
  for (int off = 128; off; off >>= 1) {
    if (tid < off) red[tid] += red[tid + off];
    __syncthreads();
  }
  if (tid == 0) dout[0] = red[0] / (float)NPOS;
}

extern "C" void kernel_launch(void* const* d_in, const int* in_sizes, int n_in,
                              void* d_out, int out_size, void* d_ws, size_t ws_size,
                              hipStream_t stream) {
  const int* input_ids = (const int*)d_in[0];
  const int* labels    = (const int*)d_in[1];
  const float* wte     = (const float*)d_in[2];
  const float* enc_w1  = (const float*)d_in[3];
  const float* enc_b1  = (const float*)d_in[4];
  const float* enc_w2  = (const float*)d_in[5];
  const float* enc_b2  = (const float*)d_in[6];
  const float* proj_w  = (const float*)d_in[7];
  const float* proj_b  = (const float*)d_in[8];
  const float* dec_w1  = (const float*)d_in[9];
  const float* dec_b1  = (const float*)d_in[10];
  const float* dec_w2  = (const float*)d_in[11];
  const float* dec_b2  = (const float*)d_in[12];
  const float* lm_w    = (const float*)d_in[13];
  float* outF = (float*)d_out;

  char* w = (char*)d_ws;
  size_t off = 0;
  unsigned char* lm8  = (unsigned char*)(w + off); off += (size_t)VPAD * DSZ;   // 51.6 MB
  unsigned char* w18  = (unsigned char*)(w + off); off += (size_t)HSZ * DSZ;    // 4 MB
  unsigned char* w28  = (unsigned char*)(w + off); off += (size_t)DSZ * HSZ;    // 4 MB
  unsigned char* p8   = (unsigned char*)(w + off); off += (size_t)DSZ * 512;    // 0.5 MB
  unsigned char* win8 = (unsigned char*)(w + off); off += (size_t)NPOS * 512;   // 1 MB
  unsigned char* pbuf8= (unsigned char*)(w + off); off += (size_t)NPOS * DSZ;   // 2 MB
  unsigned char* abuf8= (unsigned char*)(w + off); off += (size_t)NPOS * HSZ;   // 8 MB
  unsigned char* dbuf8= (unsigned char*)(w + off); off += (size_t)NPOS * DSZ;   // 2 MB
  float* t1p    = (float*)(w + off);  off += (size_t)BSZ * KS1 * HSZ * 4;
  float* ep     = (float*)(w + off);  off += (size_t)BSZ * KS2 * DSZ * 4;
  float* contrib= (float*)(w + off);  off += (size_t)NPOS * 4;
  float* pm     = (float*)(w + off);  off += (size_t)NCH * NPOS * 4;            // 6.5 MB
  float* ps     = (float*)(w + off);  off += (size_t)NCH * NPOS * 4;            // 6.5 MB
  float* pm2    = (float*)(w + off);  off += (size_t)CG * NPOS * 4;             // 512 KB
  float* ps2    = (float*)(w + off);  off += (size_t)CG * NPOS * 4;             // 512 KB
  (void)ws_size; (void)in_sizes; (void)n_in; (void)out_size;

  // weight transposes + enc1 partials in one dispatch
  transpose_all<<<14912, 256, 0, stream>>>(lm_w, dec_w1, dec_w2, proj_w,
                                           lm8, w18, w28, p8,
                                           input_ids, wte, enc_w1, t1p);

  // encoder layer 2 + windows (enc2 combine fused into win8)
  enc2p_kernel<<<dim3(DSZ / 256, KS2), 256, 0, stream>>>(t1p, enc_b1, enc_w2, ep);
  win8_kernel<<<2048, 256, 0, stream>>>(ep, enc_b2, win8);

  // MX-fp8 GEMM chain (1D grids, all divisible by 8 for the XCD swizzle)
  gemmMX0<0><<<128, 256, 0, stream>>>(win8, p8, proj_b, pbuf8, 8, DSZ, 512);
  gemmMX0<1><<<512, 256, 0, stream>>>(pbuf8, w18, dec_b1, abuf8, 32, HSZ, DSZ);
  gemmMX0<0><<<128, 256, 0, stream>>>(abuf8, w28, dec_b2, dbuf8, 8, DSZ, HSZ);
  // lm head MX-fp8: 394 m-tiles x 16 n-tiles = 6304 blocks
  gemmLM<<<6304, 256, 0, stream>>>(lm8, dbuf8, outF, pm, ps);

  // loss: two-stage merge + mean
  lsestage1_kernel<<<512, 256, 0, stream>>>(pm, ps, pm2, ps2);
  lsemerge_kernel<<<dim3(NPOS / 256), 256, 0, stream>>>(pm2, ps2, outF, labels, contrib);
  lossfinal_kernel<<<1, 256, 0, stream>>>(contrib, outF);
}

// Round 18
// 363.699 us; speedup vs baseline: 1.4372x; 1.0126x over previous
//
#include <hip/hip_runtime.h>

#define VSZ 50257
#define DSZ 1024
#define TSZ 512
#define BSZ 4
#define HSZ 4096
#define VPAD 50432   // 394*128
#define NCH (VPAD / 64)   // 788 v-stripes of 64
#define NPOS 2048
#define QS 16.0f
#define DQS (1.0f / 256.0f)
#define CG 64        // stage-1 chunk groups
#define CPC 13       // chunks per group (64*13 = 832 >= 788)

typedef __attribute__((ext_vector_type(4))) float f32x4;
typedef __attribute__((ext_vector_type(16))) float f32x16;
typedef __attribute__((ext_vector_type(4))) int i32x4;
typedef __attribute__((ext_vector_type(8))) int i32x8;

#define GLD16(gp, lp) __builtin_amdgcn_global_load_lds( \
  (const __attribute__((address_space(1))) unsigned int*)(gp), \
  (__attribute__((address_space(3))) unsigned int*)(lp), 16, 0, 0)

__device__ __forceinline__ float gelu_f(float x) {
  float x3 = x * x * x;
  float u = 0.7978845608028654f * (x + 0.044715f * x3);
  return 0.5f * x * (1.f + tanhf(u));
}

__device__ __forceinline__ unsigned char q8(float v) {
  return (unsigned char)__builtin_amdgcn_cvt_pk_fp8_f32(v * QS, v * QS, 0, 0);
}

// -------- fused: all weight transposes (f32 -> fp8 x16) + enc1 partials.
// Blocks 0..14783: transposes (64x64 tiles). Blocks 14784..14911: enc1p.
#define KS1 8
#define KS2 16
__global__ __launch_bounds__(256) void transpose_all(
    const float* __restrict__ lm_w, const float* __restrict__ dw1,
    const float* __restrict__ dw2, const float* __restrict__ pw,
    unsigned char* __restrict__ lm8, unsigned char* __restrict__ w18,
    unsigned char* __restrict__ w28, unsigned char* __restrict__ p8,
    const int* __restrict__ ids, const float* __restrict__ wte,
    const float* __restrict__ w1, float* __restrict__ t1p) {
  __shared__ float tile[64][65];
  int bid = blockIdx.x;
  int tid = threadIdx.x;

  if (bid >= 14784) {
    int eb = bid - 14784;
    int h = (eb & 15) * 256 + tid;
    int kc = eb >> 4;
    float (*ev)[128] = (float(*)[128])tile;
    for (int i = tid; i < 512; i += 256) {
      int b = i >> 7, d = i & 127;
      int tok = ids[b * TSZ + (TSZ - 1)];
      ev[b][d] = wte[(size_t)tok * DSZ + kc * 128 + d];
    }
    __syncthreads();
    const float* w = w1 + (size_t)(kc * 128) * HSZ + h;
    float s0 = 0.f, s1 = 0.f, s2 = 0.f, s3 = 0.f;
#pragma unroll 4
    for (int d = 0; d < 128; ++d) {
      float wv = w[(size_t)d * HSZ];
      s0 += ev[0][d] * wv; s1 += ev[1][d] * wv;
      s2 += ev[2][d] * wv; s3 += ev[3][d] * wv;
    }
    t1p[((size_t)(0 * KS1 + kc)) * HSZ + h] = s0;
    t1p[((size_t)(1 * KS1 + kc)) * HSZ + h] = s1;
    t1p[((size_t)(2 * KS1 + kc)) * HSZ + h] = s2;
    t1p[((size_t)(3 * KS1 + kc)) * HSZ + h] = s3;
    return;
  }

  const float* src; unsigned char* dst; int R, C, Cpad, bx, by;
  if (bid < 12608)      { src = lm_w; dst = lm8; R = DSZ; C = VSZ; Cpad = VPAD; bx = bid % 788; by = bid / 788; }
  else if (bid < 13632) { int b = bid - 12608; src = dw1; dst = w18; R = DSZ; C = HSZ; Cpad = HSZ; bx = b % 64; by = b / 64; }
  else if (bid < 14656) { int b = bid - 13632; src = dw2; dst = w28; R = HSZ; C = DSZ; Cpad = DSZ; bx = b % 16; by = b / 16; }
  else                  { int b = bid - 14656; src = pw;  dst = p8;  R = 512; C = DSZ; Cpad = DSZ; bx = b % 16; by = b / 16; }
  int c0 = bx * 64, r0 = by * 64;
  int wv = tid >> 6, ln = tid & 63;
  int c = c0 + ln;
#pragma unroll 4
  for (int i = 0; i < 16; ++i) {
    int r = i * 4 + wv;
    tile[r][ln] = (c < C) ? src[(size_t)(r0 + r) * C + c] : 0.f;
  }
  __syncthreads();
  int ccb = tid >> 4;
  int r4 = (tid & 15) * 4;
#pragma unroll
  for (int j = 0; j < 4; ++j) {
    int cc = ccb + j * 16;
    if (c0 + cc >= Cpad) continue;
    unsigned int u = __builtin_amdgcn_cvt_pk_fp8_f32(QS * tile[r4 + 0][cc], QS * tile[r4 + 1][cc], 0, 0);
    u = __builtin_amdgcn_cvt_pk_fp8_f32(QS * tile[r4 + 2][cc], QS * tile[r4 + 3][cc], u, 1);
    *(unsigned int*)(dst + (size_t)(c0 + cc) * R + r0 + r4) = u;
  }
}

// -------- encoder layer 2 partials: all 4 batch rows per block (w2 read once)
__global__ __launch_bounds__(256) void enc2p_kernel(const float* __restrict__ t1p,
                                                    const float* __restrict__ b1,
                                                    const float* __restrict__ w2,
                                                    float* __restrict__ ep) {
  __shared__ float ts[4][256];
  int i = blockIdx.x * 256 + threadIdx.x;
  int kc = blockIdx.y;
  int h = kc * 256 + threadIdx.x;
  float bv = b1[h];
#pragma unroll
  for (int b = 0; b < 4; ++b) {
    float s0 = bv;
#pragma unroll
    for (int cc = 0; cc < KS1; ++cc) s0 += t1p[((size_t)(b * KS1 + cc)) * HSZ + h];
    ts[b][threadIdx.x] = gelu_f(s0);
  }
  __syncthreads();
  const float* w = w2 + (size_t)(kc * 256) * DSZ + i;
  float a0 = 0.f, a1 = 0.f, a2 = 0.f, a3 = 0.f;
#pragma unroll 4
  for (int j = 0; j < 256; ++j) {
    float wv = w[(size_t)j * DSZ];
    a0 += ts[0][j] * wv; a1 += ts[1][j] * wv;
    a2 += ts[2][j] * wv; a3 += ts[3][j] * wv;
  }
  ep[((size_t)(0 * KS2 + kc)) * DSZ + i] = a0;
  ep[((size_t)(1 * KS2 + kc)) * DSZ + i] = a1;
  ep[((size_t)(2 * KS2 + kc)) * DSZ + i] = a2;
  ep[((size_t)(3 * KS2 + kc)) * DSZ + i] = a3;
}

// -------- windows (enc2 combine fused): win8[b*T+t][j] = fp8((b2[t+j] + sum ep)*16)
__global__ __launch_bounds__(256) void win8_kernel(const float* __restrict__ ep,
                                                   const float* __restrict__ b2,
                                                   unsigned char* __restrict__ win8) {
  int blk = blockIdx.x;
  int b = blk >> 9, t = blk & 511;
  const float* epb = ep + (size_t)b * KS2 * DSZ;
  for (int j = threadIdx.x; j < 512; j += 256) {
    int d = t + j;
    float s = b2[d];
#pragma unroll
    for (int kc = 0; kc < KS2; ++kc) s += epb[(size_t)kc * DSZ + d];
    win8[(size_t)blk * 512 + j] = q8(s);
  }
}

// -------- mid MX-fp8 GEMM (proj/dec1/dec2): mfma_scale 32x32x64, 128x128 tile,
// BK=64, 3-buffer ring depth-2, rotation LDS layout, ONE barrier per K-step.
// Compiler-scheduled LDS->MFMA (no manual lgkmcnt/sched_barrier pinning).
template<int GELU>
__global__ __launch_bounds__(256, 3) void gemmMX0(
    const unsigned char* __restrict__ A, const unsigned char* __restrict__ Bm,
    const float* __restrict__ bias, unsigned char* __restrict__ out8,
    int NT, int N, int K) {
  __shared__ __align__(16) char SM[49152];
  const int tid = threadIdx.x;
  const int lane = tid & 63;
  const int wave = tid >> 6;
  const int wr = (wave >> 1) * 64, wc = (wave & 1) * 64;
  const int l31 = lane & 31, hi = lane >> 5;

  const int cpx = (int)gridDim.x >> 3;
  const int wg = ((int)blockIdx.x & 7) * cpx + ((int)blockIdx.x >> 3);
  const int m0 = (wg / NT) * 128, n0 = (wg % NT) * 128;

  f32x16 acc[2][2];
#pragma unroll
  for (int i = 0; i < 2; ++i)
#pragma unroll
    for (int j = 0; j < 2; ++j)
#pragma unroll
      for (int r = 0; r < 16; ++r) acc[i][j][r] = 0.f;

  const int ppair = lane & 3;
  const int row0 = wave * 16 + (lane >> 2);
  const int row1 = row0 + 64;
  const int og0 = (ppair - (row0 >> 1)) & 3;
  const int og1 = (ppair - (row1 >> 1)) & 3;
  const unsigned char* a0 = A + (size_t)(m0 + row0) * K + og0 * 16;
  const unsigned char* a1 = A + (size_t)(m0 + row1) * K + og1 * 16;
  const unsigned char* b0 = Bm + (size_t)(n0 + row0) * K + og0 * 16;
  const unsigned char* b1 = Bm + (size_t)(n0 + row1) * K + og1 * 16;

#define STGM(tt, bufb) do { \
    GLD16(a0 + (size_t)(tt) * 64, SM + (bufb) + wave * 1024); \
    GLD16(a1 + (size_t)(tt) * 64, SM + (bufb) + 4096 + wave * 1024); \
    GLD16(b0 + (size_t)(tt) * 64, SM + (bufb) + 8192 + wave * 1024); \
    GLD16(b1 + (size_t)(tt) * 64, SM + (bufb) + 12288 + wave * 1024); \
  } while (0)

  const int KT = K >> 6;
  STGM(0, 0);
  STGM(1, 16384);
  asm volatile("s_waitcnt vmcnt(4)" ::: "memory");
  __builtin_amdgcn_s_barrier();
  asm volatile("" ::: "memory");
  int cb = 0;
  for (int t = 0; t < KT; ++t) {
    if (t + 2 < KT) {
      int nb = cb + 32768; if (nb >= 49152) nb -= 49152;
      STGM(t + 2, nb);
    }
    i32x8 a8[2], b8[2];
#pragma unroll
    for (int mf = 0; mf < 2; ++mf) {
      const int row = wr + mf * 32 + l31;
      const char* base = SM + cb + row * 64;
      const int ph0 = (2 * hi + (row >> 1)) & 3;
      const int ph1 = (2 * hi + 1 + (row >> 1)) & 3;
      i32x4 q01 = *(const i32x4*)(base + ph0 * 16);
      i32x4 q23 = *(const i32x4*)(base + ph1 * 16);
      a8[mf] = __builtin_shufflevector(q01, q23, 0, 1, 2, 3, 4, 5, 6, 7);
    }
#pragma unroll
    for (int nf = 0; nf < 2; ++nf) {
      const int row = wc + nf * 32 + l31;
      const char* base = SM + cb + 8192 + row * 64;
      const int ph0 = (2 * hi + (row >> 1)) & 3;
      const int ph1 = (2 * hi + 1 + (row >> 1)) & 3;
      i32x4 q01 = *(const i32x4*)(base + ph0 * 16);
      i32x4 q23 = *(const i32x4*)(base + ph1 * 16);
      b8[nf] = __builtin_shufflevector(q01, q23, 0, 1, 2, 3, 4, 5, 6, 7);
    }
#pragma unroll
    for (int mf = 0; mf < 2; ++mf)
#pragma unroll
      for (int nf = 0; nf < 2; ++nf)
        acc[mf][nf] = __builtin_amdgcn_mfma_scale_f32_32x32x64_f8f6f4(
            a8[mf], b8[nf], acc[mf][nf], 0, 0, 0, 123, 0, 123);
    if (t + 2 < KT) {
      asm volatile("s_waitcnt vmcnt(4)" ::: "memory");
      __builtin_amdgcn_s_barrier();
      asm volatile("" ::: "memory");
    } else if (t + 1 < KT) {
      asm volatile("s_waitcnt vmcnt(0)" ::: "memory");
      __builtin_amdgcn_s_barrier();
      asm volatile("" ::: "memory");
    }
    cb += 16384; if (cb >= 49152) cb = 0;
  }
#undef STGM

#pragma unroll
  for (int nf = 0; nf < 2; ++nf) {
    const int n = n0 + wc + nf * 32 + l31;
    const float bv = bias[n];
#pragma unroll
    for (int mf = 0; mf < 2; ++mf) {
      const int mb = m0 + wr + mf * 32 + 4 * hi;
#pragma unroll
      for (int r = 0; r < 16; ++r) {
        const int m = mb + (r & 3) + 8 * (r >> 2);
        float v = acc[mf][nf][r] + bv;
        if (GELU) v = gelu_f(v);
        out8[(size_t)m * N + n] = q8(v);
      }
    }
  }
}

// -------- lm-head MX-fp8 GEMM: as r17 but compiler-scheduled LDS->MFMA.
__global__ __launch_bounds__(256, 3) void gemmLM(
    const unsigned char* __restrict__ A, const unsigned char* __restrict__ Bm,
    float* __restrict__ outF, float* __restrict__ pm, float* __restrict__ ps) {
  __shared__ __align__(16) char SM[49152];
  const int tid = threadIdx.x;
  const int lane = tid & 63;
  const int wave = tid >> 6;
  const int wr = (wave >> 1) * 64, wc = (wave & 1) * 64;
  const int l31 = lane & 31, hi = lane >> 5;

  const int cpx = (int)gridDim.x >> 3;
  const int wg = ((int)blockIdx.x & 7) * cpx + ((int)blockIdx.x >> 3);
  const int m0 = (wg >> 4) * 128, n0 = (wg & 15) * 128;

  f32x16 acc[2][2];
#pragma unroll
  for (int i = 0; i < 2; ++i)
#pragma unroll
    for (int j = 0; j < 2; ++j)
#pragma unroll
      for (int r = 0; r < 16; ++r) acc[i][j][r] = 0.f;

  const int ppair = lane & 3;
  const int row0 = wave * 16 + (lane >> 2);
  const int row1 = row0 + 64;
  const int og0 = (ppair - (row0 >> 1)) & 3;
  const int og1 = (ppair - (row1 >> 1)) & 3;
  const unsigned char* a0 = A + (size_t)(m0 + row0) * DSZ + og0 * 16;
  const unsigned char* a1 = A + (size_t)(m0 + row1) * DSZ + og1 * 16;
  const unsigned char* b0 = Bm + (size_t)(n0 + row0) * DSZ + og0 * 16;
  const unsigned char* b1 = Bm + (size_t)(n0 + row1) * DSZ + og1 * 16;

#define STGL(tt, bufb) do { \
    GLD16(a0 + (size_t)(tt) * 64, SM + (bufb) + wave * 1024); \
    GLD16(a1 + (size_t)(tt) * 64, SM + (bufb) + 4096 + wave * 1024); \
    GLD16(b0 + (size_t)(tt) * 64, SM + (bufb) + 8192 + wave * 1024); \
    GLD16(b1 + (size_t)(tt) * 64, SM + (bufb) + 12288 + wave * 1024); \
  } while (0)

  STGL(0, 0);
  STGL(1, 16384);
  asm volatile("s_waitcnt vmcnt(4)" ::: "memory");
  __builtin_amdgcn_s_barrier();
  asm volatile("" ::: "memory");
  int cb = 0;
  for (int t = 0; t < 16; ++t) {
    if (t + 2 < 16) {
      int nb = cb + 32768; if (nb >= 49152) nb -= 49152;
      STGL(t + 2, nb);
    }
    i32x8 a8[2], b8[2];
#pragma unroll
    for (int mf = 0; mf < 2; ++mf) {
      const int row = wr + mf * 32 + l31;
      const char* base = SM + cb + row * 64;
      const int ph0 = (2 * hi + (row >> 1)) & 3;
      const int ph1 = (2 * hi + 1 + (row >> 1)) & 3;
      i32x4 q01 = *(const i32x4*)(base + ph0 * 16);
      i32x4 q23 = *(const i32x4*)(base + ph1 * 16);
      a8[mf] = __builtin_shufflevector(q01, q23, 0, 1, 2, 3, 4, 5, 6, 7);
    }
#pragma unroll
    for (int nf = 0; nf < 2; ++nf) {
      const int row = wc + nf * 32 + l31;
      const char* base = SM + cb + 8192 + row * 64;
      const int ph0 = (2 * hi + (row >> 1)) & 3;
      const int ph1 = (2 * hi + 1 + (row >> 1)) & 3;
      i32x4 q01 = *(const i32x4*)(base + ph0 * 16);
      i32x4 q23 = *(const i32x4*)(base + ph1 * 16);
      b8[nf] = __builtin_shufflevector(q01, q23, 0, 1, 2, 3, 4, 5, 6, 7);
    }
#pragma unroll
    for (int mf = 0; mf < 2; ++mf)
#pragma unroll
      for (int nf = 0; nf < 2; ++nf)
        acc[mf][nf] = __builtin_amdgcn_mfma_scale_f32_32x32x64_f8f6f4(
            a8[mf], b8[nf], acc[mf][nf], 0, 0, 0, 123, 0, 123);
    if (t + 2 < 16) {
      asm volatile("s_waitcnt vmcnt(4)" ::: "memory");
      __builtin_amdgcn_s_barrier();
      asm volatile("" ::: "memory");
    } else if (t + 1 < 16) {
      asm volatile("s_waitcnt vmcnt(0)" ::: "memory");
      __builtin_amdgcn_s_barrier();
      asm volatile("" ::: "memory");
    }
    cb += 16384; if (cb >= 49152) cb = 0;
  }
#undef STGL

  // ---- fused softmax partials: wave's 64 v-rows = stripe ch
  const int ch = (m0 + wr) >> 6;
#pragma unroll
  for (int nf = 0; nf < 2; ++nf) {
    const int pos = n0 + wc + nf * 32 + l31;
    float mloc = -1e30f, sloc = 0.f;
#pragma unroll
    for (int mf = 0; mf < 2; ++mf) {
      const int vb = m0 + wr + mf * 32 + 4 * hi;
#pragma unroll
      for (int r = 0; r < 16; ++r) {
        const int v = vb + (r & 3) + 8 * (r >> 2);
        if (v < VSZ) mloc = fmaxf(mloc, acc[mf][nf][r]);
      }
    }
#pragma unroll
    for (int mf = 0; mf < 2; ++mf) {
      const int vb = m0 + wr + mf * 32 + 4 * hi;
#pragma unroll
      for (int r = 0; r < 16; ++r) {
        const int v = vb + (r & 3) + 8 * (r >> 2);
        if (v < VSZ) sloc += __expf(acc[mf][nf][r] - mloc);
      }
    }
    {
      float mo = __shfl_xor(mloc, 32, 64);
      float so = __shfl_xor(sloc, 32, 64);
      float nm = fmaxf(mloc, mo);
      sloc = sloc * __expf(mloc - nm) + so * __expf(mo - nm);
      mloc = nm;
    }
    if (hi == 0) {
      pm[(size_t)ch * NPOS + pos] = mloc;
      ps[(size_t)ch * NPOS + pos] = sloc;
    }
  }

  // ---- 2-pass dual-region LDS restage + aligned NT stores.
  float* epi = (float*)SM;
  const int bb = n0 >> 9, t0 = n0 & 511;
  float* outG = outF + 1 + (size_t)bb * VSZ * TSZ + t0;
  const int trow = tid >> 5;
  const int lofs = (tid & 31) * 4;
#pragma unroll
  for (int p = 0; p < 2; ++p) {
    __builtin_amdgcn_s_barrier();
    asm volatile("" ::: "memory");
    {
      const int rg = wave >> 1;
#pragma unroll
      for (int nf = 0; nf < 2; ++nf)
#pragma unroll
        for (int r = 0; r < 16; ++r)
          epi[rg * 4224 + ((r & 3) + 8 * (r >> 2) + 4 * hi) * 132 + wc + nf * 32 + l31] =
              acc[p][nf][r];
    }
    __builtin_amdgcn_s_barrier();
    asm volatile("" ::: "memory");
#pragma unroll
    for (int rg = 0; rg < 2; ++rg) {
      const int q = rg * 2 + p;
#pragma unroll
      for (int pp = 0; pp < 4; ++pp) {
        int row = pp * 8 + trow;
        int v = m0 + q * 32 + row;
        if (v < VSZ) {
          f32x4 val = *(const f32x4*)&epi[rg * 4224 + row * 132 + lofs];
          float* gp = outG + (size_t)v * TSZ + lofs;
          __builtin_nontemporal_store(val[0], gp + 0);
          __builtin_nontemporal_store(val[1], gp + 1);
          __builtin_nontemporal_store(val[2], gp + 2);
          __builtin_nontemporal_store(val[3], gp + 3);
        }
      }
    }
  }
}

// -------- loss stage 1: merge 13-chunk groups (512 blocks, 2/CU)
__global__ __launch_bounds__(256) void lsestage1_kernel(const float* __restrict__ pm,
                                                        const float* __restrict__ ps,
                                                        float* __restrict__ pm2,
                                                        float* __restrict__ ps2) {
  int pos = (blockIdx.x & 7) * 256 + threadIdx.x;
  int cg = blockIdx.x >> 3;
  int c0 = cg * CPC;
  int c1 = c0 + CPC; if (c1 > NCH) c1 = NCH;
  float m = -1e30f, s = 0.f;
  for (int c = c0; c < c1; ++c) {
    float cm = pm[(size_t)c * NPOS + pos];
    float cs = ps[(size_t)c * NPOS + pos];
    float nm = fmaxf(m, cm);
    s = s * __expf(m - nm) + cs * __expf(cm - nm);
    m = nm;
  }
  pm2[(size_t)cg * NPOS + pos] = m;
  ps2[(size_t)cg * NPOS + pos] = s;
}

// -------- loss stage 2: merge 64 groups per position, gather label logit
__global__ __launch_bounds__(256) void lsemerge_kernel(const float* __restrict__ pm2,
                                                       const float* __restrict__ ps2,
                                                       const float* __restrict__ outF,
                                                       const int* __restrict__ labels,
                                                       float* __restrict__ contrib) {
  int pos = blockIdx.x * 256 + threadIdx.x;
  float m[4] = {-1e30f, -1e30f, -1e30f, -1e30f};
  float s[4] = {0.f, 0.f, 0.f, 0.f};
  for (int c = 0; c < CG; c += 4) {
#pragma unroll
    for (int j = 0; j < 4; ++j) {
      float cm = pm2[(size_t)(c + j) * NPOS + pos];
      float cs = ps2[(size_t)(c + j) * NPOS + pos];
      float nm = fmaxf(m[j], cm);
      s[j] = s[j] * __expf(m[j] - nm) + cs * __expf(cm - nm);
      m[j] = nm;
    }
  }
#pragma unroll
  for (int j = 1; j < 4; ++j) {
    float nm = fmaxf(m[0], m[j]);
    s[0] = s[0] * __expf(m[0] - nm) + s[j] * __expf(m[j] - nm);
    m[0] = nm;
  }
  float lse = m[0] + logf(s[0]);
  int b = pos >> 9, t = pos & 511;
  int lab = labels[pos];
  float x = outF[1 + (size_t)b * VSZ * TSZ + (size_t)lab * TSZ + t];
  contrib[pos] = lse - x;
}

__global__ __launch_bounds__(256) void lossfinal_kernel(const float* __restrict__ contrib,
                                                        float* __restrict__ dout) {
  __shared__ float red[256];
  int tid = threadIdx.x;
  float a = 0.f;
  for (int i = tid; i < NPOS; i += 256) a += contrib[i];
  red[tid] = a;
  __syncthreads();
  for (int off = 128; off; off >>= 1) {
    if (tid < off) red[tid] += red[tid + off];
    __syncthreads();
  }
  if (tid == 0) dout[0] = red[0] / (float)NPOS;
}

extern "C" void kernel_launch(void* const* d_in, const int* in_sizes, int n_in,
                              void* d_out, int out_size, void* d_ws, size_t ws_size,
                              hipStream_t stream) {
  const int* input_ids = (const int*)d_in[0];
  const int* labels    = (const int*)d_in[1];
  const float* wte     = (const float*)d_in[2];
  const float* enc_w1  = (const float*)d_in[3];
  const float* enc_b1  = (const float*)d_in[4];
  const float* enc_w2  = (const float*)d_in[5];
  const float* enc_b2  = (const float*)d_in[6];
  const float* proj_w  = (const float*)d_in[7];
  const float* proj_b  = (const float*)d_in[8];
  const float* dec_w1  = (const float*)d_in[9];
  const float* dec_b1  = (const float*)d_in[10];
  const float* dec_w2  = (const float*)d_in[11];
  const float* dec_b2  = (const float*)d_in[12];
  const float* lm_w    = (const float*)d_in[13];
  float* outF = (float*)d_out;

  char* w = (char*)d_ws;
  size_t off = 0;
  unsigned char* lm8  = (unsigned char*)(w + off); off += (size_t)VPAD * DSZ;   // 51.6 MB
  unsigned char* w18  = (unsigned char*)(w + off); off += (size_t)HSZ * DSZ;    // 4 MB
  unsigned char* w28  = (unsigned char*)(w + off); off += (size_t)DSZ * HSZ;    // 4 MB
  unsigned char* p8   = (unsigned char*)(w + off); off += (size_t)DSZ * 512;    // 0.5 MB
  unsigned char* win8 = (unsigned char*)(w + off); off += (size_t)NPOS * 512;   // 1 MB
  unsigned char* pbuf8= (unsigned char*)(w + off); off += (size_t)NPOS * DSZ;   // 2 MB
  unsigned char* abuf8= (unsigned char*)(w + off); off += (size_t)NPOS * HSZ;   // 8 MB
  unsigned char* dbuf8= (unsigned char*)(w + off); off += (size_t)NPOS * DSZ;   // 2 MB
  float* t1p    = (float*)(w + off);  off += (size_t)BSZ * KS1 * HSZ * 4;
  float* ep     = (float*)(w + off);  off += (size_t)BSZ * KS2 * DSZ * 4;
  float* contrib= (float*)(w + off);  off += (size_t)NPOS * 4;
  float* pm     = (float*)(w + off);  off += (size_t)NCH * NPOS * 4;            // 6.5 MB
  float* ps     = (float*)(w + off);  off += (size_t)NCH * NPOS * 4;            // 6.5 MB
  float* pm2    = (float*)(w + off);  off += (size_t)CG * NPOS * 4;             // 512 KB
  float* ps2    = (float*)(w + off);  off += (size_t)CG * NPOS * 4;             // 512 KB
  (void)ws_size; (void)in_sizes; (void)n_in; (void)out_size;

  // weight transposes + enc1 partials in one dispatch
  transpose_all<<<14912, 256, 0, stream>>>(lm_w, dec_w1, dec_w2, proj_w,
                                           lm8, w18, w28, p8,
                                           input_ids, wte, enc_w1, t1p);

  // encoder layer 2 + windows (enc2 combine fused into win8)
  enc2p_kernel<<<dim3(DSZ / 256, KS2), 256, 0, stream>>>(t1p, enc_b1, enc_w2, ep);
  win8_kernel<<<2048, 256, 0, stream>>>(ep, enc_b2, win8);

  // MX-fp8 GEMM chain (1D grids, all divisible by 8 for the XCD swizzle)
  gemmMX0<0><<<128, 256, 0, stream>>>(win8, p8, proj_b, pbuf8, 8, DSZ, 512);
  gemmMX0<1><<<512, 256, 0, stream>>>(pbuf8, w18, dec_b1, abuf8, 32, HSZ, DSZ);
  gemmMX0<0><<<128, 256, 0, stream>>>(abuf8, w28, dec_b2, dbuf8, 8, DSZ, HSZ);
  // lm head MX-fp8: 394 m-tiles x 16 n-tiles = 6304 blocks
  gemmLM<<<6304, 256, 0, stream>>>(lm8, dbuf8, outF, pm, ps);

  // loss: two-stage merge + mean
  lsestage1_kernel<<<512, 256, 0, stream>>>(pm, ps, pm2, ps2);
  lsemerge_kernel<<<dim3(NPOS / 256), 256, 0, stream>>>(pm2, ps2, outF, labels, contrib);
  lossfinal_kernel<<<1, 256, 0, stream>>>(contrib, outF);
}

// Round 19
// 363.326 us; speedup vs baseline: 1.4387x; 1.0010x over previous
//
#include <hip/hip_runtime.h>

#define VSZ 50257
#define DSZ 1024
#define TSZ 512
#define BSZ 4
#define HSZ 4096
#define VPAD 50432   // 394*128
#define NCH (VPAD / 64)   // 788 v-stripes of 64
#define NPOS 2048
#define QS 16.0f
#define DQS (1.0f / 256.0f)
#define CG 64        // stage-1 chunk groups
#define CPC 13       // chunks per group (64*13 = 832 >= 788)

typedef __attribute__((ext_vector_type(4))) float f32x4;
typedef __attribute__((ext_vector_type(16))) float f32x16;
typedef __attribute__((ext_vector_type(4))) int i32x4;
typedef __attribute__((ext_vector_type(8))) int i32x8;

#define GLD16(gp, lp) __builtin_amdgcn_global_load_lds( \
  (const __attribute__((address_space(1))) unsigned int*)(gp), \
  (__attribute__((address_space(3))) unsigned int*)(lp), 16, 0, 0)

__device__ __forceinline__ float gelu_f(float x) {
  float x3 = x * x * x;
  float u = 0.7978845608028654f * (x + 0.044715f * x3);
  return 0.5f * x * (1.f + tanhf(u));
}

__device__ __forceinline__ unsigned char q8(float v) {
  return (unsigned char)__builtin_amdgcn_cvt_pk_fp8_f32(v * QS, v * QS, 0, 0);
}

// -------- fused: all weight transposes (f32 -> fp8 x16) + enc1 partials.
#define KS1 8
#define KS2 16
__global__ __launch_bounds__(256) void transpose_all(
    const float* __restrict__ lm_w, const float* __restrict__ dw1,
    const float* __restrict__ dw2, const float* __restrict__ pw,
    unsigned char* __restrict__ lm8, unsigned char* __restrict__ w18,
    unsigned char* __restrict__ w28, unsigned char* __restrict__ p8,
    const int* __restrict__ ids, const float* __restrict__ wte,
    const float* __restrict__ w1, float* __restrict__ t1p) {
  __shared__ float tile[64][65];
  int bid = blockIdx.x;
  int tid = threadIdx.x;

  if (bid >= 14784) {
    int eb = bid - 14784;
    int h = (eb & 15) * 256 + tid;
    int kc = eb >> 4;
    float (*ev)[128] = (float(*)[128])tile;
    for (int i = tid; i < 512; i += 256) {
      int b = i >> 7, d = i & 127;
      int tok = ids[b * TSZ + (TSZ - 1)];
      ev[b][d] = wte[(size_t)tok * DSZ + kc * 128 + d];
    }
    __syncthreads();
    const float* w = w1 + (size_t)(kc * 128) * HSZ + h;
    float s0 = 0.f, s1 = 0.f, s2 = 0.f, s3 = 0.f;
#pragma unroll 4
    for (int d = 0; d < 128; ++d) {
      float wv = w[(size_t)d * HSZ];
      s0 += ev[0][d] * wv; s1 += ev[1][d] * wv;
      s2 += ev[2][d] * wv; s3 += ev[3][d] * wv;
    }
    t1p[((size_t)(0 * KS1 + kc)) * HSZ + h] = s0;
    t1p[((size_t)(1 * KS1 + kc)) * HSZ + h] = s1;
    t1p[((size_t)(2 * KS1 + kc)) * HSZ + h] = s2;
    t1p[((size_t)(3 * KS1 + kc)) * HSZ + h] = s3;
    return;
  }

  const float* src; unsigned char* dst; int R, C, Cpad, bx, by;
  if (bid < 12608)      { src = lm_w; dst = lm8; R = DSZ; C = VSZ; Cpad = VPAD; bx = bid % 788; by = bid / 788; }
  else if (bid < 13632) { int b = bid - 12608; src = dw1; dst = w18; R = DSZ; C = HSZ; Cpad = HSZ; bx = b % 64; by = b / 64; }
  else if (bid < 14656) { int b = bid - 13632; src = dw2; dst = w28; R = HSZ; C = DSZ; Cpad = DSZ; bx = b % 16; by = b / 16; }
  else                  { int b = bid - 14656; src = pw;  dst = p8;  R = 512; C = DSZ; Cpad = DSZ; bx = b % 16; by = b / 16; }
  int c0 = bx * 64, r0 = by * 64;
  int wv = tid >> 6, ln = tid & 63;
  int c = c0 + ln;
#pragma unroll 4
  for (int i = 0; i < 16; ++i) {
    int r = i * 4 + wv;
    tile[r][ln] = (c < C) ? src[(size_t)(r0 + r) * C + c] : 0.f;
  }
  __syncthreads();
  int ccb = tid >> 4;
  int r4 = (tid & 15) * 4;
#pragma unroll
  for (int j = 0; j < 4; ++j) {
    int cc = ccb + j * 16;
    if (c0 + cc >= Cpad) continue;
    unsigned int u = __builtin_amdgcn_cvt_pk_fp8_f32(QS * tile[r4 + 0][cc], QS * tile[r4 + 1][cc], 0, 0);
    u = __builtin_amdgcn_cvt_pk_fp8_f32(QS * tile[r4 + 2][cc], QS * tile[r4 + 3][cc], u, 1);
    *(unsigned int*)(dst + (size_t)(c0 + cc) * R + r0 + r4) = u;
  }
}

// -------- encoder layer 2 partials: all 4 batch rows per block (w2 read once)
__global__ __launch_bounds__(256) void enc2p_kernel(const float* __restrict__ t1p,
                                                    const float* __restrict__ b1,
                                                    const float* __restrict__ w2,
                                                    float* __restrict__ ep) {
  __shared__ float ts[4][256];
  int i = blockIdx.x * 256 + threadIdx.x;
  int kc = blockIdx.y;
  int h = kc * 256 + threadIdx.x;
  float bv = b1[h];
#pragma unroll
  for (int b = 0; b < 4; ++b) {
    float s0 = bv;
#pragma unroll
    for (int cc = 0; cc < KS1; ++cc) s0 += t1p[((size_t)(b * KS1 + cc)) * HSZ + h];
    ts[b][threadIdx.x] = gelu_f(s0);
  }
  __syncthreads();
  const float* w = w2 + (size_t)(kc * 256) * DSZ + i;
  float a0 = 0.f, a1 = 0.f, a2 = 0.f, a3 = 0.f;
#pragma unroll 4
  for (int j = 0; j < 256; ++j) {
    float wv = w[(size_t)j * DSZ];
    a0 += ts[0][j] * wv; a1 += ts[1][j] * wv;
    a2 += ts[2][j] * wv; a3 += ts[3][j] * wv;
  }
  ep[((size_t)(0 * KS2 + kc)) * DSZ + i] = a0;
  ep[((size_t)(1 * KS2 + kc)) * DSZ + i] = a1;
  ep[((size_t)(2 * KS2 + kc)) * DSZ + i] = a2;
  ep[((size_t)(3 * KS2 + kc)) * DSZ + i] = a3;
}

// -------- windows (enc2 combine fused): win8[b*T+t][j] = fp8((b2[t+j] + sum ep)*16)
__global__ __launch_bounds__(256) void win8_kernel(const float* __restrict__ ep,
                                                   const float* __restrict__ b2,
                                                   unsigned char* __restrict__ win8) {
  int blk = blockIdx.x;
  int b = blk >> 9, t = blk & 511;
  const float* epb = ep + (size_t)b * KS2 * DSZ;
  for (int j = threadIdx.x; j < 512; j += 256) {
    int d = t + j;
    float s = b2[d];
#pragma unroll
    for (int kc = 0; kc < KS2; ++kc) s += epb[(size_t)kc * DSZ + d];
    win8[(size_t)blk * 512 + j] = q8(s);
  }
}

// -------- mid MX-fp8 GEMM: compiler-scheduled reads/MFMA inside each step;
// end-of-step waits fold lgkmcnt(0) so a wave never signals the barrier with
// LDS reads in flight (closes the r18 race window).
template<int GELU>
__global__ __launch_bounds__(256, 3) void gemmMX0(
    const unsigned char* __restrict__ A, const unsigned char* __restrict__ Bm,
    const float* __restrict__ bias, unsigned char* __restrict__ out8,
    int NT, int N, int K) {
  __shared__ __align__(16) char SM[49152];
  const int tid = threadIdx.x;
  const int lane = tid & 63;
  const int wave = tid >> 6;
  const int wr = (wave >> 1) * 64, wc = (wave & 1) * 64;
  const int l31 = lane & 31, hi = lane >> 5;

  const int cpx = (int)gridDim.x >> 3;
  const int wg = ((int)blockIdx.x & 7) * cpx + ((int)blockIdx.x >> 3);
  const int m0 = (wg / NT) * 128, n0 = (wg % NT) * 128;

  f32x16 acc[2][2];
#pragma unroll
  for (int i = 0; i < 2; ++i)
#pragma unroll
    for (int j = 0; j < 2; ++j)
#pragma unroll
      for (int r = 0; r < 16; ++r) acc[i][j][r] = 0.f;

  const int ppair = lane & 3;
  const int row0 = wave * 16 + (lane >> 2);
  const int row1 = row0 + 64;
  const int og0 = (ppair - (row0 >> 1)) & 3;
  const int og1 = (ppair - (row1 >> 1)) & 3;
  const unsigned char* a0 = A + (size_t)(m0 + row0) * K + og0 * 16;
  const unsigned char* a1 = A + (size_t)(m0 + row1) * K + og1 * 16;
  const unsigned char* b0 = Bm + (size_t)(n0 + row0) * K + og0 * 16;
  const unsigned char* b1 = Bm + (size_t)(n0 + row1) * K + og1 * 16;

#define STGM(tt, bufb) do { \
    GLD16(a0 + (size_t)(tt) * 64, SM + (bufb) + wave * 1024); \
    GLD16(a1 + (size_t)(tt) * 64, SM + (bufb) + 4096 + wave * 1024); \
    GLD16(b0 + (size_t)(tt) * 64, SM + (bufb) + 8192 + wave * 1024); \
    GLD16(b1 + (size_t)(tt) * 64, SM + (bufb) + 12288 + wave * 1024); \
  } while (0)

  const int KT = K >> 6;
  STGM(0, 0);
  STGM(1, 16384);
  asm volatile("s_waitcnt vmcnt(4)" ::: "memory");
  __builtin_amdgcn_s_barrier();
  asm volatile("" ::: "memory");
  int cb = 0;
  for (int t = 0; t < KT; ++t) {
    if (t + 2 < KT) {
      int nb = cb + 32768; if (nb >= 49152) nb -= 49152;
      STGM(t + 2, nb);
    }
    i32x8 a8[2], b8[2];
#pragma unroll
    for (int mf = 0; mf < 2; ++mf) {
      const int row = wr + mf * 32 + l31;
      const char* base = SM + cb + row * 64;
      const int ph0 = (2 * hi + (row >> 1)) & 3;
      const int ph1 = (2 * hi + 1 + (row >> 1)) & 3;
      i32x4 q01 = *(const i32x4*)(base + ph0 * 16);
      i32x4 q23 = *(const i32x4*)(base + ph1 * 16);
      a8[mf] = __builtin_shufflevector(q01, q23, 0, 1, 2, 3, 4, 5, 6, 7);
    }
#pragma unroll
    for (int nf = 0; nf < 2; ++nf) {
      const int row = wc + nf * 32 + l31;
      const char* base = SM + cb + 8192 + row * 64;
      const int ph0 = (2 * hi + (row >> 1)) & 3;
      const int ph1 = (2 * hi + 1 + (row >> 1)) & 3;
      i32x4 q01 = *(const i32x4*)(base + ph0 * 16);
      i32x4 q23 = *(const i32x4*)(base + ph1 * 16);
      b8[nf] = __builtin_shufflevector(q01, q23, 0, 1, 2, 3, 4, 5, 6, 7);
    }
#pragma unroll
    for (int mf = 0; mf < 2; ++mf)
#pragma unroll
      for (int nf = 0; nf < 2; ++nf)
        acc[mf][nf] = __builtin_amdgcn_mfma_scale_f32_32x32x64_f8f6f4(
            a8[mf], b8[nf], acc[mf][nf], 0, 0, 0, 123, 0, 123);
    if (t + 2 < KT) {
      asm volatile("s_waitcnt vmcnt(4) lgkmcnt(0)" ::: "memory");
      __builtin_amdgcn_s_barrier();
      asm volatile("" ::: "memory");
    } else if (t + 1 < KT) {
      asm volatile("s_waitcnt vmcnt(0) lgkmcnt(0)" ::: "memory");
      __builtin_amdgcn_s_barrier();
      asm volatile("" ::: "memory");
    }
    cb += 16384; if (cb >= 49152) cb = 0;
  }
#undef STGM
  asm volatile("s_waitcnt lgkmcnt(0)" ::: "memory");

#pragma unroll
  for (int nf = 0; nf < 2; ++nf) {
    const int n = n0 + wc + nf * 32 + l31;
    const float bv = bias[n];
#pragma unroll
    for (int mf = 0; mf < 2; ++mf) {
      const int mb = m0 + wr + mf * 32 + 4 * hi;
#pragma unroll
      for (int r = 0; r < 16; ++r) {
        const int m = mb + (r & 3) + 8 * (r >> 2);
        float v = acc[mf][nf][r] + bv;
        if (GELU) v = gelu_f(v);
        out8[(size_t)m * N + n] = q8(v);
      }
    }
  }
}

// -------- lm-head MX-fp8 GEMM: same race-closed schedule.
__global__ __launch_bounds__(256, 3) void gemmLM(
    const unsigned char* __restrict__ A, const unsigned char* __restrict__ Bm,
    float* __restrict__ outF, float* __restrict__ pm, float* __restrict__ ps) {
  __shared__ __align__(16) char SM[49152];
  const int tid = threadIdx.x;
  const int lane = tid & 63;
  const int wave = tid >> 6;
  const int wr = (wave >> 1) * 64, wc = (wave & 1) * 64;
  const int l31 = lane & 31, hi = lane >> 5;

  const int cpx = (int)gridDim.x >> 3;
  const int wg = ((int)blockIdx.x & 7) * cpx + ((int)blockIdx.x >> 3);
  const int m0 = (wg >> 4) * 128, n0 = (wg & 15) * 128;

  f32x16 acc[2][2];
#pragma unroll
  for (int i = 0; i < 2; ++i)
#pragma unroll
    for (int j = 0; j < 2; ++j)
#pragma unroll
      for (int r = 0; r < 16; ++r) acc[i][j][r] = 0.f;

  const int ppair = lane & 3;
  const int row0 = wave * 16 + (lane >> 2);
  const int row1 = row0 + 64;
  const int og0 = (ppair - (row0 >> 1)) & 3;
  const int og1 = (ppair - (row1 >> 1)) & 3;
  const unsigned char* a0 = A + (size_t)(m0 + row0) * DSZ + og0 * 16;
  const unsigned char* a1 = A + (size_t)(m0 + row1) * DSZ + og1 * 16;
  const unsigned char* b0 = Bm + (size_t)(n0 + row0) * DSZ + og0 * 16;
  const unsigned char* b1 = Bm + (size_t)(n0 + row1) * DSZ + og1 * 16;

#define STGL(tt, bufb) do { \
    GLD16(a0 + (size_t)(tt) * 64, SM + (bufb) + wave * 1024); \
    GLD16(a1 + (size_t)(tt) * 64, SM + (bufb) + 4096 + wave * 1024); \
    GLD16(b0 + (size_t)(tt) * 64, SM + (bufb) + 8192 + wave * 1024); \
    GLD16(b1 + (size_t)(tt) * 64, SM + (bufb) + 12288 + wave * 1024); \
  } while (0)

  STGL(0, 0);
  STGL(1, 16384);
  asm volatile("s_waitcnt vmcnt(4)" ::: "memory");
  __builtin_amdgcn_s_barrier();
  asm volatile("" ::: "memory");
  int cb = 0;
  for (int t = 0; t < 16; ++t) {
    if (t + 2 < 16) {
      int nb = cb + 32768; if (nb >= 49152) nb -= 49152;
      STGL(t + 2, nb);
    }
    i32x8 a8[2], b8[2];
#pragma unroll
    for (int mf = 0; mf < 2; ++mf) {
      const int row = wr + mf * 32 + l31;
      const char* base = SM + cb + row * 64;
      const int ph0 = (2 * hi + (row >> 1)) & 3;
      const int ph1 = (2 * hi + 1 + (row >> 1)) & 3;
      i32x4 q01 = *(const i32x4*)(base + ph0 * 16);
      i32x4 q23 = *(const i32x4*)(base + ph1 * 16);
      a8[mf] = __builtin_shufflevector(q01, q23, 0, 1, 2, 3, 4, 5, 6, 7);
    }
#pragma unroll
    for (int nf = 0; nf < 2; ++nf) {
      const int row = wc + nf * 32 + l31;
      const char* base = SM + cb + 8192 + row * 64;
      const int ph0 = (2 * hi + (row >> 1)) & 3;
      const int ph1 = (2 * hi + 1 + (row >> 1)) & 3;
      i32x4 q01 = *(const i32x4*)(base + ph0 * 16);
      i32x4 q23 = *(const i32x4*)(base + ph1 * 16);
      b8[nf] = __builtin_shufflevector(q01, q23, 0, 1, 2, 3, 4, 5, 6, 7);
    }
#pragma unroll
    for (int mf = 0; mf < 2; ++mf)
#pragma unroll
      for (int nf = 0; nf < 2; ++nf)
        acc[mf][nf] = __builtin_amdgcn_mfma_scale_f32_32x32x64_f8f6f4(
            a8[mf], b8[nf], acc[mf][nf], 0, 0, 0, 123, 0, 123);
    if (t + 2 < 16) {
      asm volatile("s_waitcnt vmcnt(4) lgkmcnt(0)" ::: "memory");
      __builtin_amdgcn_s_barrier();
      asm volatile("" ::: "memory");
    } else if (t + 1 < 16) {
      asm volatile("s_waitcnt vmcnt(0) lgkmcnt(0)" ::: "memory");
      __builtin_amdgcn_s_barrier();
      asm volatile("" ::: "memory");
    }
    cb += 16384; if (cb >= 49152) cb = 0;
  }
#undef STGL
  asm volatile("s_waitcnt lgkmcnt(0)" ::: "memory");

  // ---- fused softmax partials: wave's 64 v-rows = stripe ch
  const int ch = (m0 + wr) >> 6;
#pragma unroll
  for (int nf = 0; nf < 2; ++nf) {
    const int pos = n0 + wc + nf * 32 + l31;
    float mloc = -1e30f, sloc = 0.f;
#pragma unroll
    for (int mf = 0; mf < 2; ++mf) {
      const int vb = m0 + wr + mf * 32 + 4 * hi;
#pragma unroll
      for (int r = 0; r < 16; ++r) {
        const int v = vb + (r & 3) + 8 * (r >> 2);
        if (v < VSZ) mloc = fmaxf(mloc, acc[mf][nf][r]);
      }
    }
#pragma unroll
    for (int mf = 0; mf < 2; ++mf) {
      const int vb = m0 + wr + mf * 32 + 4 * hi;
#pragma unroll
      for (int r = 0; r < 16; ++r) {
        const int v = vb + (r & 3) + 8 * (r >> 2);
        if (v < VSZ) sloc += __expf(acc[mf][nf][r] - mloc);
      }
    }
    {
      float mo = __shfl_xor(mloc, 32, 64);
      float so = __shfl_xor(sloc, 32, 64);
      float nm = fmaxf(mloc, mo);
      sloc = sloc * __expf(mloc - nm) + so * __expf(mo - nm);
      mloc = nm;
    }
    if (hi == 0) {
      pm[(size_t)ch * NPOS + pos] = mloc;
      ps[(size_t)ch * NPOS + pos] = sloc;
    }
  }

  // ---- 2-pass dual-region LDS restage + aligned NT stores.
  float* epi = (float*)SM;
  const int bb = n0 >> 9, t0 = n0 & 511;
  float* outG = outF + 1 + (size_t)bb * VSZ * TSZ + t0;
  const int trow = tid >> 5;
  const int lofs = (tid & 31) * 4;
#pragma unroll
  for (int p = 0; p < 2; ++p) {
    __builtin_amdgcn_s_barrier();
    asm volatile("" ::: "memory");
    {
      const int rg = wave >> 1;
#pragma unroll
      for (int nf = 0; nf < 2; ++nf)
#pragma unroll
        for (int r = 0; r < 16; ++r)
          epi[rg * 4224 + ((r & 3) + 8 * (r >> 2) + 4 * hi) * 132 + wc + nf * 32 + l31] =
              acc[p][nf][r];
    }
    __builtin_amdgcn_s_barrier();
    asm volatile("" ::: "memory");
#pragma unroll
    for (int rg = 0; rg < 2; ++rg) {
      const int q = rg * 2 + p;
#pragma unroll
      for (int pp = 0; pp < 4; ++pp) {
        int row = pp * 8 + trow;
        int v = m0 + q * 32 + row;
        if (v < VSZ) {
          f32x4 val = *(const f32x4*)&epi[rg * 4224 + row * 132 + lofs];
          float* gp = outG + (size_t)v * TSZ + lofs;
          __builtin_nontemporal_store(val[0], gp + 0);
          __builtin_nontemporal_store(val[1], gp + 1);
          __builtin_nontemporal_store(val[2], gp + 2);
          __builtin_nontemporal_store(val[3], gp + 3);
        }
      }
    }
  }
}

// -------- loss stage 1: merge 13-chunk groups (512 blocks, 2/CU)
__global__ __launch_bounds__(256) void lsestage1_kernel(const float* __restrict__ pm,
                                                        const float* __restrict__ ps,
                                                        float* __restrict__ pm2,
                                                        float* __restrict__ ps2) {
  int pos = (blockIdx.x & 7) * 256 + threadIdx.x;
  int cg = blockIdx.x >> 3;
  int c0 = cg * CPC;
  int c1 = c0 + CPC; if (c1 > NCH) c1 = NCH;
  float m = -1e30f, s = 0.f;
  for (int c = c0; c < c1; ++c) {
    float cm = pm[(size_t)c * NPOS + pos];
    float cs = ps[(size_t)c * NPOS + pos];
    float nm = fmaxf(m, cm);
    s = s * __expf(m - nm) + cs * __expf(cm - nm);
    m = nm;
  }
  pm2[(size_t)cg * NPOS + pos] = m;
  ps2[(size_t)cg * NPOS + pos] = s;
}

// -------- loss stage 2: merge 64 groups per position, gather label logit
__global__ __launch_bounds__(256) void lsemerge_kernel(const float* __restrict__ pm2,
                                                       const float* __restrict__ ps2,
                                                       const float* __restrict__ outF,
                                                       const int* __restrict__ labels,
                                                       float* __restrict__ contrib) {
  int pos = blockIdx.x * 256 + threadIdx.x;
  float m[4] = {-1e30f, -1e30f, -1e30f, -1e30f};
  float s[4] = {0.f, 0.f, 0.f, 0.f};
  for (int c = 0; c < CG; c += 4) {
#pragma unroll
    for (int j = 0; j < 4; ++j) {
      float cm = pm2[(size_t)(c + j) * NPOS + pos];
      float cs = ps2[(size_t)(c + j) * NPOS + pos];
      float nm = fmaxf(m[j], cm);
      s[j] = s[j] * __expf(m[j] - nm) + cs * __expf(cm - nm);
      m[j] = nm;
    }
  }
#pragma unroll
  for (int j = 1; j < 4; ++j) {
    float nm = fmaxf(m[0], m[j]);
    s[0] = s[0] * __expf(m[0] - nm) + s[j] * __expf(m[j] - nm);
    m[0] = nm;
  }
  float lse = m[0] + logf(s[0]);
  int b = pos >> 9, t = pos & 511;
  int lab = labels[pos];
  float x = outF[1 + (size_t)b * VSZ * TSZ + (size_t)lab * TSZ + t];
  contrib[pos] = lse - x;
}

__global__ __launch_bounds__(256) void lossfinal_kernel(const float* __restrict__ contrib,
                                                        float* __restrict__ dout) {
  __shared__ float red[256];
  int tid = threadIdx.x;
  float a = 0.f;
  for (int i = tid; i < NPOS; i += 256) a += contrib[i];
  red[tid] = a;
  __syncthreads();
  for (int off = 128; off; off >>= 1) {
    if (tid < off) red[tid] += red[tid + off];
    __syncthreads();
  }
  if (tid == 0) dout[0] = red[0] / (float)NPOS;
}

extern "C" void kernel_launch(void* const* d_in, const int* in_sizes, int n_in,
                              void* d_out, int out_size, void* d_ws, size_t ws_size,
                              hipStream_t stream) {
  const int* input_ids = (const int*)d_in[0];
  const int* labels    = (const int*)d_in[1];
  const float* wte     = (const float*)d_in[2];
  const float* enc_w1  = (const float*)d_in[3];
  const float* enc_b1  = (const float*)d_in[4];
  const float* enc_w2  = (const float*)d_in[5];
  const float* enc_b2  = (const float*)d_in[6];
  const float* proj_w  = (const float*)d_in[7];
  const float* proj_b  = (const float*)d_in[8];
  const float* dec_w1  = (const float*)d_in[9];
  const float* dec_b1  = (const float*)d_in[10];
  const float* dec_w2  = (const float*)d_in[11];
  const float* dec_b2  = (const float*)d_in[12];
  const float* lm_w    = (const float*)d_in[13];
  float* outF = (float*)d_out;

  char* w = (char*)d_ws;
  size_t off = 0;
  unsigned char* lm8  = (unsigned char*)(w + off); off += (size_t)VPAD * DSZ;   // 51.6 MB
  unsigned char* w18  = (unsigned char*)(w + off); off += (size_t)HSZ * DSZ;    // 4 MB
  unsigned char* w28  = (unsigned char*)(w + off); off += (size_t)DSZ * HSZ;    // 4 MB
  unsigned char* p8   = (unsigned char*)(w + off); off += (size_t)DSZ * 512;    // 0.5 MB
  unsigned char* win8 = (unsigned char*)(w + off); off += (size_t)NPOS * 512;   // 1 MB
  unsigned char* pbuf8= (unsigned char*)(w + off); off += (size_t)NPOS * DSZ;   // 2 MB
  unsigned char* abuf8= (unsigned char*)(w + off); off += (size_t)NPOS * HSZ;   // 8 MB
  unsigned char* dbuf8= (unsigned char*)(w + off); off += (size_t)NPOS * DSZ;   // 2 MB
  float* t1p    = (float*)(w + off);  off += (size_t)BSZ * KS1 * HSZ * 4;
  float* ep     = (float*)(w + off);  off += (size_t)BSZ * KS2 * DSZ * 4;
  float* contrib= (float*)(w + off);  off += (size_t)NPOS * 4;
  float* pm     = (float*)(w + off);  off += (size_t)NCH * NPOS * 4;            // 6.5 MB
  float* ps     = (float*)(w + off);  off += (size_t)NCH * NPOS * 4;            // 6.5 MB
  float* pm2    = (float*)(w + off);  off += (size_t)CG * NPOS * 4;             // 512 KB
  float* ps2    = (float*)(w + off);  off += (size_t)CG * NPOS * 4;             // 512 KB
  (void)ws_size; (void)in_sizes; (void)n_in; (void)out_size;

  // weight transposes + enc1 partials in one dispatch
  transpose_all<<<14912, 256, 0, stream>>>(lm_w, dec_w1, dec_w2, proj_w,
                                           lm8, w18, w28, p8,
                                           input_ids, wte, enc_w1, t1p);

  // encoder layer 2 + windows (enc2 combine fused into win8)
  enc2p_kernel<<<dim3(DSZ / 256, KS2), 256, 0, stream>>>(t1p, enc_b1, enc_w2, ep);
  win8_kernel<<<2048, 256, 0, stream>>>(ep, enc_b2, win8);

  // MX-fp8 GEMM chain (1D grids, all divisible by 8 for the XCD swizzle)
  gemmMX0<0><<<128, 256, 0, stream>>>(win8, p8, proj_b, pbuf8, 8, DSZ, 512);
  gemmMX0<1><<<512, 256, 0, stream>>>(pbuf8, w18, dec_b1, abuf8, 32, HSZ, DSZ);
  gemmMX0<0><<<128, 256, 0, stream>>>(abuf8, w28, dec_b2, dbuf8, 8, DSZ, HSZ);
  // lm head MX-fp8: 394 m-tiles x 16 n-tiles = 6304 blocks
  gemmLM<<<6304, 256, 0, stream>>>(lm8, dbuf8, outF, pm, ps);

  // loss: two-stage merge + mean
  lsestage1_kernel<<<512, 256, 0, stream>>>(pm, ps, pm2, ps2);
  lsemerge_kernel<<<dim3(NPOS / 256), 256, 0, stream>>>(pm2, ps2, outF, labels, contrib);
  lossfinal_kernel<<<1, 256, 0, stream>>>(contrib, outF);
}